// Round 2
// baseline (795.919 us; speedup 1.0000x reference)
//
#include <hip/hip_runtime.h>
#include <math.h>

// ---------------------------------------------------------------------------
// N=64, L=128, W=256, D=384, H=8, E=48, NL=4, DFF=1536, rows = N*L = 8192
// GEMMs: bf16 MFMA 16x16x32, A [M][K] bf16 row-major, Bt [N][K] bf16.
// R19: eliminate cnn stage-C im2col. Stage B stores output TRANSPOSED as
// p1T[row][ci] bf16 (row = pos+3, 3 zero rows each side, row stride 24
// shorts = 48B). Conv2 = 4 paired-shift GEMMs: K=32 = {2 shifts x 16 ci};
// the B-fragment for shift s is a b128 read of p1T at row p+s -- no
// materialized im2col, no stage-C barriers (6 -> 4 per block). w2 is
// pre-arranged to the matching [c][pr][q*8+j] layout in w2cvt (shift 7
// columns zeroed). LDS 25.5KB -> 15.2KB.
// Post-mortem R18: conflicts 7.2M->1.9M but dur unchanged -> kernel is
// bound by per-thread VALU/LDS serial work (~3200 inst/thread), not
// occupancy; this round removes ~600 VALU + ~64 scalar ds_reads/thread.
// ---------------------------------------------------------------------------

typedef float f32x4 __attribute__((ext_vector_type(4)));
typedef short bf16x8 __attribute__((ext_vector_type(8)));
typedef short s16x4 __attribute__((ext_vector_type(4)));

__device__ __forceinline__ short f2bf(float f) {
    union { float f; unsigned u; } c; c.f = f;
    unsigned r = (c.u + 0x7FFFu + ((c.u >> 16) & 1u)) >> 16;
    return (short)r;
}
__device__ __forceinline__ float bf2f(short s) {
    union { unsigned u; float f; } c;
    c.u = ((unsigned)(unsigned short)s) << 16;
    return c.f;
}

__device__ __forceinline__ void gload_lds16(const void* g, void* l) {
    __builtin_amdgcn_global_load_lds(
        (const __attribute__((address_space(1))) unsigned int*)g,
        (__attribute__((address_space(3))) unsigned int*)l,
        16, 0, 0);
}

// ---------------- positional encoding table: pe[l][d] ----------------------
__global__ __launch_bounds__(384) void pe_kernel(float* __restrict__ pe) {
    int l = blockIdx.x, d = threadIdx.x;
    int i2 = d >> 1;
    float ang = (float)l * expf(-(2.0f * (float)i2 / 384.0f) * 9.210340371976184f);
    pe[l * 384 + d] = (d & 1) ? cosf(ang) : sinf(ang);
}

// ---------------- weight convert+transpose: W fp32 [K][N] -> bf16 [N][K] ---
__global__ __launch_bounds__(256) void wcvt_kernel(
    const float* __restrict__ W, short* __restrict__ Wt, int K, int N,
    int dstOff, int srcZ, int dstZ)
{
    __shared__ float tile[32][33];
    int kb = blockIdx.x * 32, nb = blockIdx.y * 32;
    const float* Wp = W + (size_t)blockIdx.z * srcZ;
    short* Wtp = Wt + (size_t)blockIdx.z * dstZ + dstOff;
    int tx = threadIdx.x & 31, ty = threadIdx.x >> 5;
    #pragma unroll
    for (int r = ty; r < 32; r += 8)
        tile[r][tx] = Wp[(size_t)(kb + r) * N + nb + tx];
    __syncthreads();
    #pragma unroll
    for (int r = ty; r < 32; r += 8)
        Wtp[(size_t)(nb + r) * K + kb + tx] = f2bf(tile[tx][r]);
}

// ---------------- Wq/Wk/Wv -> WqkvT in one dispatch (z = layer*3+which) ----
__global__ __launch_bounds__(256) void qkvcvt_kernel(
    const float* __restrict__ Wq, const float* __restrict__ Wk,
    const float* __restrict__ Wv, short* __restrict__ WqkvT)
{
    __shared__ float tile[32][33];
    int kb = blockIdx.x * 32, nb = blockIdx.y * 32;
    int layer = blockIdx.z / 3, which = blockIdx.z - layer * 3;
    const float* Wp = (which == 0 ? Wq : (which == 1 ? Wk : Wv)) +
                      (size_t)layer * 147456;
    short* Wtp = WqkvT + (size_t)layer * 442368 + (size_t)which * 147456;
    int tx = threadIdx.x & 31, ty = threadIdx.x >> 5;
    #pragma unroll
    for (int r = ty; r < 32; r += 8)
        tile[r][tx] = Wp[(size_t)(kb + r) * 384 + nb + tx];
    __syncthreads();
    #pragma unroll
    for (int r = ty; r < 32; r += 8)
        Wtp[(size_t)(nb + r) * 384 + kb + tx] = f2bf(tile[tx][r]);
}

// ---------------- conv2 weights -> paired-shift layout [64][128] -----------
// w2p[c][pr*32 + q*8 + j] = w2[c][ci*7 + sft], ci=(q&1)*8+j, sft=2*pr+(q>>1);
// sft==7 (pair 3, upper half) -> 0. Matches stage-C A-fragment reads.
__global__ __launch_bounds__(256) void w2cvt_kernel(
    const float* __restrict__ w2, short* __restrict__ w2T)
{
    int idx = blockIdx.x * 256 + threadIdx.x;   // 64*128 = 8192
    int c = idx >> 7, r = idx & 127;
    int pr = r >> 5, q = (r >> 3) & 3, j = r & 7;
    int ci = (q & 1) * 8 + j;
    int sft = 2 * pr + (q >> 1);
    w2T[idx] = (sft < 7) ? f2bf(w2[c * 112 + ci * 7 + sft]) : (short)0;
}

// ---------------- concatenated qkv bias: bqkv[l][1152] ---------------------
__global__ __launch_bounds__(384) void biascat_kernel(
    const float* __restrict__ bq, const float* __restrict__ bk,
    const float* __restrict__ bv, float* __restrict__ bqkv)
{
    int l = blockIdx.x, j = threadIdx.x;
    bqkv[l * 1152 + j] = bq[l * 384 + j];
    bqkv[l * 1152 + 384 + j] = bk[l * 384 + j];
    bqkv[l * 1152 + 768 + j] = bv[l * 384 + j];
}

// ---------------- fused CNN window encoder: 2 windows per block ------------
// LDS layout (15232 B total):
//   [0     .. 2048)   xs[2][256] f32
//   [2048  .. 6400)   p0[2][4][136] f32
//   [6400  .. 8192)   w1s[64][7] f32
//   [8192  .. 8304)   w0s[4*7] f32
//   [8320  .. 15232)  p1T[2][72][24] bf16  (row = pos+3; rows 0-2 & 67-71
//                     zeroed; only cols 0-15 used, stride 24 for banks)
__global__ __launch_bounds__(256, 8) void cnn_kernel(
    const float* __restrict__ x,
    const float* __restrict__ w0, const float* __restrict__ b0,
    const float* __restrict__ w1, const float* __restrict__ b1,
    const short* __restrict__ w2T, const float* __restrict__ b2,
    short* __restrict__ feat)
{
    __shared__ __align__(16) char smem[15232];
    float* xs = (float*)smem;                         // [2][256]
    float* p0 = (float*)(smem + 2048);                // [2][4][136]
    float (*w1s)[7] = (float(*)[7])(smem + 6400);     // [64][7]
    float* w0s = (float*)(smem + 8192);               // [4*7]
    short* p1T = (short*)(smem + 8320);               // [2][72][24]

    int tid = threadIdx.x;
    size_t win0 = (size_t)blockIdx.x * 2;
    int w = tid >> 6, lane = tid & 63;
    int cq = lane >> 4, cl = lane & 15;

    xs[tid] = x[win0 * 256 + tid];
    xs[256 + tid] = x[(win0 + 1) * 256 + tid];
    if (tid < 28) w0s[tid] = w0[tid];
    if (tid < 64) {
        for (int k = 0; k < 7; ++k) w1s[tid][k] = w1[tid * 7 + k];
    }
    // zero p1T (covers the boundary pad rows; interior overwritten in B)
    {
        int* pz = (int*)p1T;
        #pragma unroll
        for (int i = tid; i < 1728; i += 256) pz[i] = 0;
    }
    __syncthreads();

    // ---- stage A: conv0 (1->4) + relu + pool2 -> p0[wv][4][128] ----
    #pragma unroll
    for (int wv = 0; wv < 2; ++wv) {
        int c = tid & 3, p = tid >> 2;
        float bb = b0[c];
        #pragma unroll
        for (int t2 = 0; t2 < 2; ++t2) {
            int pp = p + 64 * t2;
            float rv[9];
            #pragma unroll
            for (int u = 0; u < 9; ++u) {
                int j = 2 * pp + u - 3;
                rv[u] = (j >= 0 && j < 256) ? xs[wv * 256 + j] : 0.f;
            }
            float a0 = bb, a1 = bb;
            #pragma unroll
            for (int k = 0; k < 7; ++k) {
                float ww = w0s[c * 7 + k];
                a0 = fmaf(ww, rv[k], a0);
                a1 = fmaf(ww, rv[k + 1], a1);
            }
            p0[(wv * 4 + c) * 136 + pp] = fmaxf(fmaxf(a0, a1), 0.f);
        }
    }
    __syncthreads();

    // ---- stage B: conv1 (4->16) + relu + pool2 -> p1T[wv][3+pos][c] ----
    #pragma unroll
    for (int wv = 0; wv < 2; ++wv) {
        int c = tid & 15;
        int i0 = (tid >> 4) * 8;
        float acc[8];
        float bb = b1[c];
        #pragma unroll
        for (int m = 0; m < 8; ++m) acc[m] = bb;
        #pragma unroll
        for (int ci = 0; ci < 4; ++ci) {
            float rv[14];
            #pragma unroll
            for (int u = 0; u < 14; ++u) {
                int j = i0 + u - 3;
                rv[u] = (j >= 0 && j < 128) ? p0[(wv * 4 + ci) * 136 + j] : 0.f;
            }
            #pragma unroll
            for (int k = 0; k < 7; ++k) {
                float ww = w1s[c * 4 + ci][k];
                #pragma unroll
                for (int m = 0; m < 8; ++m) acc[m] = fmaf(ww, rv[m + k], acc[m]);
            }
        }
        int po = i0 >> 1;
        #pragma unroll
        for (int m = 0; m < 4; ++m)
            p1T[wv * 1728 + (3 + po + m) * 24 + c] =
                f2bf(fmaxf(fmaxf(acc[2 * m], acc[2 * m + 1]), 0.f));
    }
    __syncthreads();

    // ---- stage C: conv2 as 4 paired-shift GEMMs on p1T (no im2col) ----
    // MFMA K=32 = {shift 2pr (q=0,1: ci 0-7,8-15), shift 2pr+1 (q=2,3)}.
    // B-fragment: lane(q,n) reads p1T[w*16+n + (q>>1) + 2pr][(q&1)*8..+7].
    f32x4 acc0[4], acc1[4];
    #pragma unroll
    for (int mt = 0; mt < 4; ++mt) {
        acc0[mt] = (f32x4){0.f, 0.f, 0.f, 0.f};
        acc1[mt] = (f32x4){0.f, 0.f, 0.f, 0.f};
    }
    {
        const short* bp0 = p1T + (w * 16 + cl + (cq >> 1)) * 24 + (cq & 1) * 8;
        const short* bp1 = bp0 + 1728;
        #pragma unroll
        for (int pr = 0; pr < 4; ++pr) {
            bf16x8 bfr0 = *(const bf16x8*)&bp0[pr * 48];
            bf16x8 bfr1 = *(const bf16x8*)&bp1[pr * 48];
            #pragma unroll
            for (int mt = 0; mt < 4; ++mt) {
                bf16x8 af = *(const bf16x8*)&w2T[(mt * 16 + cl) * 128 +
                                                 pr * 32 + cq * 8];
                acc0[mt] = __builtin_amdgcn_mfma_f32_16x16x32_bf16(
                    af, bfr0, acc0[mt], 0, 0, 0);
                acc1[mt] = __builtin_amdgcn_mfma_f32_16x16x32_bf16(
                    af, bfr1, acc1[mt], 0, 0, 0);
            }
        }
    }

    // ---- epilogue: pool pairs via shfl, store bf16 ----
    #pragma unroll
    for (int wv = 0; wv < 2; ++wv) {
        short* fp = feat + (win0 + wv) * 2048;
        int iev = (w * 16 + cl) >> 1;
        #pragma unroll
        for (int mt = 0; mt < 4; ++mt) {
            #pragma unroll
            for (int rg = 0; rg < 4; ++rg) {
                float v = wv ? acc1[mt][rg] : acc0[mt][rg];
                float v2 = __shfl_xor(v, 1, 64);
                if ((cl & 1) == 0) {
                    int c = mt * 16 + cq * 4 + rg;
                    float pv = fmaxf(fmaxf(v, v2) + b2[c], 0.f);
                    fp[c * 32 + iev] = f2bf(pv);
                }
            }
        }
    }
}

// ---------------- bf16 MFMA GEMM (thin-N): BM=128, BN=64, double-buffered --
// EPI bits: 1=relu, 2=+resid(f32), 4=+pe, 8=write f32, 16=write bf16
template <int EPI>
__global__ __launch_bounds__(256) void gemm_bf16(
    const short* __restrict__ A, const short* __restrict__ Bt,
    const float* __restrict__ bias, const float* __restrict__ resid,
    const float* __restrict__ pe, float* __restrict__ outF,
    short* __restrict__ outB, int M, int N, int K)
{
    __shared__ short As[2][128 * 64];
    __shared__ short Bs[2][64 * 64];
    int tid = threadIdx.x;
    int w = tid >> 6, lane = tid & 63;
    int wm = w >> 1, wn = w & 1;
    int m0 = blockIdx.y * 128, n0 = blockIdx.x * 64;

    int rl = lane >> 3, sl = lane & 7;
    int cb = sl ^ rl;
    const short* aptr[4];
    const short* bptr[2];
    int arow[4], brow[2];
    #pragma unroll
    for (int l = 0; l < 4; ++l) {
        arow[l] = l * 32 + w * 8;
        aptr[l] = A + (size_t)(m0 + arow[l] + rl) * K + cb * 8;
    }
    #pragma unroll
    for (int l = 0; l < 2; ++l) {
        brow[l] = l * 32 + w * 8;
        bptr[l] = Bt + (size_t)(n0 + brow[l] + rl) * K + cb * 8;
    }

    int cq = lane >> 4, cl = lane & 15;
    f32x4 acc[4][2];
    #pragma unroll
    for (int mt = 0; mt < 4; ++mt)
        #pragma unroll
        for (int nt = 0; nt < 2; ++nt)
            acc[mt][nt] = (f32x4){0.f, 0.f, 0.f, 0.f};

    #pragma unroll
    for (int l = 0; l < 4; ++l) { gload_lds16(aptr[l], &As[0][arow[l] * 64]); aptr[l] += 64; }
    #pragma unroll
    for (int l = 0; l < 2; ++l) { gload_lds16(bptr[l], &Bs[0][brow[l] * 64]); bptr[l] += 64; }
    __syncthreads();

    int nk = K >> 6;
    for (int k = 0; k < nk; ++k) {
        int cur = k & 1;
        if (k + 1 < nk) {
            #pragma unroll
            for (int l = 0; l < 4; ++l) { gload_lds16(aptr[l], &As[cur ^ 1][arow[l] * 64]); aptr[l] += 64; }
            #pragma unroll
            for (int l = 0; l < 2; ++l) { gload_lds16(bptr[l], &Bs[cur ^ 1][brow[l] * 64]); bptr[l] += 64; }
        }
        #pragma unroll
        for (int s = 0; s < 2; ++s) {
            bf16x8 afr[4], bfr[2];
            #pragma unroll
            for (int mt = 0; mt < 4; ++mt) {
                int r = wm * 64 + mt * 16 + cl;
                int slot = (s * 4 + cq) ^ (r & 7);
                afr[mt] = *(const bf16x8*)&As[cur][r * 64 + slot * 8];
            }
            #pragma unroll
            for (int nt = 0; nt < 2; ++nt) {
                int r = wn * 32 + nt * 16 + cl;
                int slot = (s * 4 + cq) ^ (r & 7);
                bfr[nt] = *(const bf16x8*)&Bs[cur][r * 64 + slot * 8];
            }
            #pragma unroll
            for (int mt = 0; mt < 4; ++mt)
                #pragma unroll
                for (int nt = 0; nt < 2; ++nt)
                    acc[mt][nt] = __builtin_amdgcn_mfma_f32_16x16x32_bf16(
                        afr[mt], bfr[nt], acc[mt][nt], 0, 0, 0);
        }
        __syncthreads();
    }

    #pragma unroll
    for (int mt = 0; mt < 4; ++mt) {
        #pragma unroll
        for (int nt = 0; nt < 2; ++nt) {
            int col = n0 + wn * 32 + nt * 16 + cl;
            float bb = bias[col];
            #pragma unroll
            for (int rg = 0; rg < 4; ++rg) {
                int row = m0 + wm * 64 + mt * 16 + cq * 4 + rg;
                float v = acc[mt][nt][rg] + bb;
                if (EPI & 1) v = fmaxf(v, 0.f);
                if (EPI & 4) v += pe[(row & 127) * 384 + col];
                if (EPI & 2) v += resid[(size_t)row * N + col];
                if (EPI & 8) outF[(size_t)row * N + col] = v;
                if (EPI & 16) outB[(size_t)row * N + col] = f2bf(v);
            }
        }
    }
}

// ---------------- bf16 MFMA GEMM (wide-N): BM=128, BN=128, BK=32 dbuf ------
template <int EPI>
__global__ __launch_bounds__(256) void gemm_bf16_wide(
    const short* __restrict__ A, const short* __restrict__ Bt,
    const float* __restrict__ bias, float* __restrict__ outF,
    short* __restrict__ outB, int M, int N, int K)
{
    __shared__ short As[2][128 * 32];
    __shared__ short Bs[2][128 * 32];
    int tid = threadIdx.x;
    int w = tid >> 6, lane = tid & 63;
    int wm = w >> 1, wn = w & 1;
    int m0 = blockIdx.y * 128, n0 = blockIdx.x * 128;

    int rl = lane >> 2, sl = lane & 3;
    int cb = sl ^ (rl & 3) ^ ((rl >> 2) & 3);
    const short* aptr[2];
    const short* bptr[2];
    int srow[2];
    #pragma unroll
    for (int l = 0; l < 2; ++l) {
        srow[l] = w * 32 + l * 16;
        aptr[l] = A + (size_t)(m0 + srow[l] + rl) * K + cb * 8;
        bptr[l] = Bt + (size_t)(n0 + srow[l] + rl) * K + cb * 8;
    }

    int cq = lane >> 4, cl = lane & 15;
    f32x4 acc[4][4];
    #pragma unroll
    for (int mt = 0; mt < 4; ++mt)
        #pragma unroll
        for (int nt = 0; nt < 4; ++nt)
            acc[mt][nt] = (f32x4){0.f, 0.f, 0.f, 0.f};

    #pragma unroll
    for (int l = 0; l < 2; ++l) {
        gload_lds16(aptr[l], &As[0][srow[l] * 32]);
        gload_lds16(bptr[l], &Bs[0][srow[l] * 32]);
        aptr[l] += 32; bptr[l] += 32;
    }
    __syncthreads();

    int nk = K >> 5;
    for (int k = 0; k < nk; ++k) {
        int cur = k & 1;
        if (k + 1 < nk) {
            #pragma unroll
            for (int l = 0; l < 2; ++l) {
                gload_lds16(aptr[l], &As[cur ^ 1][srow[l] * 32]);
                gload_lds16(bptr[l], &Bs[cur ^ 1][srow[l] * 32]);
                aptr[l] += 32; bptr[l] += 32;
            }
        }
        bf16x8 afr[4], bfr[4];
        #pragma unroll
        for (int mt = 0; mt < 4; ++mt) {
            int r = wm * 64 + mt * 16 + cl;
            int slot = cq ^ (r & 3) ^ ((r >> 2) & 3);
            afr[mt] = *(const bf16x8*)&As[cur][r * 32 + slot * 8];
        }
        #pragma unroll
        for (int nt = 0; nt < 4; ++nt) {
            int r = wn * 64 + nt * 16 + cl;
            int slot = cq ^ (r & 3) ^ ((r >> 2) & 3);
            bfr[nt] = *(const bf16x8*)&Bs[cur][r * 32 + slot * 8];
        }
        #pragma unroll
        for (int mt = 0; mt < 4; ++mt)
            #pragma unroll
            for (int nt = 0; nt < 4; ++nt)
                acc[mt][nt] = __builtin_amdgcn_mfma_f32_16x16x32_bf16(
                    afr[mt], bfr[nt], acc[mt][nt], 0, 0, 0);
        __syncthreads();
    }

    #pragma unroll
    for (int mt = 0; mt < 4; ++mt) {
        #pragma unroll
        for (int nt = 0; nt < 4; ++nt) {
            int col = n0 + wn * 64 + nt * 16 + cl;
            float bb = bias[col];
            #pragma unroll
            for (int rg = 0; rg < 4; ++rg) {
                int row = m0 + wm * 64 + mt * 16 + cq * 4 + rg;
                float v = acc[mt][nt][rg] + bb;
                if (EPI & 1) v = fmaxf(v, 0.f);
                if (EPI & 8) outF[(size_t)row * N + col] = v;
                if (EPI & 16) outB[(size_t)row * N + col] = f2bf(v);
            }
        }
    }
}

// ---------------- fused GEMM + bias + residual + LayerNorm -----------------
// BM=16, BN=384, BK=64 -> grid 512. (BK=32 regressed in R13.)
__global__ __launch_bounds__(256) void gemm_ln(
    const short* __restrict__ A, const short* __restrict__ Bt,
    const float* __restrict__ bias, const float* resid,
    const float* __restrict__ g, const float* __restrict__ be,
    float* t, short* __restrict__ tb, int K)
{
    __shared__ __align__(16) char smem[51200];
    short* As = (short*)smem;              // 16 x 64 bf16 = 2 KB
    short* Bs = (short*)(smem + 2048);     // 384 x 64 bf16 = 48 KB

    int tid = threadIdx.x;
    int w = tid >> 6, lane = tid & 63;
    int m0 = blockIdx.x * 16;
    int rl = lane >> 3, sl = lane & 7;
    int cb = sl ^ rl;

    const short* aptr = A + (size_t)(m0 + w * 8 + rl) * K + cb * 8;
    const short* bptr[12];
    #pragma unroll
    for (int l = 0; l < 12; ++l)
        bptr[l] = Bt + (size_t)(w * 96 + l * 8 + rl) * K + cb * 8;

    int cq = lane >> 4, cl = lane & 15;
    f32x4 acc[6];
    #pragma unroll
    for (int nt = 0; nt < 6; ++nt) acc[nt] = (f32x4){0.f, 0.f, 0.f, 0.f};

    for (int k0 = 0; k0 < K; k0 += 64) {
        if (w < 2) {
            gload_lds16(aptr, &As[(w * 8) * 64]);
            aptr += 64;
        }
        #pragma unroll
        for (int l = 0; l < 12; ++l) {
            gload_lds16(bptr[l], &Bs[(w * 96 + l * 8) * 64]);
            bptr[l] += 64;
        }
        __syncthreads();
        #pragma unroll
        for (int s = 0; s < 2; ++s) {
            bf16x8 afr, bfr[6];
            {
                int r = cl;
                int slot = (s * 4 + cq) ^ (r & 7);
                afr = *(const bf16x8*)&As[r * 64 + slot * 8];
            }
            #pragma unroll
            for (int nt = 0; nt < 6; ++nt) {
                int r = w * 96 + nt * 16 + cl;
                int slot = (s * 4 + cq) ^ (r & 7);
                bfr[nt] = *(const bf16x8*)&Bs[r * 64 + slot * 8];
            }
            #pragma unroll
            for (int nt = 0; nt < 6; ++nt)
                acc[nt] = __builtin_amdgcn_mfma_f32_16x16x32_bf16(
                    afr, bfr[nt], acc[nt], 0, 0, 0);
        }
        __syncthreads();
    }

    // ---- epilogue: y = acc + bias + resid -> LDS (16 x 388 f32) ----
    float* yb = (float*)smem;
    #pragma unroll
    for (int nt = 0; nt < 6; ++nt) {
        int col = w * 96 + nt * 16 + cl;
        float bb = bias[col];
        #pragma unroll
        for (int rg = 0; rg < 4; ++rg) {
            int rloc = cq * 4 + rg;
            yb[rloc * 388 + col] =
                acc[nt][rg] + bb + resid[(size_t)(m0 + rloc) * 384 + col];
        }
    }
    __syncthreads();

    // ---- LayerNorm: 16 threads per row ----
    int rloc = tid >> 4, sub = tid & 15;
    f32x4 vals[6];
    float s = 0.f, s2 = 0.f;
    #pragma unroll
    for (int m = 0; m < 6; ++m) {
        f32x4 vv = *(const f32x4*)&yb[rloc * 388 + m * 64 + sub * 4];
        vals[m] = vv;
        #pragma unroll
        for (int j = 0; j < 4; ++j) {
            s += vv[j];
            s2 = fmaf(vv[j], vv[j], s2);
        }
    }
    s += __shfl_xor(s, 1, 64);  s2 += __shfl_xor(s2, 1, 64);
    s += __shfl_xor(s, 2, 64);  s2 += __shfl_xor(s2, 2, 64);
    s += __shfl_xor(s, 4, 64);  s2 += __shfl_xor(s2, 4, 64);
    s += __shfl_xor(s, 8, 64);  s2 += __shfl_xor(s2, 8, 64);
    float mean = s * (1.f / 384.f);
    float var = s2 * (1.f / 384.f) - mean * mean;
    float inv = rsqrtf(var + 1e-5f);

    size_t ro = (size_t)(m0 + rloc) * 384;
    #pragma unroll
    for (int m = 0; m < 6; ++m) {
        int c0 = m * 64 + sub * 4;
        f32x4 gg = *(const f32x4*)&g[c0];
        f32x4 bb = *(const f32x4*)&be[c0];
        f32x4 ov;
        s16x4 ob2;
        #pragma unroll
        for (int j = 0; j < 4; ++j) {
            float v = (vals[m][j] - mean) * inv * gg[j] + bb[j];
            ov[j] = v;
            ob2[j] = f2bf(v);
        }
        *(f32x4*)&t[ro + c0] = ov;
        *(s16x4*)&tb[ro + c0] = ob2;
    }
}

// ---------------- fused attention per (n,h): split-E x2, 256 threads -------
__global__ __launch_bounds__(256) void attn_kernel(
    const short* __restrict__ qkv, short* __restrict__ o)
{
    __shared__ f32x4 Ks[128][12];
    __shared__ f32x4 Vs[128][12];
    int tid = threadIdx.x;
    int n = blockIdx.x >> 3, h = blockIdx.x & 7;
    size_t base = (size_t)n * 128 * 1152 + (size_t)h * 48;
    const short* kp = qkv + base + 384;
    const short* vp = qkv + base + 768;
    for (int i = tid; i < 1536; i += 256) {
        int s = i / 12, e4 = i - s * 12;
        s16x4 kv = *(const s16x4*)(kp + (size_t)s * 1152 + e4 * 4);
        s16x4 vv = *(const s16x4*)(vp + (size_t)s * 1152 + e4 * 4);
        f32x4 kf, vf;
        #pragma unroll
        for (int j = 0; j < 4; ++j) { kf[j] = bf2f(kv[j]); vf[j] = bf2f(vv[j]); }
        Ks[s][e4] = kf;
        Vs[s][e4] = vf;
    }
    const float temp = 0.14433756729740643f;  // 1/sqrt(48)
    int r = tid >> 1;
    int h2 = tid & 1;
    int eb0 = h2 * 6;
    float qr[24];
    {
        const short* qp = qkv + base + (size_t)r * 1152 + h2 * 24;
        #pragma unroll
        for (int e4 = 0; e4 < 6; ++e4) {
            s16x4 qv = *(const s16x4*)(qp + e4 * 4);
            #pragma unroll
            for (int j = 0; j < 4; ++j) qr[e4 * 4 + j] = bf2f(qv[j]) * temp;
        }
    }
    __syncthreads();

    float m = -1e30f, denom = 0.f;
    f32x4 acc[6];
    #pragma unroll
    for (int e = 0; e < 6; ++e) acc[e] = (f32x4){0.f, 0.f, 0.f, 0.f};

    for (int s0 = 0; s0 < 128; s0 += 8) {
        float sc[8];
        #pragma unroll
        for (int u = 0; u < 8; ++u) {
            float t0 = 0.f;
            #pragma unroll
            for (int e = 0; e < 6; ++e) {
                f32x4 kk = Ks[s0 + u][eb0 + e];
                t0 = fmaf(qr[e * 4 + 0], kk[0], t0);
                t0 = fmaf(qr[e * 4 + 1], kk[1], t0);
                t0 = fmaf(qr[e * 4 + 2], kk[2], t0);
                t0 = fmaf(qr[e * 4 + 3], kk[3], t0);
            }
            sc[u] = t0 + __shfl_xor(t0, 1, 64);
        }
        float cmax = sc[0];
        #pragma unroll
        for (int u = 1; u < 8; ++u) cmax = fmaxf(cmax, sc[u]);
        float nm = fmaxf(m, cmax);
        float alpha = __expf(m - nm);
        m = nm;
        float p[8];
        float ps = 0.f;
        #pragma unroll
        for (int u = 0; u < 8; ++u) { p[u] = __expf(sc[u] - nm); ps += p[u]; }
        denom = denom * alpha + ps;
        #pragma unroll
        for (int e = 0; e < 6; ++e) {
            f32x4 a = acc[e];
            a[0] *= alpha; a[1] *= alpha; a[2] *= alpha; a[3] *= alpha;
            #pragma unroll
            for (int u = 0; u < 8; ++u) {
                f32x4 vv = Vs[s0 + u][eb0 + e];
                a[0] = fmaf(p[u], vv[0], a[0]);
                a[1] = fmaf(p[u], vv[1], a[1]);
                a[2] = fmaf(p[u], vv[2], a[2]);
                a[3] = fmaf(p[u], vv[3], a[3]);
            }
            acc[e] = a;
        }
    }
    float inv = 1.f / denom;
    short* op = o + ((size_t)n * 128 + r) * 384 + h * 48 + h2 * 24;
    #pragma unroll
    for (int e = 0; e < 6; ++e) {
        s16x4 ov;
        #pragma unroll
        for (int j = 0; j < 4; ++j) ov[j] = f2bf(acc[e][j] * inv);
        *(s16x4*)(op + e * 4) = ov;
    }
}

// ---------------- classifier head ------------------------------------------
__global__ __launch_bounds__(384) void head_kernel(
    const float* __restrict__ t, const float* __restrict__ cls_w,
    const float* __restrict__ cls_b, float* __restrict__ out)
{
    int n = blockIdx.x, d = threadIdx.x;
    float s = 0.f;
    for (int l = 0; l < 128; ++l) s += t[((size_t)n * 128 + l) * 384 + d];
    float p = s * (1.f / 128.f) * cls_w[d];
    #pragma unroll
    for (int off = 32; off > 0; off >>= 1) p += __shfl_xor(p, off, 64);
    __shared__ float red[6];
    if ((threadIdx.x & 63) == 0) red[threadIdx.x >> 6] = p;
    __syncthreads();
    if (threadIdx.x == 0) {
        float tot = red[0] + red[1] + red[2] + red[3] + red[4] + red[5];
        out[n] = tot + cls_b[0];
    }
}

// ---------------------------------------------------------------------------
extern "C" void kernel_launch(void* const* d_in, const int* in_sizes, int n_in,
                              void* d_out, int out_size, void* d_ws, size_t ws_size,
                              hipStream_t stream) {
    (void)n_in; (void)out_size; (void)ws_size;
    const float* x   = (const float*)d_in[0];
    const float* cw0 = (const float*)d_in[1];
    const float* cb0 = (const float*)d_in[2];
    const float* cw1 = (const float*)d_in[3];
    const float* cb1 = (const float*)d_in[4];
    const float* cw2 = (const float*)d_in[5];
    const float* cb2 = (const float*)d_in[6];
    const float* ew  = (const float*)d_in[7];
    const float* eb  = (const float*)d_in[8];
    bool dict_order = (in_sizes[10] == 589824);
    const float *Wq, *Wk, *Wv, *Wo, *W1, *W2, *bq, *bk, *bv, *bo, *b1, *b2;
    if (dict_order) {
        Wq = (const float*)d_in[9];  Wk = (const float*)d_in[10];
        Wv = (const float*)d_in[11]; Wo = (const float*)d_in[12];
        W1 = (const float*)d_in[13]; W2 = (const float*)d_in[14];
        bq = (const float*)d_in[15]; bk = (const float*)d_in[16];
        bv = (const float*)d_in[17]; bo = (const float*)d_in[18];
        b1 = (const float*)d_in[19]; b2 = (const float*)d_in[20];
    } else {
        Wq = (const float*)d_in[9];  bq = (const float*)d_in[10];
        Wk = (const float*)d_in[11]; bk = (const float*)d_in[12];
        Wv = (const float*)d_in[13]; bv = (const float*)d_in[14];
        Wo = (const float*)d_in[15]; bo = (const float*)d_in[16];
        W1 = (const float*)d_in[17]; b1 = (const float*)d_in[18];
        W2 = (const float*)d_in[19]; b2 = (const float*)d_in[20];
    }
    const float* g1  = (const float*)d_in[21];
    const float* be1 = (const float*)d_in[22];
    const float* g2  = (const float*)d_in[23];
    const float* be2 = (const float*)d_in[24];
    const float* clw = (const float*)d_in[25];
    const float* clb = (const float*)d_in[26];

    // ---- workspace layout (bytes) ----
    char* wp = (char*)d_ws;
    float* pe    = (float*)wp; wp += 196608;      // 128*384 f32
    short* featb = (short*)wp; wp += 33554432;    // 8192*2048 bf16 (reused as FFN hidden)
    float* t     = (float*)wp; wp += 12582912;    // 8192*384 f32
    short* tb    = (short*)wp; wp += 6291456;     // 8192*384 bf16
    short* qkvb  = (short*)wp; wp += 18874368;    // 8192*1152 bf16
    short* ob    = (short*)wp; wp += 6291456;     // 8192*384 bf16 (attn out)
    short* ewT   = (short*)wp; wp += 1572864;     // 384 x 2048
    short* WqkvT = (short*)wp; wp += 3538944;     // 4 x 1152 x 384
    short* WoT   = (short*)wp; wp += 1179648;     // 4 x 384 x 384
    short* W1T   = (short*)wp; wp += 4718592;     // 4 x 1536 x 384
    short* W2T   = (short*)wp; wp += 4718592;     // 4 x 384 x 1536
    float* bqkv  = (float*)wp; wp += 18432;       // 4 x 1152 f32
    short* w2T   = (short*)wp; wp += 16384;       // 64 x 128 bf16 (conv2, paired-shift layout)
    short* hb    = featb;                         // FFN hidden 8192*1536 bf16

    const int ROWS = 8192;

    pe_kernel<<<128, 384, 0, stream>>>(pe);
    wcvt_kernel<<<dim3(64, 12, 1), 256, 0, stream>>>(ew, ewT, 2048, 384, 0, 0, 0);
    qkvcvt_kernel<<<dim3(12, 12, 12), 256, 0, stream>>>(Wq, Wk, Wv, WqkvT);
    wcvt_kernel<<<dim3(12, 12, 4), 256, 0, stream>>>(Wo, WoT, 384, 384, 0, 147456, 147456);
    wcvt_kernel<<<dim3(12, 48, 4), 256, 0, stream>>>(W1, W1T, 384, 1536, 0, 589824, 589824);
    wcvt_kernel<<<dim3(48, 12, 4), 256, 0, stream>>>(W2, W2T, 1536, 384, 0, 589824, 589824);
    biascat_kernel<<<4, 384, 0, stream>>>(bq, bk, bv, bqkv);
    w2cvt_kernel<<<32, 256, 0, stream>>>(cw2, w2T);
    cnn_kernel<<<4096, 256, 0, stream>>>(x, cw0, cb0, cw1, cb1, w2T, cb2, featb);

    // t/tb = relu(feat @ ew + eb) + pe
    gemm_bf16<29><<<dim3(6, 64), 256, 0, stream>>>(featb, ewT, eb, nullptr, pe,
                                                   t, tb, ROWS, 384, 2048);
    for (int i = 0; i < 4; ++i) {
        const short* WqkvTi = WqkvT + (size_t)i * 442368;
        const short* WoTi = WoT + (size_t)i * 147456;
        const short* W1Ti = W1T + (size_t)i * 589824;
        const short* W2Ti = W2T + (size_t)i * 589824;
        gemm_bf16_wide<16><<<dim3(9, 64), 256, 0, stream>>>(tb, WqkvTi,
            bqkv + i * 1152, nullptr, qkvb, ROWS, 1152, 384);
        attn_kernel<<<512, 256, 0, stream>>>(qkvb, ob);
        // t/tb = LN(o @ Wo + bo + t)
        gemm_ln<<<512, 256, 0, stream>>>(ob, WoTi, bo + i * 384, t,
            g1 + i * 384, be1 + i * 384, t, tb, 384);
        // hidden = relu(t @ W1 + b1)
        gemm_bf16_wide<17><<<dim3(12, 64), 256, 0, stream>>>(tb, W1Ti,
            b1 + i * 1536, nullptr, hb, ROWS, 1536, 384);
        // t/tb = LN(hidden @ W2 + b2 + t)
        gemm_ln<<<512, 256, 0, stream>>>(hb, W2Ti, b2 + i * 384, t,
            g2 + i * 384, be2 + i * 384, t, tb, 1536);
    }
    head_kernel<<<64, 384, 0, stream>>>(t, clw, clb, (float*)d_out);
}

// Round 3
// 742.487 us; speedup vs baseline: 1.0720x; 1.0720x over previous
//
#include <hip/hip_runtime.h>
#include <math.h>

// ---------------------------------------------------------------------------
// N=64, L=128, W=256, D=384, H=8, E=48, NL=4, DFF=1536, rows = N*L = 8192
// GEMMs: bf16 MFMA 16x16x32, A [M][K] bf16 row-major, Bt [N][K] bf16.
// R20 = R19 (conv2 as paired-shift GEMMs on transposed p1T, no im2col,
// 4 barriers) with the occupancy bound relaxed to (256,4).
// Post-mortem R19: __launch_bounds__(256,8) made the allocator honor the
// 64-VGPR cap by SPILLING (VGPR=32, WRITE_SIZE 32MB->241MB, FETCH
// 4.3MB->110MB = scratch traffic, dur 99.5->118us despite occupancy 77%).
// Occupancy was never the lever; cap at 128 VGPR (4 waves/EU) -> no spill.
// ---------------------------------------------------------------------------

typedef float f32x4 __attribute__((ext_vector_type(4)));
typedef short bf16x8 __attribute__((ext_vector_type(8)));
typedef short s16x4 __attribute__((ext_vector_type(4)));

__device__ __forceinline__ short f2bf(float f) {
    union { float f; unsigned u; } c; c.f = f;
    unsigned r = (c.u + 0x7FFFu + ((c.u >> 16) & 1u)) >> 16;
    return (short)r;
}
__device__ __forceinline__ float bf2f(short s) {
    union { unsigned u; float f; } c;
    c.u = ((unsigned)(unsigned short)s) << 16;
    return c.f;
}

__device__ __forceinline__ void gload_lds16(const void* g, void* l) {
    __builtin_amdgcn_global_load_lds(
        (const __attribute__((address_space(1))) unsigned int*)g,
        (__attribute__((address_space(3))) unsigned int*)l,
        16, 0, 0);
}

// ---------------- positional encoding table: pe[l][d] ----------------------
__global__ __launch_bounds__(384) void pe_kernel(float* __restrict__ pe) {
    int l = blockIdx.x, d = threadIdx.x;
    int i2 = d >> 1;
    float ang = (float)l * expf(-(2.0f * (float)i2 / 384.0f) * 9.210340371976184f);
    pe[l * 384 + d] = (d & 1) ? cosf(ang) : sinf(ang);
}

// ---------------- weight convert+transpose: W fp32 [K][N] -> bf16 [N][K] ---
__global__ __launch_bounds__(256) void wcvt_kernel(
    const float* __restrict__ W, short* __restrict__ Wt, int K, int N,
    int dstOff, int srcZ, int dstZ)
{
    __shared__ float tile[32][33];
    int kb = blockIdx.x * 32, nb = blockIdx.y * 32;
    const float* Wp = W + (size_t)blockIdx.z * srcZ;
    short* Wtp = Wt + (size_t)blockIdx.z * dstZ + dstOff;
    int tx = threadIdx.x & 31, ty = threadIdx.x >> 5;
    #pragma unroll
    for (int r = ty; r < 32; r += 8)
        tile[r][tx] = Wp[(size_t)(kb + r) * N + nb + tx];
    __syncthreads();
    #pragma unroll
    for (int r = ty; r < 32; r += 8)
        Wtp[(size_t)(nb + r) * K + kb + tx] = f2bf(tile[tx][r]);
}

// ---------------- Wq/Wk/Wv -> WqkvT in one dispatch (z = layer*3+which) ----
__global__ __launch_bounds__(256) void qkvcvt_kernel(
    const float* __restrict__ Wq, const float* __restrict__ Wk,
    const float* __restrict__ Wv, short* __restrict__ WqkvT)
{
    __shared__ float tile[32][33];
    int kb = blockIdx.x * 32, nb = blockIdx.y * 32;
    int layer = blockIdx.z / 3, which = blockIdx.z - layer * 3;
    const float* Wp = (which == 0 ? Wq : (which == 1 ? Wk : Wv)) +
                      (size_t)layer * 147456;
    short* Wtp = WqkvT + (size_t)layer * 442368 + (size_t)which * 147456;
    int tx = threadIdx.x & 31, ty = threadIdx.x >> 5;
    #pragma unroll
    for (int r = ty; r < 32; r += 8)
        tile[r][tx] = Wp[(size_t)(kb + r) * 384 + nb + tx];
    __syncthreads();
    #pragma unroll
    for (int r = ty; r < 32; r += 8)
        Wtp[(size_t)(nb + r) * 384 + kb + tx] = f2bf(tile[tx][r]);
}

// ---------------- conv2 weights -> paired-shift layout [64][128] -----------
// w2p[c][pr*32 + q*8 + j] = w2[c][ci*7 + sft], ci=(q&1)*8+j, sft=2*pr+(q>>1);
// sft==7 (pair 3, upper half) -> 0. Matches stage-C A-fragment reads.
__global__ __launch_bounds__(256) void w2cvt_kernel(
    const float* __restrict__ w2, short* __restrict__ w2T)
{
    int idx = blockIdx.x * 256 + threadIdx.x;   // 64*128 = 8192
    int c = idx >> 7, r = idx & 127;
    int pr = r >> 5, q = (r >> 3) & 3, j = r & 7;
    int ci = (q & 1) * 8 + j;
    int sft = 2 * pr + (q >> 1);
    w2T[idx] = (sft < 7) ? f2bf(w2[c * 112 + ci * 7 + sft]) : (short)0;
}

// ---------------- concatenated qkv bias: bqkv[l][1152] ---------------------
__global__ __launch_bounds__(384) void biascat_kernel(
    const float* __restrict__ bq, const float* __restrict__ bk,
    const float* __restrict__ bv, float* __restrict__ bqkv)
{
    int l = blockIdx.x, j = threadIdx.x;
    bqkv[l * 1152 + j] = bq[l * 384 + j];
    bqkv[l * 1152 + 384 + j] = bk[l * 384 + j];
    bqkv[l * 1152 + 768 + j] = bv[l * 384 + j];
}

// ---------------- fused CNN window encoder: 2 windows per block ------------
// LDS layout (15232 B total):
//   [0     .. 2048)   xs[2][256] f32
//   [2048  .. 6400)   p0[2][4][136] f32
//   [6400  .. 8192)   w1s[64][7] f32
//   [8192  .. 8304)   w0s[4*7] f32
//   [8320  .. 15232)  p1T[2][72][24] bf16  (row = pos+3; rows 0-2 & 67-71
//                     zeroed; only cols 0-15 used, stride 24 for banks)
__global__ __launch_bounds__(256, 4) void cnn_kernel(
    const float* __restrict__ x,
    const float* __restrict__ w0, const float* __restrict__ b0,
    const float* __restrict__ w1, const float* __restrict__ b1,
    const short* __restrict__ w2T, const float* __restrict__ b2,
    short* __restrict__ feat)
{
    __shared__ __align__(16) char smem[15232];
    float* xs = (float*)smem;                         // [2][256]
    float* p0 = (float*)(smem + 2048);                // [2][4][136]
    float (*w1s)[7] = (float(*)[7])(smem + 6400);     // [64][7]
    float* w0s = (float*)(smem + 8192);               // [4*7]
    short* p1T = (short*)(smem + 8320);               // [2][72][24]

    int tid = threadIdx.x;
    size_t win0 = (size_t)blockIdx.x * 2;
    int w = tid >> 6, lane = tid & 63;
    int cq = lane >> 4, cl = lane & 15;

    xs[tid] = x[win0 * 256 + tid];
    xs[256 + tid] = x[(win0 + 1) * 256 + tid];
    if (tid < 28) w0s[tid] = w0[tid];
    if (tid < 64) {
        for (int k = 0; k < 7; ++k) w1s[tid][k] = w1[tid * 7 + k];
    }
    // zero p1T (covers the boundary pad rows; interior overwritten in B)
    {
        int* pz = (int*)p1T;
        #pragma unroll
        for (int i = tid; i < 1728; i += 256) pz[i] = 0;
    }
    __syncthreads();

    // ---- stage A: conv0 (1->4) + relu + pool2 -> p0[wv][4][128] ----
    #pragma unroll
    for (int wv = 0; wv < 2; ++wv) {
        int c = tid & 3, p = tid >> 2;
        float bb = b0[c];
        #pragma unroll
        for (int t2 = 0; t2 < 2; ++t2) {
            int pp = p + 64 * t2;
            float rv[9];
            #pragma unroll
            for (int u = 0; u < 9; ++u) {
                int j = 2 * pp + u - 3;
                rv[u] = (j >= 0 && j < 256) ? xs[wv * 256 + j] : 0.f;
            }
            float a0 = bb, a1 = bb;
            #pragma unroll
            for (int k = 0; k < 7; ++k) {
                float ww = w0s[c * 7 + k];
                a0 = fmaf(ww, rv[k], a0);
                a1 = fmaf(ww, rv[k + 1], a1);
            }
            p0[(wv * 4 + c) * 136 + pp] = fmaxf(fmaxf(a0, a1), 0.f);
        }
    }
    __syncthreads();

    // ---- stage B: conv1 (4->16) + relu + pool2 -> p1T[wv][3+pos][c] ----
    #pragma unroll
    for (int wv = 0; wv < 2; ++wv) {
        int c = tid & 15;
        int i0 = (tid >> 4) * 8;
        float acc[8];
        float bb = b1[c];
        #pragma unroll
        for (int m = 0; m < 8; ++m) acc[m] = bb;
        #pragma unroll
        for (int ci = 0; ci < 4; ++ci) {
            float rv[14];
            #pragma unroll
            for (int u = 0; u < 14; ++u) {
                int j = i0 + u - 3;
                rv[u] = (j >= 0 && j < 128) ? p0[(wv * 4 + ci) * 136 + j] : 0.f;
            }
            #pragma unroll
            for (int k = 0; k < 7; ++k) {
                float ww = w1s[c * 4 + ci][k];
                #pragma unroll
                for (int m = 0; m < 8; ++m) acc[m] = fmaf(ww, rv[m + k], acc[m]);
            }
        }
        int po = i0 >> 1;
        #pragma unroll
        for (int m = 0; m < 4; ++m)
            p1T[wv * 1728 + (3 + po + m) * 24 + c] =
                f2bf(fmaxf(fmaxf(acc[2 * m], acc[2 * m + 1]), 0.f));
    }
    __syncthreads();

    // ---- stage C: conv2 as 4 paired-shift GEMMs on p1T (no im2col) ----
    // MFMA K=32 = {shift 2pr (q=0,1: ci 0-7,8-15), shift 2pr+1 (q=2,3)}.
    // B-fragment: lane(q,n) reads p1T[w*16+n + (q>>1) + 2pr][(q&1)*8..+7].
    f32x4 acc0[4], acc1[4];
    #pragma unroll
    for (int mt = 0; mt < 4; ++mt) {
        acc0[mt] = (f32x4){0.f, 0.f, 0.f, 0.f};
        acc1[mt] = (f32x4){0.f, 0.f, 0.f, 0.f};
    }
    {
        const short* bp0 = p1T + (w * 16 + cl + (cq >> 1)) * 24 + (cq & 1) * 8;
        const short* bp1 = bp0 + 1728;
        #pragma unroll
        for (int pr = 0; pr < 4; ++pr) {
            bf16x8 bfr0 = *(const bf16x8*)&bp0[pr * 48];
            bf16x8 bfr1 = *(const bf16x8*)&bp1[pr * 48];
            #pragma unroll
            for (int mt = 0; mt < 4; ++mt) {
                bf16x8 af = *(const bf16x8*)&w2T[(mt * 16 + cl) * 128 +
                                                 pr * 32 + cq * 8];
                acc0[mt] = __builtin_amdgcn_mfma_f32_16x16x32_bf16(
                    af, bfr0, acc0[mt], 0, 0, 0);
                acc1[mt] = __builtin_amdgcn_mfma_f32_16x16x32_bf16(
                    af, bfr1, acc1[mt], 0, 0, 0);
            }
        }
    }

    // ---- epilogue: pool pairs via shfl, store bf16 ----
    #pragma unroll
    for (int wv = 0; wv < 2; ++wv) {
        short* fp = feat + (win0 + wv) * 2048;
        int iev = (w * 16 + cl) >> 1;
        #pragma unroll
        for (int mt = 0; mt < 4; ++mt) {
            #pragma unroll
            for (int rg = 0; rg < 4; ++rg) {
                float v = wv ? acc1[mt][rg] : acc0[mt][rg];
                float v2 = __shfl_xor(v, 1, 64);
                if ((cl & 1) == 0) {
                    int c = mt * 16 + cq * 4 + rg;
                    float pv = fmaxf(fmaxf(v, v2) + b2[c], 0.f);
                    fp[c * 32 + iev] = f2bf(pv);
                }
            }
        }
    }
}

// ---------------- bf16 MFMA GEMM (thin-N): BM=128, BN=64, double-buffered --
// EPI bits: 1=relu, 2=+resid(f32), 4=+pe, 8=write f32, 16=write bf16
template <int EPI>
__global__ __launch_bounds__(256) void gemm_bf16(
    const short* __restrict__ A, const short* __restrict__ Bt,
    const float* __restrict__ bias, const float* __restrict__ resid,
    const float* __restrict__ pe, float* __restrict__ outF,
    short* __restrict__ outB, int M, int N, int K)
{
    __shared__ short As[2][128 * 64];
    __shared__ short Bs[2][64 * 64];
    int tid = threadIdx.x;
    int w = tid >> 6, lane = tid & 63;
    int wm = w >> 1, wn = w & 1;
    int m0 = blockIdx.y * 128, n0 = blockIdx.x * 64;

    int rl = lane >> 3, sl = lane & 7;
    int cb = sl ^ rl;
    const short* aptr[4];
    const short* bptr[2];
    int arow[4], brow[2];
    #pragma unroll
    for (int l = 0; l < 4; ++l) {
        arow[l] = l * 32 + w * 8;
        aptr[l] = A + (size_t)(m0 + arow[l] + rl) * K + cb * 8;
    }
    #pragma unroll
    for (int l = 0; l < 2; ++l) {
        brow[l] = l * 32 + w * 8;
        bptr[l] = Bt + (size_t)(n0 + brow[l] + rl) * K + cb * 8;
    }

    int cq = lane >> 4, cl = lane & 15;
    f32x4 acc[4][2];
    #pragma unroll
    for (int mt = 0; mt < 4; ++mt)
        #pragma unroll
        for (int nt = 0; nt < 2; ++nt)
            acc[mt][nt] = (f32x4){0.f, 0.f, 0.f, 0.f};

    #pragma unroll
    for (int l = 0; l < 4; ++l) { gload_lds16(aptr[l], &As[0][arow[l] * 64]); aptr[l] += 64; }
    #pragma unroll
    for (int l = 0; l < 2; ++l) { gload_lds16(bptr[l], &Bs[0][brow[l] * 64]); bptr[l] += 64; }
    __syncthreads();

    int nk = K >> 6;
    for (int k = 0; k < nk; ++k) {
        int cur = k & 1;
        if (k + 1 < nk) {
            #pragma unroll
            for (int l = 0; l < 4; ++l) { gload_lds16(aptr[l], &As[cur ^ 1][arow[l] * 64]); aptr[l] += 64; }
            #pragma unroll
            for (int l = 0; l < 2; ++l) { gload_lds16(bptr[l], &Bs[cur ^ 1][brow[l] * 64]); bptr[l] += 64; }
        }
        #pragma unroll
        for (int s = 0; s < 2; ++s) {
            bf16x8 afr[4], bfr[2];
            #pragma unroll
            for (int mt = 0; mt < 4; ++mt) {
                int r = wm * 64 + mt * 16 + cl;
                int slot = (s * 4 + cq) ^ (r & 7);
                afr[mt] = *(const bf16x8*)&As[cur][r * 64 + slot * 8];
            }
            #pragma unroll
            for (int nt = 0; nt < 2; ++nt) {
                int r = wn * 32 + nt * 16 + cl;
                int slot = (s * 4 + cq) ^ (r & 7);
                bfr[nt] = *(const bf16x8*)&Bs[cur][r * 64 + slot * 8];
            }
            #pragma unroll
            for (int mt = 0; mt < 4; ++mt)
                #pragma unroll
                for (int nt = 0; nt < 2; ++nt)
                    acc[mt][nt] = __builtin_amdgcn_mfma_f32_16x16x32_bf16(
                        afr[mt], bfr[nt], acc[mt][nt], 0, 0, 0);
        }
        __syncthreads();
    }

    #pragma unroll
    for (int mt = 0; mt < 4; ++mt) {
        #pragma unroll
        for (int nt = 0; nt < 2; ++nt) {
            int col = n0 + wn * 32 + nt * 16 + cl;
            float bb = bias[col];
            #pragma unroll
            for (int rg = 0; rg < 4; ++rg) {
                int row = m0 + wm * 64 + mt * 16 + cq * 4 + rg;
                float v = acc[mt][nt][rg] + bb;
                if (EPI & 1) v = fmaxf(v, 0.f);
                if (EPI & 4) v += pe[(row & 127) * 384 + col];
                if (EPI & 2) v += resid[(size_t)row * N + col];
                if (EPI & 8) outF[(size_t)row * N + col] = v;
                if (EPI & 16) outB[(size_t)row * N + col] = f2bf(v);
            }
        }
    }
}

// ---------------- bf16 MFMA GEMM (wide-N): BM=128, BN=128, BK=32 dbuf ------
template <int EPI>
__global__ __launch_bounds__(256) void gemm_bf16_wide(
    const short* __restrict__ A, const short* __restrict__ Bt,
    const float* __restrict__ bias, float* __restrict__ outF,
    short* __restrict__ outB, int M, int N, int K)
{
    __shared__ short As[2][128 * 32];
    __shared__ short Bs[2][128 * 32];
    int tid = threadIdx.x;
    int w = tid >> 6, lane = tid & 63;
    int wm = w >> 1, wn = w & 1;
    int m0 = blockIdx.y * 128, n0 = blockIdx.x * 128;

    int rl = lane >> 2, sl = lane & 3;
    int cb = sl ^ (rl & 3) ^ ((rl >> 2) & 3);
    const short* aptr[2];
    const short* bptr[2];
    int srow[2];
    #pragma unroll
    for (int l = 0; l < 2; ++l) {
        srow[l] = w * 32 + l * 16;
        aptr[l] = A + (size_t)(m0 + srow[l] + rl) * K + cb * 8;
        bptr[l] = Bt + (size_t)(n0 + srow[l] + rl) * K + cb * 8;
    }

    int cq = lane >> 4, cl = lane & 15;
    f32x4 acc[4][4];
    #pragma unroll
    for (int mt = 0; mt < 4; ++mt)
        #pragma unroll
        for (int nt = 0; nt < 4; ++nt)
            acc[mt][nt] = (f32x4){0.f, 0.f, 0.f, 0.f};

    #pragma unroll
    for (int l = 0; l < 2; ++l) {
        gload_lds16(aptr[l], &As[0][srow[l] * 32]);
        gload_lds16(bptr[l], &Bs[0][srow[l] * 32]);
        aptr[l] += 32; bptr[l] += 32;
    }
    __syncthreads();

    int nk = K >> 5;
    for (int k = 0; k < nk; ++k) {
        int cur = k & 1;
        if (k + 1 < nk) {
            #pragma unroll
            for (int l = 0; l < 2; ++l) {
                gload_lds16(aptr[l], &As[cur ^ 1][srow[l] * 32]);
                gload_lds16(bptr[l], &Bs[cur ^ 1][srow[l] * 32]);
                aptr[l] += 32; bptr[l] += 32;
            }
        }
        bf16x8 afr[4], bfr[4];
        #pragma unroll
        for (int mt = 0; mt < 4; ++mt) {
            int r = wm * 64 + mt * 16 + cl;
            int slot = cq ^ (r & 3) ^ ((r >> 2) & 3);
            afr[mt] = *(const bf16x8*)&As[cur][r * 32 + slot * 8];
        }
        #pragma unroll
        for (int nt = 0; nt < 4; ++nt) {
            int r = wn * 64 + nt * 16 + cl;
            int slot = cq ^ (r & 3) ^ ((r >> 2) & 3);
            bfr[nt] = *(const bf16x8*)&Bs[cur][r * 32 + slot * 8];
        }
        #pragma unroll
        for (int mt = 0; mt < 4; ++mt)
            #pragma unroll
            for (int nt = 0; nt < 4; ++nt)
                acc[mt][nt] = __builtin_amdgcn_mfma_f32_16x16x32_bf16(
                    afr[mt], bfr[nt], acc[mt][nt], 0, 0, 0);
        __syncthreads();
    }

    #pragma unroll
    for (int mt = 0; mt < 4; ++mt) {
        #pragma unroll
        for (int nt = 0; nt < 4; ++nt) {
            int col = n0 + wn * 64 + nt * 16 + cl;
            float bb = bias[col];
            #pragma unroll
            for (int rg = 0; rg < 4; ++rg) {
                int row = m0 + wm * 64 + mt * 16 + cq * 4 + rg;
                float v = acc[mt][nt][rg] + bb;
                if (EPI & 1) v = fmaxf(v, 0.f);
                if (EPI & 8) outF[(size_t)row * N + col] = v;
                if (EPI & 16) outB[(size_t)row * N + col] = f2bf(v);
            }
        }
    }
}

// ---------------- fused GEMM + bias + residual + LayerNorm -----------------
// BM=16, BN=384, BK=64 -> grid 512. (BK=32 regressed in R13.)
__global__ __launch_bounds__(256) void gemm_ln(
    const short* __restrict__ A, const short* __restrict__ Bt,
    const float* __restrict__ bias, const float* resid,
    const float* __restrict__ g, const float* __restrict__ be,
    float* t, short* __restrict__ tb, int K)
{
    __shared__ __align__(16) char smem[51200];
    short* As = (short*)smem;              // 16 x 64 bf16 = 2 KB
    short* Bs = (short*)(smem + 2048);     // 384 x 64 bf16 = 48 KB

    int tid = threadIdx.x;
    int w = tid >> 6, lane = tid & 63;
    int m0 = blockIdx.x * 16;
    int rl = lane >> 3, sl = lane & 7;
    int cb = sl ^ rl;

    const short* aptr = A + (size_t)(m0 + w * 8 + rl) * K + cb * 8;
    const short* bptr[12];
    #pragma unroll
    for (int l = 0; l < 12; ++l)
        bptr[l] = Bt + (size_t)(w * 96 + l * 8 + rl) * K + cb * 8;

    int cq = lane >> 4, cl = lane & 15;
    f32x4 acc[6];
    #pragma unroll
    for (int nt = 0; nt < 6; ++nt) acc[nt] = (f32x4){0.f, 0.f, 0.f, 0.f};

    for (int k0 = 0; k0 < K; k0 += 64) {
        if (w < 2) {
            gload_lds16(aptr, &As[(w * 8) * 64]);
            aptr += 64;
        }
        #pragma unroll
        for (int l = 0; l < 12; ++l) {
            gload_lds16(bptr[l], &Bs[(w * 96 + l * 8) * 64]);
            bptr[l] += 64;
        }
        __syncthreads();
        #pragma unroll
        for (int s = 0; s < 2; ++s) {
            bf16x8 afr, bfr[6];
            {
                int r = cl;
                int slot = (s * 4 + cq) ^ (r & 7);
                afr = *(const bf16x8*)&As[r * 64 + slot * 8];
            }
            #pragma unroll
            for (int nt = 0; nt < 6; ++nt) {
                int r = w * 96 + nt * 16 + cl;
                int slot = (s * 4 + cq) ^ (r & 7);
                bfr[nt] = *(const bf16x8*)&Bs[r * 64 + slot * 8];
            }
            #pragma unroll
            for (int nt = 0; nt < 6; ++nt)
                acc[nt] = __builtin_amdgcn_mfma_f32_16x16x32_bf16(
                    afr, bfr[nt], acc[nt], 0, 0, 0);
        }
        __syncthreads();
    }

    // ---- epilogue: y = acc + bias + resid -> LDS (16 x 388 f32) ----
    float* yb = (float*)smem;
    #pragma unroll
    for (int nt = 0; nt < 6; ++nt) {
        int col = w * 96 + nt * 16 + cl;
        float bb = bias[col];
        #pragma unroll
        for (int rg = 0; rg < 4; ++rg) {
            int rloc = cq * 4 + rg;
            yb[rloc * 388 + col] =
                acc[nt][rg] + bb + resid[(size_t)(m0 + rloc) * 384 + col];
        }
    }
    __syncthreads();

    // ---- LayerNorm: 16 threads per row ----
    int rloc = tid >> 4, sub = tid & 15;
    f32x4 vals[6];
    float s = 0.f, s2 = 0.f;
    #pragma unroll
    for (int m = 0; m < 6; ++m) {
        f32x4 vv = *(const f32x4*)&yb[rloc * 388 + m * 64 + sub * 4];
        vals[m] = vv;
        #pragma unroll
        for (int j = 0; j < 4; ++j) {
            s += vv[j];
            s2 = fmaf(vv[j], vv[j], s2);
        }
    }
    s += __shfl_xor(s, 1, 64);  s2 += __shfl_xor(s2, 1, 64);
    s += __shfl_xor(s, 2, 64);  s2 += __shfl_xor(s2, 2, 64);
    s += __shfl_xor(s, 4, 64);  s2 += __shfl_xor(s2, 4, 64);
    s += __shfl_xor(s, 8, 64);  s2 += __shfl_xor(s2, 8, 64);
    float mean = s * (1.f / 384.f);
    float var = s2 * (1.f / 384.f) - mean * mean;
    float inv = rsqrtf(var + 1e-5f);

    size_t ro = (size_t)(m0 + rloc) * 384;
    #pragma unroll
    for (int m = 0; m < 6; ++m) {
        int c0 = m * 64 + sub * 4;
        f32x4 gg = *(const f32x4*)&g[c0];
        f32x4 bb = *(const f32x4*)&be[c0];
        f32x4 ov;
        s16x4 ob2;
        #pragma unroll
        for (int j = 0; j < 4; ++j) {
            float v = (vals[m][j] - mean) * inv * gg[j] + bb[j];
            ov[j] = v;
            ob2[j] = f2bf(v);
        }
        *(f32x4*)&t[ro + c0] = ov;
        *(s16x4*)&tb[ro + c0] = ob2;
    }
}

// ---------------- fused attention per (n,h): split-E x2, 256 threads -------
__global__ __launch_bounds__(256) void attn_kernel(
    const short* __restrict__ qkv, short* __restrict__ o)
{
    __shared__ f32x4 Ks[128][12];
    __shared__ f32x4 Vs[128][12];
    int tid = threadIdx.x;
    int n = blockIdx.x >> 3, h = blockIdx.x & 7;
    size_t base = (size_t)n * 128 * 1152 + (size_t)h * 48;
    const short* kp = qkv + base + 384;
    const short* vp = qkv + base + 768;
    for (int i = tid; i < 1536; i += 256) {
        int s = i / 12, e4 = i - s * 12;
        s16x4 kv = *(const s16x4*)(kp + (size_t)s * 1152 + e4 * 4);
        s16x4 vv = *(const s16x4*)(vp + (size_t)s * 1152 + e4 * 4);
        f32x4 kf, vf;
        #pragma unroll
        for (int j = 0; j < 4; ++j) { kf[j] = bf2f(kv[j]); vf[j] = bf2f(vv[j]); }
        Ks[s][e4] = kf;
        Vs[s][e4] = vf;
    }
    const float temp = 0.14433756729740643f;  // 1/sqrt(48)
    int r = tid >> 1;
    int h2 = tid & 1;
    int eb0 = h2 * 6;
    float qr[24];
    {
        const short* qp = qkv + base + (size_t)r * 1152 + h2 * 24;
        #pragma unroll
        for (int e4 = 0; e4 < 6; ++e4) {
            s16x4 qv = *(const s16x4*)(qp + e4 * 4);
            #pragma unroll
            for (int j = 0; j < 4; ++j) qr[e4 * 4 + j] = bf2f(qv[j]) * temp;
        }
    }
    __syncthreads();

    float m = -1e30f, denom = 0.f;
    f32x4 acc[6];
    #pragma unroll
    for (int e = 0; e < 6; ++e) acc[e] = (f32x4){0.f, 0.f, 0.f, 0.f};

    for (int s0 = 0; s0 < 128; s0 += 8) {
        float sc[8];
        #pragma unroll
        for (int u = 0; u < 8; ++u) {
            float t0 = 0.f;
            #pragma unroll
            for (int e = 0; e < 6; ++e) {
                f32x4 kk = Ks[s0 + u][eb0 + e];
                t0 = fmaf(qr[e * 4 + 0], kk[0], t0);
                t0 = fmaf(qr[e * 4 + 1], kk[1], t0);
                t0 = fmaf(qr[e * 4 + 2], kk[2], t0);
                t0 = fmaf(qr[e * 4 + 3], kk[3], t0);
            }
            sc[u] = t0 + __shfl_xor(t0, 1, 64);
        }
        float cmax = sc[0];
        #pragma unroll
        for (int u = 1; u < 8; ++u) cmax = fmaxf(cmax, sc[u]);
        float nm = fmaxf(m, cmax);
        float alpha = __expf(m - nm);
        m = nm;
        float p[8];
        float ps = 0.f;
        #pragma unroll
        for (int u = 0; u < 8; ++u) { p[u] = __expf(sc[u] - nm); ps += p[u]; }
        denom = denom * alpha + ps;
        #pragma unroll
        for (int e = 0; e < 6; ++e) {
            f32x4 a = acc[e];
            a[0] *= alpha; a[1] *= alpha; a[2] *= alpha; a[3] *= alpha;
            #pragma unroll
            for (int u = 0; u < 8; ++u) {
                f32x4 vv = Vs[s0 + u][eb0 + e];
                a[0] = fmaf(p[u], vv[0], a[0]);
                a[1] = fmaf(p[u], vv[1], a[1]);
                a[2] = fmaf(p[u], vv[2], a[2]);
                a[3] = fmaf(p[u], vv[3], a[3]);
            }
            acc[e] = a;
        }
    }
    float inv = 1.f / denom;
    short* op = o + ((size_t)n * 128 + r) * 384 + h * 48 + h2 * 24;
    #pragma unroll
    for (int e = 0; e < 6; ++e) {
        s16x4 ov;
        #pragma unroll
        for (int j = 0; j < 4; ++j) ov[j] = f2bf(acc[e][j] * inv);
        *(s16x4*)(op + e * 4) = ov;
    }
}

// ---------------- classifier head ------------------------------------------
__global__ __launch_bounds__(384) void head_kernel(
    const float* __restrict__ t, const float* __restrict__ cls_w,
    const float* __restrict__ cls_b, float* __restrict__ out)
{
    int n = blockIdx.x, d = threadIdx.x;
    float s = 0.f;
    for (int l = 0; l < 128; ++l) s += t[((size_t)n * 128 + l) * 384 + d];
    float p = s * (1.f / 128.f) * cls_w[d];
    #pragma unroll
    for (int off = 32; off > 0; off >>= 1) p += __shfl_xor(p, off, 64);
    __shared__ float red[6];
    if ((threadIdx.x & 63) == 0) red[threadIdx.x >> 6] = p;
    __syncthreads();
    if (threadIdx.x == 0) {
        float tot = red[0] + red[1] + red[2] + red[3] + red[4] + red[5];
        out[n] = tot + cls_b[0];
    }
}

// ---------------------------------------------------------------------------
extern "C" void kernel_launch(void* const* d_in, const int* in_sizes, int n_in,
                              void* d_out, int out_size, void* d_ws, size_t ws_size,
                              hipStream_t stream) {
    (void)n_in; (void)out_size; (void)ws_size;
    const float* x   = (const float*)d_in[0];
    const float* cw0 = (const float*)d_in[1];
    const float* cb0 = (const float*)d_in[2];
    const float* cw1 = (const float*)d_in[3];
    const float* cb1 = (const float*)d_in[4];
    const float* cw2 = (const float*)d_in[5];
    const float* cb2 = (const float*)d_in[6];
    const float* ew  = (const float*)d_in[7];
    const float* eb  = (const float*)d_in[8];
    bool dict_order = (in_sizes[10] == 589824);
    const float *Wq, *Wk, *Wv, *Wo, *W1, *W2, *bq, *bk, *bv, *bo, *b1, *b2;
    if (dict_order) {
        Wq = (const float*)d_in[9];  Wk = (const float*)d_in[10];
        Wv = (const float*)d_in[11]; Wo = (const float*)d_in[12];
        W1 = (const float*)d_in[13]; W2 = (const float*)d_in[14];
        bq = (const float*)d_in[15]; bk = (const float*)d_in[16];
        bv = (const float*)d_in[17]; bo = (const float*)d_in[18];
        b1 = (const float*)d_in[19]; b2 = (const float*)d_in[20];
    } else {
        Wq = (const float*)d_in[9];  bq = (const float*)d_in[10];
        Wk = (const float*)d_in[11]; bk = (const float*)d_in[12];
        Wv = (const float*)d_in[13]; bv = (const float*)d_in[14];
        Wo = (const float*)d_in[15]; bo = (const float*)d_in[16];
        W1 = (const float*)d_in[17]; b1 = (const float*)d_in[18];
        W2 = (const float*)d_in[19]; b2 = (const float*)d_in[20];
    }
    const float* g1  = (const float*)d_in[21];
    const float* be1 = (const float*)d_in[22];
    const float* g2  = (const float*)d_in[23];
    const float* be2 = (const float*)d_in[24];
    const float* clw = (const float*)d_in[25];
    const float* clb = (const float*)d_in[26];

    // ---- workspace layout (bytes) ----
    char* wp = (char*)d_ws;
    float* pe    = (float*)wp; wp += 196608;      // 128*384 f32
    short* featb = (short*)wp; wp += 33554432;    // 8192*2048 bf16 (reused as FFN hidden)
    float* t     = (float*)wp; wp += 12582912;    // 8192*384 f32
    short* tb    = (short*)wp; wp += 6291456;     // 8192*384 bf16
    short* qkvb  = (short*)wp; wp += 18874368;    // 8192*1152 bf16
    short* ob    = (short*)wp; wp += 6291456;     // 8192*384 bf16 (attn out)
    short* ewT   = (short*)wp; wp += 1572864;     // 384 x 2048
    short* WqkvT = (short*)wp; wp += 3538944;     // 4 x 1152 x 384
    short* WoT   = (short*)wp; wp += 1179648;     // 4 x 384 x 384
    short* W1T   = (short*)wp; wp += 4718592;     // 4 x 1536 x 384
    short* W2T   = (short*)wp; wp += 4718592;     // 4 x 384 x 1536
    float* bqkv  = (float*)wp; wp += 18432;       // 4 x 1152 f32
    short* w2T   = (short*)wp; wp += 16384;       // 64 x 128 bf16 (conv2, paired-shift layout)
    short* hb    = featb;                         // FFN hidden 8192*1536 bf16

    const int ROWS = 8192;

    pe_kernel<<<128, 384, 0, stream>>>(pe);
    wcvt_kernel<<<dim3(64, 12, 1), 256, 0, stream>>>(ew, ewT, 2048, 384, 0, 0, 0);
    qkvcvt_kernel<<<dim3(12, 12, 12), 256, 0, stream>>>(Wq, Wk, Wv, WqkvT);
    wcvt_kernel<<<dim3(12, 12, 4), 256, 0, stream>>>(Wo, WoT, 384, 384, 0, 147456, 147456);
    wcvt_kernel<<<dim3(12, 48, 4), 256, 0, stream>>>(W1, W1T, 384, 1536, 0, 589824, 589824);
    wcvt_kernel<<<dim3(48, 12, 4), 256, 0, stream>>>(W2, W2T, 1536, 384, 0, 589824, 589824);
    biascat_kernel<<<4, 384, 0, stream>>>(bq, bk, bv, bqkv);
    w2cvt_kernel<<<32, 256, 0, stream>>>(cw2, w2T);
    cnn_kernel<<<4096, 256, 0, stream>>>(x, cw0, cb0, cw1, cb1, w2T, cb2, featb);

    // t/tb = relu(feat @ ew + eb) + pe
    gemm_bf16<29><<<dim3(6, 64), 256, 0, stream>>>(featb, ewT, eb, nullptr, pe,
                                                   t, tb, ROWS, 384, 2048);
    for (int i = 0; i < 4; ++i) {
        const short* WqkvTi = WqkvT + (size_t)i * 442368;
        const short* WoTi = WoT + (size_t)i * 147456;
        const short* W1Ti = W1T + (size_t)i * 589824;
        const short* W2Ti = W2T + (size_t)i * 589824;
        gemm_bf16_wide<16><<<dim3(9, 64), 256, 0, stream>>>(tb, WqkvTi,
            bqkv + i * 1152, nullptr, qkvb, ROWS, 1152, 384);
        attn_kernel<<<512, 256, 0, stream>>>(qkvb, ob);
        // t/tb = LN(o @ Wo + bo + t)
        gemm_ln<<<512, 256, 0, stream>>>(ob, WoTi, bo + i * 384, t,
            g1 + i * 384, be1 + i * 384, t, tb, 384);
        // hidden = relu(t @ W1 + b1)
        gemm_bf16_wide<17><<<dim3(12, 64), 256, 0, stream>>>(tb, W1Ti,
            b1 + i * 1536, nullptr, hb, ROWS, 1536, 384);
        // t/tb = LN(hidden @ W2 + b2 + t)
        gemm_ln<<<512, 256, 0, stream>>>(hb, W2Ti, b2 + i * 384, t,
            g2 + i * 384, be2 + i * 384, t, tb, 1536);
    }
    head_kernel<<<64, 384, 0, stream>>>(t, clw, clb, (float*)d_out);
}

// Round 5
// 729.359 us; speedup vs baseline: 1.0913x; 1.0180x over previous
//
#include <hip/hip_runtime.h>
#include <math.h>

// ---------------------------------------------------------------------------
// N=64, L=128, W=256, D=384, H=8, E=48, NL=4, DFF=1536, rows = N*L = 8192
// GEMMs: bf16 MFMA 16x16x32, A [M][K] bf16 row-major, Bt [N][K] bf16.
// R22 = R21 (wave-owns-window cnn, 1 barrier) + FIX: zero the TRAILING p0
// pad. R21's NaN: stage B reads padded p0 positions up to 133 (j0=120,
// u<=13) but stage A only writes 3..130 and only 0..2 were zeroed ->
// uninitialized LDS at 131..133 fed conv1. 12 floats/window now zeroed.
//  - 4 windows/block (grid 2048); wave w runs load->convA->convB on its OWN
//    window in wave-local LDS (no cross-wave deps); w0/w1 in registers.
//  - ONE barrier (before cooperative MFMA stage C; R20 had 3).
//  - xs/p0 zero-padded -> unconditional reads (~600 VALU saved/thread).
//  - stage B chunk order staggered per lane-group -> conflict-free p0 reads.
// Post-mortem R20: 99.5->77.6us, latency-bound (VALU 35%, Mfma 4%); R19
// lesson: watch WRITE_SIZE ~32MB for spill (keep launch_bounds (256,4)).
// ---------------------------------------------------------------------------

typedef float f32x4 __attribute__((ext_vector_type(4)));
typedef short bf16x8 __attribute__((ext_vector_type(8)));
typedef short s16x4 __attribute__((ext_vector_type(4)));

__device__ __forceinline__ short f2bf(float f) {
    union { float f; unsigned u; } c; c.f = f;
    unsigned r = (c.u + 0x7FFFu + ((c.u >> 16) & 1u)) >> 16;
    return (short)r;
}
__device__ __forceinline__ float bf2f(short s) {
    union { unsigned u; float f; } c;
    c.u = ((unsigned)(unsigned short)s) << 16;
    return c.f;
}

__device__ __forceinline__ void gload_lds16(const void* g, void* l) {
    __builtin_amdgcn_global_load_lds(
        (const __attribute__((address_space(1))) unsigned int*)g,
        (__attribute__((address_space(3))) unsigned int*)l,
        16, 0, 0);
}

// ---------------- positional encoding table: pe[l][d] ----------------------
__global__ __launch_bounds__(384) void pe_kernel(float* __restrict__ pe) {
    int l = blockIdx.x, d = threadIdx.x;
    int i2 = d >> 1;
    float ang = (float)l * expf(-(2.0f * (float)i2 / 384.0f) * 9.210340371976184f);
    pe[l * 384 + d] = (d & 1) ? cosf(ang) : sinf(ang);
}

// ---------------- weight convert+transpose: W fp32 [K][N] -> bf16 [N][K] ---
__global__ __launch_bounds__(256) void wcvt_kernel(
    const float* __restrict__ W, short* __restrict__ Wt, int K, int N,
    int dstOff, int srcZ, int dstZ)
{
    __shared__ float tile[32][33];
    int kb = blockIdx.x * 32, nb = blockIdx.y * 32;
    const float* Wp = W + (size_t)blockIdx.z * srcZ;
    short* Wtp = Wt + (size_t)blockIdx.z * dstZ + dstOff;
    int tx = threadIdx.x & 31, ty = threadIdx.x >> 5;
    #pragma unroll
    for (int r = ty; r < 32; r += 8)
        tile[r][tx] = Wp[(size_t)(kb + r) * N + nb + tx];
    __syncthreads();
    #pragma unroll
    for (int r = ty; r < 32; r += 8)
        Wtp[(size_t)(nb + r) * K + kb + tx] = f2bf(tile[tx][r]);
}

// ---------------- Wq/Wk/Wv -> WqkvT in one dispatch (z = layer*3+which) ----
__global__ __launch_bounds__(256) void qkvcvt_kernel(
    const float* __restrict__ Wq, const float* __restrict__ Wk,
    const float* __restrict__ Wv, short* __restrict__ WqkvT)
{
    __shared__ float tile[32][33];
    int kb = blockIdx.x * 32, nb = blockIdx.y * 32;
    int layer = blockIdx.z / 3, which = blockIdx.z - layer * 3;
    const float* Wp = (which == 0 ? Wq : (which == 1 ? Wk : Wv)) +
                      (size_t)layer * 147456;
    short* Wtp = WqkvT + (size_t)layer * 442368 + (size_t)which * 147456;
    int tx = threadIdx.x & 31, ty = threadIdx.x >> 5;
    #pragma unroll
    for (int r = ty; r < 32; r += 8)
        tile[r][tx] = Wp[(size_t)(kb + r) * 384 + nb + tx];
    __syncthreads();
    #pragma unroll
    for (int r = ty; r < 32; r += 8)
        Wtp[(size_t)(nb + r) * 384 + kb + tx] = f2bf(tile[tx][r]);
}

// ---------------- conv2 weights -> paired-shift layout [64][128] -----------
// w2p[c][pr*32 + q*8 + j] = w2[c][ci*7 + sft], ci=(q&1)*8+j, sft=2*pr+(q>>1);
// sft==7 (pair 3, upper half) -> 0. Matches stage-C A-fragment reads.
__global__ __launch_bounds__(256) void w2cvt_kernel(
    const float* __restrict__ w2, short* __restrict__ w2T)
{
    int idx = blockIdx.x * 256 + threadIdx.x;   // 64*128 = 8192
    int c = idx >> 7, r = idx & 127;
    int pr = r >> 5, q = (r >> 3) & 3, j = r & 7;
    int ci = (q & 1) * 8 + j;
    int sft = 2 * pr + (q >> 1);
    w2T[idx] = (sft < 7) ? f2bf(w2[c * 112 + ci * 7 + sft]) : (short)0;
}

// ---------------- concatenated qkv bias: bqkv[l][1152] ---------------------
__global__ __launch_bounds__(384) void biascat_kernel(
    const float* __restrict__ bq, const float* __restrict__ bk,
    const float* __restrict__ bv, float* __restrict__ bqkv)
{
    int l = blockIdx.x, j = threadIdx.x;
    bqkv[l * 1152 + j] = bq[l * 384 + j];
    bqkv[l * 1152 + 384 + j] = bk[l * 384 + j];
    bqkv[l * 1152 + 768 + j] = bv[l * 384 + j];
}

// ---------------- fused CNN window encoder: 4 windows/block, 1 barrier -----
// LDS layout (26880 B -> 5 blocks/CU):
//   [0     .. 4224)   xs[4][264] f32   (x at idx j+4, zeros [0..3],[260..263])
//   [4224  .. 13056)  p0[4][4][138] f32 (conv0 out at idx j+3, zeros [0..2]
//                     and [131..133]; stride 138)
//   [13056 .. 26880)  p1T[4][72][24] bf16 (row=pos+3, pad rows zeroed)
__global__ __launch_bounds__(256, 4) void cnn_kernel(
    const float* __restrict__ x,
    const float* __restrict__ w0, const float* __restrict__ b0,
    const float* __restrict__ w1, const float* __restrict__ b1,
    const short* __restrict__ w2T, const float* __restrict__ b2,
    short* __restrict__ feat)
{
    __shared__ __align__(16) char smem[26880];
    float* xs  = (float*)smem;                    // [4][264]
    float* p0  = (float*)(smem + 4224);           // [4][4][138]
    short* p1T = (short*)(smem + 13056);          // [4][72][24]

    int tid = threadIdx.x;
    int w = tid >> 6, lane = tid & 63;
    size_t win = (size_t)blockIdx.x * 4 + w;
    int cq = lane >> 4, cl = lane & 15;

    float* xs_w = xs + w * 264;
    float* p0_w = p0 + w * 552;                   // 4*138
    short* p1T_w = p1T + w * 1728;

    // ---- per-wave setup: weights to regs (L2-broadcast), xs fill ----
    int ca = lane & 3;
    int cb = lane & 15, g = lane >> 4;
    float w0r[7], w1r[4][7];
    float b0r = b0[ca];
    float b1r = b1[cb];
    #pragma unroll
    for (int k = 0; k < 7; ++k) w0r[k] = w0[ca * 7 + k];
    #pragma unroll
    for (int ci = 0; ci < 4; ++ci)
        #pragma unroll
        for (int k = 0; k < 7; ++k) w1r[ci][k] = w1[(cb * 4 + ci) * 7 + k];

    {
        f32x4 v = *(const f32x4*)(x + win * 256 + lane * 4);
        *(f32x4*)&xs_w[4 + lane * 4] = v;
        if (lane < 2) *(f32x4*)&xs_w[lane * 260] = (f32x4){0.f, 0.f, 0.f, 0.f};
    }

    // ---- stage A (wave-local): conv0 + relu + pool2 -> p0_w[c][pp+3] ----
    {
        int pa = lane >> 2;
        #pragma unroll
        for (int t2 = 0; t2 < 8; ++t2) {
            int pp = t2 * 16 + pa;
            float rv[9];
            #pragma unroll
            for (int u = 0; u < 9; ++u) rv[u] = xs_w[2 * pp + u + 1];
            float a0 = b0r, a1 = b0r;
            #pragma unroll
            for (int k = 0; k < 7; ++k) {
                a0 = fmaf(w0r[k], rv[k], a0);
                a1 = fmaf(w0r[k], rv[k + 1], a1);
            }
            p0_w[ca * 138 + pp + 3] = fmaxf(fmaxf(a0, a1), 0.f);
        }
        if (lane < 4) {
            // leading pad (j = -3..-1)
            p0_w[lane * 138 + 0] = 0.f;
            p0_w[lane * 138 + 1] = 0.f;
            p0_w[lane * 138 + 2] = 0.f;
            // trailing pad (j = 128..130) -- R21's NaN was this hole
            p0_w[lane * 138 + 131] = 0.f;
            p0_w[lane * 138 + 132] = 0.f;
            p0_w[lane * 138 + 133] = 0.f;
        }
    }

    // ---- stage B (wave-local): conv1 + relu + pool2 -> p1T_w[3+pos][c] ----
    // chunk order staggered per group (independent outputs -> bit-identical);
    // group banks: 8*((cc+g)&3) in {0,8,16,24} -> conflict-free reads.
    #pragma unroll
    for (int cc = 0; cc < 4; ++cc) {
        int cci = (cc + g) & 3;
        int j0 = g * 32 + cci * 8;           // padded pre-pool base
        float acc[8];
        #pragma unroll
        for (int m = 0; m < 8; ++m) acc[m] = b1r;
        #pragma unroll
        for (int ci = 0; ci < 4; ++ci) {
            float rv[14];
            #pragma unroll
            for (int u = 0; u < 14; ++u) rv[u] = p0_w[ci * 138 + j0 + u];
            #pragma unroll
            for (int k = 0; k < 7; ++k) {
                float ww = w1r[ci][k];
                #pragma unroll
                for (int m = 0; m < 8; ++m) acc[m] = fmaf(ww, rv[m + k], acc[m]);
            }
        }
        int po = g * 16 + cci * 4;
        #pragma unroll
        for (int m = 0; m < 4; ++m)
            p1T_w[(3 + po + m) * 24 + cb] =
                f2bf(fmaxf(fmaxf(acc[2 * m], acc[2 * m + 1]), 0.f));
    }
    // zero p1T pad rows (own window): rows 0..2 (dwords 0..35), 67..71 (804..863)
    {
        int* pz = (int*)p1T_w;
        if (lane < 36) pz[lane] = 0;
        if (lane < 60) pz[804 + lane] = 0;
    }
    __syncthreads();   // the ONLY barrier: all 4 windows' p1T ready

    // ---- stage C: conv2 as 4 paired-shift GEMMs, all 4 windows/wave ----
    // wave w covers positions [w*16, w*16+16) of every window (R19 mapping).
    f32x4 acc[4][4];   // [window v][mt]
    #pragma unroll
    for (int v = 0; v < 4; ++v)
        #pragma unroll
        for (int mt = 0; mt < 4; ++mt)
            acc[v][mt] = (f32x4){0.f, 0.f, 0.f, 0.f};

    {
        const short* bpb = p1T + (w * 16 + cl + (cq >> 1)) * 24 + (cq & 1) * 8;
        #pragma unroll
        for (int pr = 0; pr < 4; ++pr) {
            bf16x8 bfr[4];
            #pragma unroll
            for (int v = 0; v < 4; ++v)
                bfr[v] = *(const bf16x8*)&bpb[v * 1728 + pr * 48];
            #pragma unroll
            for (int mt = 0; mt < 4; ++mt) {
                bf16x8 af = *(const bf16x8*)&w2T[(mt * 16 + cl) * 128 +
                                                 pr * 32 + cq * 8];
                #pragma unroll
                for (int v = 0; v < 4; ++v)
                    acc[v][mt] = __builtin_amdgcn_mfma_f32_16x16x32_bf16(
                        af, bfr[v], acc[v][mt], 0, 0, 0);
            }
        }
    }

    // ---- epilogue: pool pairs via shfl, store bf16 (per window) ----
    int iev = (w * 16 + cl) >> 1;
    #pragma unroll
    for (int v = 0; v < 4; ++v) {
        short* fp = feat + ((size_t)blockIdx.x * 4 + v) * 2048;
        #pragma unroll
        for (int mt = 0; mt < 4; ++mt) {
            #pragma unroll
            for (int rg = 0; rg < 4; ++rg) {
                float vv = acc[v][mt][rg];
                float v2 = __shfl_xor(vv, 1, 64);
                if ((cl & 1) == 0) {
                    int c = mt * 16 + cq * 4 + rg;
                    float pv = fmaxf(fmaxf(vv, v2) + b2[c], 0.f);
                    fp[c * 32 + iev] = f2bf(pv);
                }
            }
        }
    }
}

// ---------------- bf16 MFMA GEMM (thin-N): BM=128, BN=64, double-buffered --
// EPI bits: 1=relu, 2=+resid(f32), 4=+pe, 8=write f32, 16=write bf16
template <int EPI>
__global__ __launch_bounds__(256) void gemm_bf16(
    const short* __restrict__ A, const short* __restrict__ Bt,
    const float* __restrict__ bias, const float* __restrict__ resid,
    const float* __restrict__ pe, float* __restrict__ outF,
    short* __restrict__ outB, int M, int N, int K)
{
    __shared__ short As[2][128 * 64];
    __shared__ short Bs[2][64 * 64];
    int tid = threadIdx.x;
    int w = tid >> 6, lane = tid & 63;
    int wm = w >> 1, wn = w & 1;
    int m0 = blockIdx.y * 128, n0 = blockIdx.x * 64;

    int rl = lane >> 3, sl = lane & 7;
    int cb = sl ^ rl;
    const short* aptr[4];
    const short* bptr[2];
    int arow[4], brow[2];
    #pragma unroll
    for (int l = 0; l < 4; ++l) {
        arow[l] = l * 32 + w * 8;
        aptr[l] = A + (size_t)(m0 + arow[l] + rl) * K + cb * 8;
    }
    #pragma unroll
    for (int l = 0; l < 2; ++l) {
        brow[l] = l * 32 + w * 8;
        bptr[l] = Bt + (size_t)(n0 + brow[l] + rl) * K + cb * 8;
    }

    int cq = lane >> 4, cl = lane & 15;
    f32x4 acc[4][2];
    #pragma unroll
    for (int mt = 0; mt < 4; ++mt)
        #pragma unroll
        for (int nt = 0; nt < 2; ++nt)
            acc[mt][nt] = (f32x4){0.f, 0.f, 0.f, 0.f};

    #pragma unroll
    for (int l = 0; l < 4; ++l) { gload_lds16(aptr[l], &As[0][arow[l] * 64]); aptr[l] += 64; }
    #pragma unroll
    for (int l = 0; l < 2; ++l) { gload_lds16(bptr[l], &Bs[0][brow[l] * 64]); bptr[l] += 64; }
    __syncthreads();

    int nk = K >> 6;
    for (int k = 0; k < nk; ++k) {
        int cur = k & 1;
        if (k + 1 < nk) {
            #pragma unroll
            for (int l = 0; l < 4; ++l) { gload_lds16(aptr[l], &As[cur ^ 1][arow[l] * 64]); aptr[l] += 64; }
            #pragma unroll
            for (int l = 0; l < 2; ++l) { gload_lds16(bptr[l], &Bs[cur ^ 1][brow[l] * 64]); bptr[l] += 64; }
        }
        #pragma unroll
        for (int s = 0; s < 2; ++s) {
            bf16x8 afr[4], bfr[2];
            #pragma unroll
            for (int mt = 0; mt < 4; ++mt) {
                int r = wm * 64 + mt * 16 + cl;
                int slot = (s * 4 + cq) ^ (r & 7);
                afr[mt] = *(const bf16x8*)&As[cur][r * 64 + slot * 8];
            }
            #pragma unroll
            for (int nt = 0; nt < 2; ++nt) {
                int r = wn * 32 + nt * 16 + cl;
                int slot = (s * 4 + cq) ^ (r & 7);
                bfr[nt] = *(const bf16x8*)&Bs[cur][r * 64 + slot * 8];
            }
            #pragma unroll
            for (int mt = 0; mt < 4; ++mt)
                #pragma unroll
                for (int nt = 0; nt < 2; ++nt)
                    acc[mt][nt] = __builtin_amdgcn_mfma_f32_16x16x32_bf16(
                        afr[mt], bfr[nt], acc[mt][nt], 0, 0, 0);
        }
        __syncthreads();
    }

    #pragma unroll
    for (int mt = 0; mt < 4; ++mt) {
        #pragma unroll
        for (int nt = 0; nt < 2; ++nt) {
            int col = n0 + wn * 32 + nt * 16 + cl;
            float bb = bias[col];
            #pragma unroll
            for (int rg = 0; rg < 4; ++rg) {
                int row = m0 + wm * 64 + mt * 16 + cq * 4 + rg;
                float v = acc[mt][nt][rg] + bb;
                if (EPI & 1) v = fmaxf(v, 0.f);
                if (EPI & 4) v += pe[(row & 127) * 384 + col];
                if (EPI & 2) v += resid[(size_t)row * N + col];
                if (EPI & 8) outF[(size_t)row * N + col] = v;
                if (EPI & 16) outB[(size_t)row * N + col] = f2bf(v);
            }
        }
    }
}

// ---------------- bf16 MFMA GEMM (wide-N): BM=128, BN=128, BK=32 dbuf ------
template <int EPI>
__global__ __launch_bounds__(256) void gemm_bf16_wide(
    const short* __restrict__ A, const short* __restrict__ Bt,
    const float* __restrict__ bias, float* __restrict__ outF,
    short* __restrict__ outB, int M, int N, int K)
{
    __shared__ short As[2][128 * 32];
    __shared__ short Bs[2][128 * 32];
    int tid = threadIdx.x;
    int w = tid >> 6, lane = tid & 63;
    int wm = w >> 1, wn = w & 1;
    int m0 = blockIdx.y * 128, n0 = blockIdx.x * 128;

    int rl = lane >> 2, sl = lane & 3;
    int cb = sl ^ (rl & 3) ^ ((rl >> 2) & 3);
    const short* aptr[2];
    const short* bptr[2];
    int srow[2];
    #pragma unroll
    for (int l = 0; l < 2; ++l) {
        srow[l] = w * 32 + l * 16;
        aptr[l] = A + (size_t)(m0 + srow[l] + rl) * K + cb * 8;
        bptr[l] = Bt + (size_t)(n0 + srow[l] + rl) * K + cb * 8;
    }

    int cq = lane >> 4, cl = lane & 15;
    f32x4 acc[4][4];
    #pragma unroll
    for (int mt = 0; mt < 4; ++mt)
        #pragma unroll
        for (int nt = 0; nt < 4; ++nt)
            acc[mt][nt] = (f32x4){0.f, 0.f, 0.f, 0.f};

    #pragma unroll
    for (int l = 0; l < 2; ++l) {
        gload_lds16(aptr[l], &As[0][srow[l] * 32]);
        gload_lds16(bptr[l], &Bs[0][srow[l] * 32]);
        aptr[l] += 32; bptr[l] += 32;
    }
    __syncthreads();

    int nk = K >> 5;
    for (int k = 0; k < nk; ++k) {
        int cur = k & 1;
        if (k + 1 < nk) {
            #pragma unroll
            for (int l = 0; l < 2; ++l) {
                gload_lds16(aptr[l], &As[cur ^ 1][srow[l] * 32]);
                gload_lds16(bptr[l], &Bs[cur ^ 1][srow[l] * 32]);
                aptr[l] += 32; bptr[l] += 32;
            }
        }
        bf16x8 afr[4], bfr[4];
        #pragma unroll
        for (int mt = 0; mt < 4; ++mt) {
            int r = wm * 64 + mt * 16 + cl;
            int slot = cq ^ (r & 3) ^ ((r >> 2) & 3);
            afr[mt] = *(const bf16x8*)&As[cur][r * 32 + slot * 8];
        }
        #pragma unroll
        for (int nt = 0; nt < 4; ++nt) {
            int r = wn * 64 + nt * 16 + cl;
            int slot = cq ^ (r & 3) ^ ((r >> 2) & 3);
            bfr[nt] = *(const bf16x8*)&Bs[cur][r * 32 + slot * 8];
        }
        #pragma unroll
        for (int mt = 0; mt < 4; ++mt)
            #pragma unroll
            for (int nt = 0; nt < 4; ++nt)
                acc[mt][nt] = __builtin_amdgcn_mfma_f32_16x16x32_bf16(
                    afr[mt], bfr[nt], acc[mt][nt], 0, 0, 0);
        __syncthreads();
    }

    #pragma unroll
    for (int mt = 0; mt < 4; ++mt) {
        #pragma unroll
        for (int nt = 0; nt < 4; ++nt) {
            int col = n0 + wn * 64 + nt * 16 + cl;
            float bb = bias[col];
            #pragma unroll
            for (int rg = 0; rg < 4; ++rg) {
                int row = m0 + wm * 64 + mt * 16 + cq * 4 + rg;
                float v = acc[mt][nt][rg] + bb;
                if (EPI & 1) v = fmaxf(v, 0.f);
                if (EPI & 8) outF[(size_t)row * N + col] = v;
                if (EPI & 16) outB[(size_t)row * N + col] = f2bf(v);
            }
        }
    }
}

// ---------------- fused GEMM + bias + residual + LayerNorm -----------------
// BM=16, BN=384, BK=64 -> grid 512. (BK=32 regressed in R13.)
__global__ __launch_bounds__(256) void gemm_ln(
    const short* __restrict__ A, const short* __restrict__ Bt,
    const float* __restrict__ bias, const float* resid,
    const float* __restrict__ g, const float* __restrict__ be,
    float* t, short* __restrict__ tb, int K)
{
    __shared__ __align__(16) char smem[51200];
    short* As = (short*)smem;              // 16 x 64 bf16 = 2 KB
    short* Bs = (short*)(smem + 2048);     // 384 x 64 bf16 = 48 KB

    int tid = threadIdx.x;
    int w = tid >> 6, lane = tid & 63;
    int m0 = blockIdx.x * 16;
    int rl = lane >> 3, sl = lane & 7;
    int cb = sl ^ rl;

    const short* aptr = A + (size_t)(m0 + w * 8 + rl) * K + cb * 8;
    const short* bptr[12];
    #pragma unroll
    for (int l = 0; l < 12; ++l)
        bptr[l] = Bt + (size_t)(w * 96 + l * 8 + rl) * K + cb * 8;

    int cq = lane >> 4, cl = lane & 15;
    f32x4 acc[6];
    #pragma unroll
    for (int nt = 0; nt < 6; ++nt) acc[nt] = (f32x4){0.f, 0.f, 0.f, 0.f};

    for (int k0 = 0; k0 < K; k0 += 64) {
        if (w < 2) {
            gload_lds16(aptr, &As[(w * 8) * 64]);
            aptr += 64;
        }
        #pragma unroll
        for (int l = 0; l < 12; ++l) {
            gload_lds16(bptr[l], &Bs[(w * 96 + l * 8) * 64]);
            bptr[l] += 64;
        }
        __syncthreads();
        #pragma unroll
        for (int s = 0; s < 2; ++s) {
            bf16x8 afr, bfr[6];
            {
                int r = cl;
                int slot = (s * 4 + cq) ^ (r & 7);
                afr = *(const bf16x8*)&As[r * 64 + slot * 8];
            }
            #pragma unroll
            for (int nt = 0; nt < 6; ++nt) {
                int r = w * 96 + nt * 16 + cl;
                int slot = (s * 4 + cq) ^ (r & 7);
                bfr[nt] = *(const bf16x8*)&Bs[r * 64 + slot * 8];
            }
            #pragma unroll
            for (int nt = 0; nt < 6; ++nt)
                acc[nt] = __builtin_amdgcn_mfma_f32_16x16x32_bf16(
                    afr, bfr[nt], acc[nt], 0, 0, 0);
        }
        __syncthreads();
    }

    // ---- epilogue: y = acc + bias + resid -> LDS (16 x 388 f32) ----
    float* yb = (float*)smem;
    #pragma unroll
    for (int nt = 0; nt < 6; ++nt) {
        int col = w * 96 + nt * 16 + cl;
        float bb = bias[col];
        #pragma unroll
        for (int rg = 0; rg < 4; ++rg) {
            int rloc = cq * 4 + rg;
            yb[rloc * 388 + col] =
                acc[nt][rg] + bb + resid[(size_t)(m0 + rloc) * 384 + col];
        }
    }
    __syncthreads();

    // ---- LayerNorm: 16 threads per row ----
    int rloc = tid >> 4, sub = tid & 15;
    f32x4 vals[6];
    float s = 0.f, s2 = 0.f;
    #pragma unroll
    for (int m = 0; m < 6; ++m) {
        f32x4 vv = *(const f32x4*)&yb[rloc * 388 + m * 64 + sub * 4];
        vals[m] = vv;
        #pragma unroll
        for (int j = 0; j < 4; ++j) {
            s += vv[j];
            s2 = fmaf(vv[j], vv[j], s2);
        }
    }
    s += __shfl_xor(s, 1, 64);  s2 += __shfl_xor(s2, 1, 64);
    s += __shfl_xor(s, 2, 64);  s2 += __shfl_xor(s2, 2, 64);
    s += __shfl_xor(s, 4, 64);  s2 += __shfl_xor(s2, 4, 64);
    s += __shfl_xor(s, 8, 64);  s2 += __shfl_xor(s2, 8, 64);
    float mean = s * (1.f / 384.f);
    float var = s2 * (1.f / 384.f) - mean * mean;
    float inv = rsqrtf(var + 1e-5f);

    size_t ro = (size_t)(m0 + rloc) * 384;
    #pragma unroll
    for (int m = 0; m < 6; ++m) {
        int c0 = m * 64 + sub * 4;
        f32x4 gg = *(const f32x4*)&g[c0];
        f32x4 bb = *(const f32x4*)&be[c0];
        f32x4 ov;
        s16x4 ob2;
        #pragma unroll
        for (int j = 0; j < 4; ++j) {
            float v = (vals[m][j] - mean) * inv * gg[j] + bb[j];
            ov[j] = v;
            ob2[j] = f2bf(v);
        }
        *(f32x4*)&t[ro + c0] = ov;
        *(s16x4*)&tb[ro + c0] = ob2;
    }
}

// ---------------- fused attention per (n,h): split-E x2, 256 threads -------
__global__ __launch_bounds__(256) void attn_kernel(
    const short* __restrict__ qkv, short* __restrict__ o)
{
    __shared__ f32x4 Ks[128][12];
    __shared__ f32x4 Vs[128][12];
    int tid = threadIdx.x;
    int n = blockIdx.x >> 3, h = blockIdx.x & 7;
    size_t base = (size_t)n * 128 * 1152 + (size_t)h * 48;
    const short* kp = qkv + base + 384;
    const short* vp = qkv + base + 768;
    for (int i = tid; i < 1536; i += 256) {
        int s = i / 12, e4 = i - s * 12;
        s16x4 kv = *(const s16x4*)(kp + (size_t)s * 1152 + e4 * 4);
        s16x4 vv = *(const s16x4*)(vp + (size_t)s * 1152 + e4 * 4);
        f32x4 kf, vf;
        #pragma unroll
        for (int j = 0; j < 4; ++j) { kf[j] = bf2f(kv[j]); vf[j] = bf2f(vv[j]); }
        Ks[s][e4] = kf;
        Vs[s][e4] = vf;
    }
    const float temp = 0.14433756729740643f;  // 1/sqrt(48)
    int r = tid >> 1;
    int h2 = tid & 1;
    int eb0 = h2 * 6;
    float qr[24];
    {
        const short* qp = qkv + base + (size_t)r * 1152 + h2 * 24;
        #pragma unroll
        for (int e4 = 0; e4 < 6; ++e4) {
            s16x4 qv = *(const s16x4*)(qp + e4 * 4);
            #pragma unroll
            for (int j = 0; j < 4; ++j) qr[e4 * 4 + j] = bf2f(qv[j]) * temp;
        }
    }
    __syncthreads();

    float m = -1e30f, denom = 0.f;
    f32x4 acc[6];
    #pragma unroll
    for (int e = 0; e < 6; ++e) acc[e] = (f32x4){0.f, 0.f, 0.f, 0.f};

    for (int s0 = 0; s0 < 128; s0 += 8) {
        float sc[8];
        #pragma unroll
        for (int u = 0; u < 8; ++u) {
            float t0 = 0.f;
            #pragma unroll
            for (int e = 0; e < 6; ++e) {
                f32x4 kk = Ks[s0 + u][eb0 + e];
                t0 = fmaf(qr[e * 4 + 0], kk[0], t0);
                t0 = fmaf(qr[e * 4 + 1], kk[1], t0);
                t0 = fmaf(qr[e * 4 + 2], kk[2], t0);
                t0 = fmaf(qr[e * 4 + 3], kk[3], t0);
            }
            sc[u] = t0 + __shfl_xor(t0, 1, 64);
        }
        float cmax = sc[0];
        #pragma unroll
        for (int u = 1; u < 8; ++u) cmax = fmaxf(cmax, sc[u]);
        float nm = fmaxf(m, cmax);
        float alpha = __expf(m - nm);
        m = nm;
        float p[8];
        float ps = 0.f;
        #pragma unroll
        for (int u = 0; u < 8; ++u) { p[u] = __expf(sc[u] - nm); ps += p[u]; }
        denom = denom * alpha + ps;
        #pragma unroll
        for (int e = 0; e < 6; ++e) {
            f32x4 a = acc[e];
            a[0] *= alpha; a[1] *= alpha; a[2] *= alpha; a[3] *= alpha;
            #pragma unroll
            for (int u = 0; u < 8; ++u) {
                f32x4 vv = Vs[s0 + u][eb0 + e];
                a[0] = fmaf(p[u], vv[0], a[0]);
                a[1] = fmaf(p[u], vv[1], a[1]);
                a[2] = fmaf(p[u], vv[2], a[2]);
                a[3] = fmaf(p[u], vv[3], a[3]);
            }
            acc[e] = a;
        }
    }
    float inv = 1.f / denom;
    short* op = o + ((size_t)n * 128 + r) * 384 + h * 48 + h2 * 24;
    #pragma unroll
    for (int e = 0; e < 6; ++e) {
        s16x4 ov;
        #pragma unroll
        for (int j = 0; j < 4; ++j) ov[j] = f2bf(acc[e][j] * inv);
        *(s16x4*)(op + e * 4) = ov;
    }
}

// ---------------- classifier head ------------------------------------------
__global__ __launch_bounds__(384) void head_kernel(
    const float* __restrict__ t, const float* __restrict__ cls_w,
    const float* __restrict__ cls_b, float* __restrict__ out)
{
    int n = blockIdx.x, d = threadIdx.x;
    float s = 0.f;
    for (int l = 0; l < 128; ++l) s += t[((size_t)n * 128 + l) * 384 + d];
    float p = s * (1.f / 128.f) * cls_w[d];
    #pragma unroll
    for (int off = 32; off > 0; off >>= 1) p += __shfl_xor(p, off, 64);
    __shared__ float red[6];
    if ((threadIdx.x & 63) == 0) red[threadIdx.x >> 6] = p;
    __syncthreads();
    if (threadIdx.x == 0) {
        float tot = red[0] + red[1] + red[2] + red[3] + red[4] + red[5];
        out[n] = tot + cls_b[0];
    }
}

// ---------------------------------------------------------------------------
extern "C" void kernel_launch(void* const* d_in, const int* in_sizes, int n_in,
                              void* d_out, int out_size, void* d_ws, size_t ws_size,
                              hipStream_t stream) {
    (void)n_in; (void)out_size; (void)ws_size;
    const float* x   = (const float*)d_in[0];
    const float* cw0 = (const float*)d_in[1];
    const float* cb0 = (const float*)d_in[2];
    const float* cw1 = (const float*)d_in[3];
    const float* cb1 = (const float*)d_in[4];
    const float* cw2 = (const float*)d_in[5];
    const float* cb2 = (const float*)d_in[6];
    const float* ew  = (const float*)d_in[7];
    const float* eb  = (const float*)d_in[8];
    bool dict_order = (in_sizes[10] == 589824);
    const float *Wq, *Wk, *Wv, *Wo, *W1, *W2, *bq, *bk, *bv, *bo, *b1, *b2;
    if (dict_order) {
        Wq = (const float*)d_in[9];  Wk = (const float*)d_in[10];
        Wv = (const float*)d_in[11]; Wo = (const float*)d_in[12];
        W1 = (const float*)d_in[13]; W2 = (const float*)d_in[14];
        bq = (const float*)d_in[15]; bk = (const float*)d_in[16];
        bv = (const float*)d_in[17]; bo = (const float*)d_in[18];
        b1 = (const float*)d_in[19]; b2 = (const float*)d_in[20];
    } else {
        Wq = (const float*)d_in[9];  bq = (const float*)d_in[10];
        Wk = (const float*)d_in[11]; bk = (const float*)d_in[12];
        Wv = (const float*)d_in[13]; bv = (const float*)d_in[14];
        Wo = (const float*)d_in[15]; bo = (const float*)d_in[16];
        W1 = (const float*)d_in[17]; b1 = (const float*)d_in[18];
        W2 = (const float*)d_in[19]; b2 = (const float*)d_in[20];
    }
    const float* g1  = (const float*)d_in[21];
    const float* be1 = (const float*)d_in[22];
    const float* g2  = (const float*)d_in[23];
    const float* be2 = (const float*)d_in[24];
    const float* clw = (const float*)d_in[25];
    const float* clb = (const float*)d_in[26];

    // ---- workspace layout (bytes) ----
    char* wp = (char*)d_ws;
    float* pe    = (float*)wp; wp += 196608;      // 128*384 f32
    short* featb = (short*)wp; wp += 33554432;    // 8192*2048 bf16 (reused as FFN hidden)
    float* t     = (float*)wp; wp += 12582912;    // 8192*384 f32
    short* tb    = (short*)wp; wp += 6291456;     // 8192*384 bf16
    short* qkvb  = (short*)wp; wp += 18874368;    // 8192*1152 bf16
    short* ob    = (short*)wp; wp += 6291456;     // 8192*384 bf16 (attn out)
    short* ewT   = (short*)wp; wp += 1572864;     // 384 x 2048
    short* WqkvT = (short*)wp; wp += 3538944;     // 4 x 1152 x 384
    short* WoT   = (short*)wp; wp += 1179648;     // 4 x 384 x 384
    short* W1T   = (short*)wp; wp += 4718592;     // 4 x 1536 x 384
    short* W2T   = (short*)wp; wp += 4718592;     // 4 x 384 x 1536
    float* bqkv  = (float*)wp; wp += 18432;       // 4 x 1152 f32
    short* w2T   = (short*)wp; wp += 16384;       // 64 x 128 bf16 (conv2, paired-shift layout)
    short* hb    = featb;                         // FFN hidden 8192*1536 bf16

    const int ROWS = 8192;

    pe_kernel<<<128, 384, 0, stream>>>(pe);
    wcvt_kernel<<<dim3(64, 12, 1), 256, 0, stream>>>(ew, ewT, 2048, 384, 0, 0, 0);
    qkvcvt_kernel<<<dim3(12, 12, 12), 256, 0, stream>>>(Wq, Wk, Wv, WqkvT);
    wcvt_kernel<<<dim3(12, 12, 4), 256, 0, stream>>>(Wo, WoT, 384, 384, 0, 147456, 147456);
    wcvt_kernel<<<dim3(12, 48, 4), 256, 0, stream>>>(W1, W1T, 384, 1536, 0, 589824, 589824);
    wcvt_kernel<<<dim3(48, 12, 4), 256, 0, stream>>>(W2, W2T, 1536, 384, 0, 589824, 589824);
    biascat_kernel<<<4, 384, 0, stream>>>(bq, bk, bv, bqkv);
    w2cvt_kernel<<<32, 256, 0, stream>>>(cw2, w2T);
    cnn_kernel<<<2048, 256, 0, stream>>>(x, cw0, cb0, cw1, cb1, w2T, cb2, featb);

    // t/tb = relu(feat @ ew + eb) + pe
    gemm_bf16<29><<<dim3(6, 64), 256, 0, stream>>>(featb, ewT, eb, nullptr, pe,
                                                   t, tb, ROWS, 384, 2048);
    for (int i = 0; i < 4; ++i) {
        const short* WqkvTi = WqkvT + (size_t)i * 442368;
        const short* WoTi = WoT + (size_t)i * 147456;
        const short* W1Ti = W1T + (size_t)i * 589824;
        const short* W2Ti = W2T + (size_t)i * 589824;
        gemm_bf16_wide<16><<<dim3(9, 64), 256, 0, stream>>>(tb, WqkvTi,
            bqkv + i * 1152, nullptr, qkvb, ROWS, 1152, 384);
        attn_kernel<<<512, 256, 0, stream>>>(qkvb, ob);
        // t/tb = LN(o @ Wo + bo + t)
        gemm_ln<<<512, 256, 0, stream>>>(ob, WoTi, bo + i * 384, t,
            g1 + i * 384, be1 + i * 384, t, tb, 384);
        // hidden = relu(t @ W1 + b1)
        gemm_bf16_wide<17><<<dim3(12, 64), 256, 0, stream>>>(tb, W1Ti,
            b1 + i * 1536, nullptr, hb, ROWS, 1536, 384);
        // t/tb = LN(hidden @ W2 + b2 + t)
        gemm_ln<<<512, 256, 0, stream>>>(hb, W2Ti, b2 + i * 384, t,
            g2 + i * 384, be2 + i * 384, t, tb, 1536);
    }
    head_kernel<<<64, 384, 0, stream>>>(t, clw, clb, (float*)d_out);
}

// Round 6
// 630.411 us; speedup vs baseline: 1.2625x; 1.1570x over previous
//
#include <hip/hip_runtime.h>
#include <math.h>

// ---------------------------------------------------------------------------
// N=64, L=128, W=256, D=384, H=8, E=48, NL=4, DFF=1536, rows = N*L = 8192
// GEMMs: bf16 MFMA 16x16x32, A [M][K] bf16 row-major, Bt [N][K] bf16.
// R23: attn_kernel rewritten VALU -> MFMA. Old kernel: ~7000 VALU/thread
// (QK 3072 fmaf + PV 3456 fmaf) = >=11.7us issue floor per dispatch x4.
// New: per (n,h) block, wave w owns queries w*32..+31; S=QK^T via
// 16x16x32 MFMA (E=48 -> 2 k-steps, 2nd half zero-guarded cq<2), exact
// softmax in the verified C-layout (row=cq*4+rg, col=cl) with shfl_xor
// row-reduce; P->LDS [32][136] bf16 per wave (wave-local, no barrier);
// V transposed once to Vt[48][136]; PV = 24 MFMA/wave. 1 barrier total.
// Fragment conventions copied from this file's verified GEMMs.
// Post-mortem R22: 742->729us (cnn 68us, conflicts 655K). The 40ms
// gemm_ln rocprof row is a replay artifact (e2e=729us).
// ---------------------------------------------------------------------------

typedef float f32x4 __attribute__((ext_vector_type(4)));
typedef short bf16x8 __attribute__((ext_vector_type(8)));
typedef short s16x4 __attribute__((ext_vector_type(4)));

__device__ __forceinline__ short f2bf(float f) {
    union { float f; unsigned u; } c; c.f = f;
    unsigned r = (c.u + 0x7FFFu + ((c.u >> 16) & 1u)) >> 16;
    return (short)r;
}
__device__ __forceinline__ float bf2f(short s) {
    union { unsigned u; float f; } c;
    c.u = ((unsigned)(unsigned short)s) << 16;
    return c.f;
}

__device__ __forceinline__ void gload_lds16(const void* g, void* l) {
    __builtin_amdgcn_global_load_lds(
        (const __attribute__((address_space(1))) unsigned int*)g,
        (__attribute__((address_space(3))) unsigned int*)l,
        16, 0, 0);
}

// ---------------- positional encoding table: pe[l][d] ----------------------
__global__ __launch_bounds__(384) void pe_kernel(float* __restrict__ pe) {
    int l = blockIdx.x, d = threadIdx.x;
    int i2 = d >> 1;
    float ang = (float)l * expf(-(2.0f * (float)i2 / 384.0f) * 9.210340371976184f);
    pe[l * 384 + d] = (d & 1) ? cosf(ang) : sinf(ang);
}

// ---------------- weight convert+transpose: W fp32 [K][N] -> bf16 [N][K] ---
__global__ __launch_bounds__(256) void wcvt_kernel(
    const float* __restrict__ W, short* __restrict__ Wt, int K, int N,
    int dstOff, int srcZ, int dstZ)
{
    __shared__ float tile[32][33];
    int kb = blockIdx.x * 32, nb = blockIdx.y * 32;
    const float* Wp = W + (size_t)blockIdx.z * srcZ;
    short* Wtp = Wt + (size_t)blockIdx.z * dstZ + dstOff;
    int tx = threadIdx.x & 31, ty = threadIdx.x >> 5;
    #pragma unroll
    for (int r = ty; r < 32; r += 8)
        tile[r][tx] = Wp[(size_t)(kb + r) * N + nb + tx];
    __syncthreads();
    #pragma unroll
    for (int r = ty; r < 32; r += 8)
        Wtp[(size_t)(nb + r) * K + kb + tx] = f2bf(tile[tx][r]);
}

// ---------------- Wq/Wk/Wv -> WqkvT in one dispatch (z = layer*3+which) ----
__global__ __launch_bounds__(256) void qkvcvt_kernel(
    const float* __restrict__ Wq, const float* __restrict__ Wk,
    const float* __restrict__ Wv, short* __restrict__ WqkvT)
{
    __shared__ float tile[32][33];
    int kb = blockIdx.x * 32, nb = blockIdx.y * 32;
    int layer = blockIdx.z / 3, which = blockIdx.z - layer * 3;
    const float* Wp = (which == 0 ? Wq : (which == 1 ? Wk : Wv)) +
                      (size_t)layer * 147456;
    short* Wtp = WqkvT + (size_t)layer * 442368 + (size_t)which * 147456;
    int tx = threadIdx.x & 31, ty = threadIdx.x >> 5;
    #pragma unroll
    for (int r = ty; r < 32; r += 8)
        tile[r][tx] = Wp[(size_t)(kb + r) * 384 + nb + tx];
    __syncthreads();
    #pragma unroll
    for (int r = ty; r < 32; r += 8)
        Wtp[(size_t)(nb + r) * 384 + kb + tx] = f2bf(tile[tx][r]);
}

// ---------------- conv2 weights -> paired-shift layout [64][128] -----------
// w2p[c][pr*32 + q*8 + j] = w2[c][ci*7 + sft], ci=(q&1)*8+j, sft=2*pr+(q>>1);
// sft==7 (pair 3, upper half) -> 0. Matches stage-C A-fragment reads.
__global__ __launch_bounds__(256) void w2cvt_kernel(
    const float* __restrict__ w2, short* __restrict__ w2T)
{
    int idx = blockIdx.x * 256 + threadIdx.x;   // 64*128 = 8192
    int c = idx >> 7, r = idx & 127;
    int pr = r >> 5, q = (r >> 3) & 3, j = r & 7;
    int ci = (q & 1) * 8 + j;
    int sft = 2 * pr + (q >> 1);
    w2T[idx] = (sft < 7) ? f2bf(w2[c * 112 + ci * 7 + sft]) : (short)0;
}

// ---------------- concatenated qkv bias: bqkv[l][1152] ---------------------
__global__ __launch_bounds__(384) void biascat_kernel(
    const float* __restrict__ bq, const float* __restrict__ bk,
    const float* __restrict__ bv, float* __restrict__ bqkv)
{
    int l = blockIdx.x, j = threadIdx.x;
    bqkv[l * 1152 + j] = bq[l * 384 + j];
    bqkv[l * 1152 + 384 + j] = bk[l * 384 + j];
    bqkv[l * 1152 + 768 + j] = bv[l * 384 + j];
}

// ---------------- fused CNN window encoder: 4 windows/block, 1 barrier -----
// LDS layout (26880 B -> 5 blocks/CU):
//   [0     .. 4224)   xs[4][264] f32   (x at idx j+4, zeros [0..3],[260..263])
//   [4224  .. 13056)  p0[4][4][138] f32 (conv0 out at idx j+3, zeros [0..2]
//                     and [131..133]; stride 138)
//   [13056 .. 26880)  p1T[4][72][24] bf16 (row=pos+3, pad rows zeroed)
__global__ __launch_bounds__(256, 4) void cnn_kernel(
    const float* __restrict__ x,
    const float* __restrict__ w0, const float* __restrict__ b0,
    const float* __restrict__ w1, const float* __restrict__ b1,
    const short* __restrict__ w2T, const float* __restrict__ b2,
    short* __restrict__ feat)
{
    __shared__ __align__(16) char smem[26880];
    float* xs  = (float*)smem;                    // [4][264]
    float* p0  = (float*)(smem + 4224);           // [4][4][138]
    short* p1T = (short*)(smem + 13056);          // [4][72][24]

    int tid = threadIdx.x;
    int w = tid >> 6, lane = tid & 63;
    size_t win = (size_t)blockIdx.x * 4 + w;
    int cq = lane >> 4, cl = lane & 15;

    float* xs_w = xs + w * 264;
    float* p0_w = p0 + w * 552;                   // 4*138
    short* p1T_w = p1T + w * 1728;

    // ---- per-wave setup: weights to regs (L2-broadcast), xs fill ----
    int ca = lane & 3;
    int cb = lane & 15, g = lane >> 4;
    float w0r[7], w1r[4][7];
    float b0r = b0[ca];
    float b1r = b1[cb];
    #pragma unroll
    for (int k = 0; k < 7; ++k) w0r[k] = w0[ca * 7 + k];
    #pragma unroll
    for (int ci = 0; ci < 4; ++ci)
        #pragma unroll
        for (int k = 0; k < 7; ++k) w1r[ci][k] = w1[(cb * 4 + ci) * 7 + k];

    {
        f32x4 v = *(const f32x4*)(x + win * 256 + lane * 4);
        *(f32x4*)&xs_w[4 + lane * 4] = v;
        if (lane < 2) *(f32x4*)&xs_w[lane * 260] = (f32x4){0.f, 0.f, 0.f, 0.f};
    }

    // ---- stage A (wave-local): conv0 + relu + pool2 -> p0_w[c][pp+3] ----
    {
        int pa = lane >> 2;
        #pragma unroll
        for (int t2 = 0; t2 < 8; ++t2) {
            int pp = t2 * 16 + pa;
            float rv[9];
            #pragma unroll
            for (int u = 0; u < 9; ++u) rv[u] = xs_w[2 * pp + u + 1];
            float a0 = b0r, a1 = b0r;
            #pragma unroll
            for (int k = 0; k < 7; ++k) {
                a0 = fmaf(w0r[k], rv[k], a0);
                a1 = fmaf(w0r[k], rv[k + 1], a1);
            }
            p0_w[ca * 138 + pp + 3] = fmaxf(fmaxf(a0, a1), 0.f);
        }
        if (lane < 4) {
            // leading pad (j = -3..-1)
            p0_w[lane * 138 + 0] = 0.f;
            p0_w[lane * 138 + 1] = 0.f;
            p0_w[lane * 138 + 2] = 0.f;
            // trailing pad (j = 128..130)
            p0_w[lane * 138 + 131] = 0.f;
            p0_w[lane * 138 + 132] = 0.f;
            p0_w[lane * 138 + 133] = 0.f;
        }
    }

    // ---- stage B (wave-local): conv1 + relu + pool2 -> p1T_w[3+pos][c] ----
    // chunk order staggered per group (independent outputs -> bit-identical);
    // group banks: 8*((cc+g)&3) in {0,8,16,24} -> conflict-free reads.
    #pragma unroll
    for (int cc = 0; cc < 4; ++cc) {
        int cci = (cc + g) & 3;
        int j0 = g * 32 + cci * 8;           // padded pre-pool base
        float acc[8];
        #pragma unroll
        for (int m = 0; m < 8; ++m) acc[m] = b1r;
        #pragma unroll
        for (int ci = 0; ci < 4; ++ci) {
            float rv[14];
            #pragma unroll
            for (int u = 0; u < 14; ++u) rv[u] = p0_w[ci * 138 + j0 + u];
            #pragma unroll
            for (int k = 0; k < 7; ++k) {
                float ww = w1r[ci][k];
                #pragma unroll
                for (int m = 0; m < 8; ++m) acc[m] = fmaf(ww, rv[m + k], acc[m]);
            }
        }
        int po = g * 16 + cci * 4;
        #pragma unroll
        for (int m = 0; m < 4; ++m)
            p1T_w[(3 + po + m) * 24 + cb] =
                f2bf(fmaxf(fmaxf(acc[2 * m], acc[2 * m + 1]), 0.f));
    }
    // zero p1T pad rows (own window): rows 0..2 (dwords 0..35), 67..71 (804..863)
    {
        int* pz = (int*)p1T_w;
        if (lane < 36) pz[lane] = 0;
        if (lane < 60) pz[804 + lane] = 0;
    }
    __syncthreads();   // the ONLY barrier: all 4 windows' p1T ready

    // ---- stage C: conv2 as 4 paired-shift GEMMs, all 4 windows/wave ----
    f32x4 acc[4][4];   // [window v][mt]
    #pragma unroll
    for (int v = 0; v < 4; ++v)
        #pragma unroll
        for (int mt = 0; mt < 4; ++mt)
            acc[v][mt] = (f32x4){0.f, 0.f, 0.f, 0.f};

    {
        const short* bpb = p1T + (w * 16 + cl + (cq >> 1)) * 24 + (cq & 1) * 8;
        #pragma unroll
        for (int pr = 0; pr < 4; ++pr) {
            bf16x8 bfr[4];
            #pragma unroll
            for (int v = 0; v < 4; ++v)
                bfr[v] = *(const bf16x8*)&bpb[v * 1728 + pr * 48];
            #pragma unroll
            for (int mt = 0; mt < 4; ++mt) {
                bf16x8 af = *(const bf16x8*)&w2T[(mt * 16 + cl) * 128 +
                                                 pr * 32 + cq * 8];
                #pragma unroll
                for (int v = 0; v < 4; ++v)
                    acc[v][mt] = __builtin_amdgcn_mfma_f32_16x16x32_bf16(
                        af, bfr[v], acc[v][mt], 0, 0, 0);
            }
        }
    }

    // ---- epilogue: pool pairs via shfl, store bf16 (per window) ----
    int iev = (w * 16 + cl) >> 1;
    #pragma unroll
    for (int v = 0; v < 4; ++v) {
        short* fp = feat + ((size_t)blockIdx.x * 4 + v) * 2048;
        #pragma unroll
        for (int mt = 0; mt < 4; ++mt) {
            #pragma unroll
            for (int rg = 0; rg < 4; ++rg) {
                float vv = acc[v][mt][rg];
                float v2 = __shfl_xor(vv, 1, 64);
                if ((cl & 1) == 0) {
                    int c = mt * 16 + cq * 4 + rg;
                    float pv = fmaxf(fmaxf(vv, v2) + b2[c], 0.f);
                    fp[c * 32 + iev] = f2bf(pv);
                }
            }
        }
    }
}

// ---------------- bf16 MFMA GEMM (thin-N): BM=128, BN=64, double-buffered --
// EPI bits: 1=relu, 2=+resid(f32), 4=+pe, 8=write f32, 16=write bf16
template <int EPI>
__global__ __launch_bounds__(256) void gemm_bf16(
    const short* __restrict__ A, const short* __restrict__ Bt,
    const float* __restrict__ bias, const float* __restrict__ resid,
    const float* __restrict__ pe, float* __restrict__ outF,
    short* __restrict__ outB, int M, int N, int K)
{
    __shared__ short As[2][128 * 64];
    __shared__ short Bs[2][64 * 64];
    int tid = threadIdx.x;
    int w = tid >> 6, lane = tid & 63;
    int wm = w >> 1, wn = w & 1;
    int m0 = blockIdx.y * 128, n0 = blockIdx.x * 64;

    int rl = lane >> 3, sl = lane & 7;
    int cb = sl ^ rl;
    const short* aptr[4];
    const short* bptr[2];
    int arow[4], brow[2];
    #pragma unroll
    for (int l = 0; l < 4; ++l) {
        arow[l] = l * 32 + w * 8;
        aptr[l] = A + (size_t)(m0 + arow[l] + rl) * K + cb * 8;
    }
    #pragma unroll
    for (int l = 0; l < 2; ++l) {
        brow[l] = l * 32 + w * 8;
        bptr[l] = Bt + (size_t)(n0 + brow[l] + rl) * K + cb * 8;
    }

    int cq = lane >> 4, cl = lane & 15;
    f32x4 acc[4][2];
    #pragma unroll
    for (int mt = 0; mt < 4; ++mt)
        #pragma unroll
        for (int nt = 0; nt < 2; ++nt)
            acc[mt][nt] = (f32x4){0.f, 0.f, 0.f, 0.f};

    #pragma unroll
    for (int l = 0; l < 4; ++l) { gload_lds16(aptr[l], &As[0][arow[l] * 64]); aptr[l] += 64; }
    #pragma unroll
    for (int l = 0; l < 2; ++l) { gload_lds16(bptr[l], &Bs[0][brow[l] * 64]); bptr[l] += 64; }
    __syncthreads();

    int nk = K >> 6;
    for (int k = 0; k < nk; ++k) {
        int cur = k & 1;
        if (k + 1 < nk) {
            #pragma unroll
            for (int l = 0; l < 4; ++l) { gload_lds16(aptr[l], &As[cur ^ 1][arow[l] * 64]); aptr[l] += 64; }
            #pragma unroll
            for (int l = 0; l < 2; ++l) { gload_lds16(bptr[l], &Bs[cur ^ 1][brow[l] * 64]); bptr[l] += 64; }
        }
        #pragma unroll
        for (int s = 0; s < 2; ++s) {
            bf16x8 afr[4], bfr[2];
            #pragma unroll
            for (int mt = 0; mt < 4; ++mt) {
                int r = wm * 64 + mt * 16 + cl;
                int slot = (s * 4 + cq) ^ (r & 7);
                afr[mt] = *(const bf16x8*)&As[cur][r * 64 + slot * 8];
            }
            #pragma unroll
            for (int nt = 0; nt < 2; ++nt) {
                int r = wn * 32 + nt * 16 + cl;
                int slot = (s * 4 + cq) ^ (r & 7);
                bfr[nt] = *(const bf16x8*)&Bs[cur][r * 64 + slot * 8];
            }
            #pragma unroll
            for (int mt = 0; mt < 4; ++mt)
                #pragma unroll
                for (int nt = 0; nt < 2; ++nt)
                    acc[mt][nt] = __builtin_amdgcn_mfma_f32_16x16x32_bf16(
                        afr[mt], bfr[nt], acc[mt][nt], 0, 0, 0);
        }
        __syncthreads();
    }

    #pragma unroll
    for (int mt = 0; mt < 4; ++mt) {
        #pragma unroll
        for (int nt = 0; nt < 2; ++nt) {
            int col = n0 + wn * 32 + nt * 16 + cl;
            float bb = bias[col];
            #pragma unroll
            for (int rg = 0; rg < 4; ++rg) {
                int row = m0 + wm * 64 + mt * 16 + cq * 4 + rg;
                float v = acc[mt][nt][rg] + bb;
                if (EPI & 1) v = fmaxf(v, 0.f);
                if (EPI & 4) v += pe[(row & 127) * 384 + col];
                if (EPI & 2) v += resid[(size_t)row * N + col];
                if (EPI & 8) outF[(size_t)row * N + col] = v;
                if (EPI & 16) outB[(size_t)row * N + col] = f2bf(v);
            }
        }
    }
}

// ---------------- bf16 MFMA GEMM (wide-N): BM=128, BN=128, BK=32 dbuf ------
template <int EPI>
__global__ __launch_bounds__(256) void gemm_bf16_wide(
    const short* __restrict__ A, const short* __restrict__ Bt,
    const float* __restrict__ bias, float* __restrict__ outF,
    short* __restrict__ outB, int M, int N, int K)
{
    __shared__ short As[2][128 * 32];
    __shared__ short Bs[2][128 * 32];
    int tid = threadIdx.x;
    int w = tid >> 6, lane = tid & 63;
    int wm = w >> 1, wn = w & 1;
    int m0 = blockIdx.y * 128, n0 = blockIdx.x * 128;

    int rl = lane >> 2, sl = lane & 3;
    int cb = sl ^ (rl & 3) ^ ((rl >> 2) & 3);
    const short* aptr[2];
    const short* bptr[2];
    int srow[2];
    #pragma unroll
    for (int l = 0; l < 2; ++l) {
        srow[l] = w * 32 + l * 16;
        aptr[l] = A + (size_t)(m0 + srow[l] + rl) * K + cb * 8;
        bptr[l] = Bt + (size_t)(n0 + srow[l] + rl) * K + cb * 8;
    }

    int cq = lane >> 4, cl = lane & 15;
    f32x4 acc[4][4];
    #pragma unroll
    for (int mt = 0; mt < 4; ++mt)
        #pragma unroll
        for (int nt = 0; nt < 4; ++nt)
            acc[mt][nt] = (f32x4){0.f, 0.f, 0.f, 0.f};

    #pragma unroll
    for (int l = 0; l < 2; ++l) {
        gload_lds16(aptr[l], &As[0][srow[l] * 32]);
        gload_lds16(bptr[l], &Bs[0][srow[l] * 32]);
        aptr[l] += 32; bptr[l] += 32;
    }
    __syncthreads();

    int nk = K >> 5;
    for (int k = 0; k < nk; ++k) {
        int cur = k & 1;
        if (k + 1 < nk) {
            #pragma unroll
            for (int l = 0; l < 2; ++l) {
                gload_lds16(aptr[l], &As[cur ^ 1][srow[l] * 32]);
                gload_lds16(bptr[l], &Bs[cur ^ 1][srow[l] * 32]);
                aptr[l] += 32; bptr[l] += 32;
            }
        }
        bf16x8 afr[4], bfr[4];
        #pragma unroll
        for (int mt = 0; mt < 4; ++mt) {
            int r = wm * 64 + mt * 16 + cl;
            int slot = cq ^ (r & 3) ^ ((r >> 2) & 3);
            afr[mt] = *(const bf16x8*)&As[cur][r * 32 + slot * 8];
        }
        #pragma unroll
        for (int nt = 0; nt < 4; ++nt) {
            int r = wn * 64 + nt * 16 + cl;
            int slot = cq ^ (r & 3) ^ ((r >> 2) & 3);
            bfr[nt] = *(const bf16x8*)&Bs[cur][r * 32 + slot * 8];
        }
        #pragma unroll
        for (int mt = 0; mt < 4; ++mt)
            #pragma unroll
            for (int nt = 0; nt < 4; ++nt)
                acc[mt][nt] = __builtin_amdgcn_mfma_f32_16x16x32_bf16(
                    afr[mt], bfr[nt], acc[mt][nt], 0, 0, 0);
        __syncthreads();
    }

    #pragma unroll
    for (int mt = 0; mt < 4; ++mt) {
        #pragma unroll
        for (int nt = 0; nt < 4; ++nt) {
            int col = n0 + wn * 64 + nt * 16 + cl;
            float bb = bias[col];
            #pragma unroll
            for (int rg = 0; rg < 4; ++rg) {
                int row = m0 + wm * 64 + mt * 16 + cq * 4 + rg;
                float v = acc[mt][nt][rg] + bb;
                if (EPI & 1) v = fmaxf(v, 0.f);
                if (EPI & 8) outF[(size_t)row * N + col] = v;
                if (EPI & 16) outB[(size_t)row * N + col] = f2bf(v);
            }
        }
    }
}

// ---------------- fused GEMM + bias + residual + LayerNorm -----------------
// BM=16, BN=384, BK=64 -> grid 512. (BK=32 regressed in R13.)
__global__ __launch_bounds__(256) void gemm_ln(
    const short* __restrict__ A, const short* __restrict__ Bt,
    const float* __restrict__ bias, const float* resid,
    const float* __restrict__ g, const float* __restrict__ be,
    float* t, short* __restrict__ tb, int K)
{
    __shared__ __align__(16) char smem[51200];
    short* As = (short*)smem;              // 16 x 64 bf16 = 2 KB
    short* Bs = (short*)(smem + 2048);     // 384 x 64 bf16 = 48 KB

    int tid = threadIdx.x;
    int w = tid >> 6, lane = tid & 63;
    int m0 = blockIdx.x * 16;
    int rl = lane >> 3, sl = lane & 7;
    int cb = sl ^ rl;

    const short* aptr = A + (size_t)(m0 + w * 8 + rl) * K + cb * 8;
    const short* bptr[12];
    #pragma unroll
    for (int l = 0; l < 12; ++l)
        bptr[l] = Bt + (size_t)(w * 96 + l * 8 + rl) * K + cb * 8;

    int cq = lane >> 4, cl = lane & 15;
    f32x4 acc[6];
    #pragma unroll
    for (int nt = 0; nt < 6; ++nt) acc[nt] = (f32x4){0.f, 0.f, 0.f, 0.f};

    for (int k0 = 0; k0 < K; k0 += 64) {
        if (w < 2) {
            gload_lds16(aptr, &As[(w * 8) * 64]);
            aptr += 64;
        }
        #pragma unroll
        for (int l = 0; l < 12; ++l) {
            gload_lds16(bptr[l], &Bs[(w * 96 + l * 8) * 64]);
            bptr[l] += 64;
        }
        __syncthreads();
        #pragma unroll
        for (int s = 0; s < 2; ++s) {
            bf16x8 afr, bfr[6];
            {
                int r = cl;
                int slot = (s * 4 + cq) ^ (r & 7);
                afr = *(const bf16x8*)&As[r * 64 + slot * 8];
            }
            #pragma unroll
            for (int nt = 0; nt < 6; ++nt) {
                int r = w * 96 + nt * 16 + cl;
                int slot = (s * 4 + cq) ^ (r & 7);
                bfr[nt] = *(const bf16x8*)&Bs[r * 64 + slot * 8];
            }
            #pragma unroll
            for (int nt = 0; nt < 6; ++nt)
                acc[nt] = __builtin_amdgcn_mfma_f32_16x16x32_bf16(
                    afr, bfr[nt], acc[nt], 0, 0, 0);
        }
        __syncthreads();
    }

    // ---- epilogue: y = acc + bias + resid -> LDS (16 x 388 f32) ----
    float* yb = (float*)smem;
    #pragma unroll
    for (int nt = 0; nt < 6; ++nt) {
        int col = w * 96 + nt * 16 + cl;
        float bb = bias[col];
        #pragma unroll
        for (int rg = 0; rg < 4; ++rg) {
            int rloc = cq * 4 + rg;
            yb[rloc * 388 + col] =
                acc[nt][rg] + bb + resid[(size_t)(m0 + rloc) * 384 + col];
        }
    }
    __syncthreads();

    // ---- LayerNorm: 16 threads per row ----
    int rloc = tid >> 4, sub = tid & 15;
    f32x4 vals[6];
    float s = 0.f, s2 = 0.f;
    #pragma unroll
    for (int m = 0; m < 6; ++m) {
        f32x4 vv = *(const f32x4*)&yb[rloc * 388 + m * 64 + sub * 4];
        vals[m] = vv;
        #pragma unroll
        for (int j = 0; j < 4; ++j) {
            s += vv[j];
            s2 = fmaf(vv[j], vv[j], s2);
        }
    }
    s += __shfl_xor(s, 1, 64);  s2 += __shfl_xor(s2, 1, 64);
    s += __shfl_xor(s, 2, 64);  s2 += __shfl_xor(s2, 2, 64);
    s += __shfl_xor(s, 4, 64);  s2 += __shfl_xor(s2, 4, 64);
    s += __shfl_xor(s, 8, 64);  s2 += __shfl_xor(s2, 8, 64);
    float mean = s * (1.f / 384.f);
    float var = s2 * (1.f / 384.f) - mean * mean;
    float inv = rsqrtf(var + 1e-5f);

    size_t ro = (size_t)(m0 + rloc) * 384;
    #pragma unroll
    for (int m = 0; m < 6; ++m) {
        int c0 = m * 64 + sub * 4;
        f32x4 gg = *(const f32x4*)&g[c0];
        f32x4 bb = *(const f32x4*)&be[c0];
        f32x4 ov;
        s16x4 ob2;
        #pragma unroll
        for (int j = 0; j < 4; ++j) {
            float v = (vals[m][j] - mean) * inv * gg[j] + bb[j];
            ov[j] = v;
            ob2[j] = f2bf(v);
        }
        *(f32x4*)&t[ro + c0] = ov;
        *(s16x4*)&tb[ro + c0] = ob2;
    }
}

// ---------------- fused attention per (n,h): MFMA, 4 waves x 32 queries ----
// S = QK^T via 16x16x32 (E=48 -> 2 k-steps, 2nd zero-guarded), exact
// softmax in C-layout (row=cq*4+rg, col=cl), P->LDS (wave-local), V
// transposed once to Vt, PV = 24 MFMA/wave. LDS 47872 B -> 3 blocks/CU.
__global__ __launch_bounds__(256) void attn_kernel(
    const short* __restrict__ qkv, short* __restrict__ o)
{
    __shared__ __align__(16) short lds[23936];
    short* Vt = lds;                  // [48][136] bf16
    short* P  = lds + 6528;           // [4][32][136] bf16 (per wave)

    int tid = threadIdx.x;
    int w = tid >> 6, lane = tid & 63;
    int cq = lane >> 4, cl = lane & 15;
    int n = blockIdx.x >> 3, h = blockIdx.x & 7;
    size_t base = (size_t)n * 147456 + (size_t)h * 48;   // n*128*1152
    const short* qp = qkv + base;
    const short* kp = qkv + base + 384;
    const short* vp = qkv + base + 768;

    // ---- stage Vt: V[key][e] -> Vt[e][key] (stride 136) ----
    {
        int key = tid >> 1, half = tid & 1;
        const short* vsrc = vp + (size_t)key * 1152 + half * 24;
        #pragma unroll
        for (int e4 = 0; e4 < 6; ++e4) {
            s16x4 vv = *(const s16x4*)(vsrc + e4 * 4);
            int e0 = half * 24 + e4 * 4;
            Vt[(e0 + 0) * 136 + key] = vv[0];
            Vt[(e0 + 1) * 136 + key] = vv[1];
            Vt[(e0 + 2) * 136 + key] = vv[2];
            Vt[(e0 + 3) * 136 + key] = vv[3];
        }
    }

    // ---- Q fragments for this wave (queries w*32 + mt*16 + cl) ----
    const bf16x8 zf = (bf16x8){0, 0, 0, 0, 0, 0, 0, 0};
    bf16x8 qf[2][2];
    #pragma unroll
    for (int mt = 0; mt < 2; ++mt) {
        const short* qrow = qp + (size_t)(w * 32 + mt * 16 + cl) * 1152;
        qf[mt][0] = *(const bf16x8*)(qrow + cq * 8);
        qf[mt][1] = (cq < 2) ? *(const bf16x8*)(qrow + 32 + cq * 8) : zf;
    }

    // ---- S = QK^T: 2 m-tiles x 8 k-tiles, 2 e-steps ----
    f32x4 sacc[2][8];
    #pragma unroll
    for (int mt = 0; mt < 2; ++mt)
        #pragma unroll
        for (int kt = 0; kt < 8; ++kt)
            sacc[mt][kt] = (f32x4){0.f, 0.f, 0.f, 0.f};

    #pragma unroll
    for (int kt = 0; kt < 8; ++kt) {
        const short* krow = kp + (size_t)(kt * 16 + cl) * 1152;
        bf16x8 kf0 = *(const bf16x8*)(krow + cq * 8);
        bf16x8 kf1 = (cq < 2) ? *(const bf16x8*)(krow + 32 + cq * 8) : zf;
        #pragma unroll
        for (int mt = 0; mt < 2; ++mt) {
            sacc[mt][kt] = __builtin_amdgcn_mfma_f32_16x16x32_bf16(
                qf[mt][0], kf0, sacc[mt][kt], 0, 0, 0);
            sacc[mt][kt] = __builtin_amdgcn_mfma_f32_16x16x32_bf16(
                qf[mt][1], kf1, sacc[mt][kt], 0, 0, 0);
        }
    }
    __syncthreads();   // Vt ready (placed after MFMA to overlap staging)

    // ---- softmax (exact, per row): lane holds rows {mt*16+cq*4+rg} ----
    const float temp = 0.14433756729740643f;  // 1/sqrt(48)
    short* Pw = P + w * 4352;
    float denom[2][4];
    #pragma unroll
    for (int mt = 0; mt < 2; ++mt) {
        #pragma unroll
        for (int rg = 0; rg < 4; ++rg) {
            float m0 = sacc[mt][0][rg];
            #pragma unroll
            for (int kt = 1; kt < 8; ++kt) m0 = fmaxf(m0, sacc[mt][kt][rg]);
            m0 = fmaxf(m0, __shfl_xor(m0, 1, 64));
            m0 = fmaxf(m0, __shfl_xor(m0, 2, 64));
            m0 = fmaxf(m0, __shfl_xor(m0, 4, 64));
            m0 = fmaxf(m0, __shfl_xor(m0, 8, 64));
            int row = mt * 16 + cq * 4 + rg;
            float se = 0.f;
            #pragma unroll
            for (int kt = 0; kt < 8; ++kt) {
                float p = __expf(temp * (sacc[mt][kt][rg] - m0));
                se += p;
                Pw[row * 136 + kt * 16 + cl] = f2bf(p);
            }
            se += __shfl_xor(se, 1, 64);
            se += __shfl_xor(se, 2, 64);
            se += __shfl_xor(se, 4, 64);
            se += __shfl_xor(se, 8, 64);
            denom[mt][rg] = se;
        }
    }

    // ---- PV: 2 m-tiles x 3 n-tiles (e=48) x 4 k-steps (keys=128) ----
    f32x4 oacc[2][3];
    #pragma unroll
    for (int mt = 0; mt < 2; ++mt)
        #pragma unroll
        for (int nt = 0; nt < 3; ++nt)
            oacc[mt][nt] = (f32x4){0.f, 0.f, 0.f, 0.f};

    #pragma unroll
    for (int ks = 0; ks < 4; ++ks) {
        bf16x8 paf[2];
        #pragma unroll
        for (int mt = 0; mt < 2; ++mt)
            paf[mt] = *(const bf16x8*)&Pw[(mt * 16 + cl) * 136 + ks * 32 + cq * 8];
        #pragma unroll
        for (int nt = 0; nt < 3; ++nt) {
            bf16x8 vf = *(const bf16x8*)&Vt[(nt * 16 + cl) * 136 + ks * 32 + cq * 8];
            #pragma unroll
            for (int mt = 0; mt < 2; ++mt)
                oacc[mt][nt] = __builtin_amdgcn_mfma_f32_16x16x32_bf16(
                    paf[mt], vf, oacc[mt][nt], 0, 0, 0);
        }
    }

    // ---- epilogue: scale by 1/denom, write o bf16 ----
    #pragma unroll
    for (int mt = 0; mt < 2; ++mt) {
        #pragma unroll
        for (int rg = 0; rg < 4; ++rg) {
            float inv = 1.f / denom[mt][rg];
            int qrow = w * 32 + mt * 16 + cq * 4 + rg;
            short* op = o + ((size_t)n * 128 + qrow) * 384 + h * 48;
            #pragma unroll
            for (int nt = 0; nt < 3; ++nt)
                op[nt * 16 + cl] = f2bf(oacc[mt][nt][rg] * inv);
        }
    }
}

// ---------------- classifier head ------------------------------------------
__global__ __launch_bounds__(384) void head_kernel(
    const float* __restrict__ t, const float* __restrict__ cls_w,
    const float* __restrict__ cls_b, float* __restrict__ out)
{
    int n = blockIdx.x, d = threadIdx.x;
    float s = 0.f;
    for (int l = 0; l < 128; ++l) s += t[((size_t)n * 128 + l) * 384 + d];
    float p = s * (1.f / 128.f) * cls_w[d];
    #pragma unroll
    for (int off = 32; off > 0; off >>= 1) p += __shfl_xor(p, off, 64);
    __shared__ float red[6];
    if ((threadIdx.x & 63) == 0) red[threadIdx.x >> 6] = p;
    __syncthreads();
    if (threadIdx.x == 0) {
        float tot = red[0] + red[1] + red[2] + red[3] + red[4] + red[5];
        out[n] = tot + cls_b[0];
    }
}

// ---------------------------------------------------------------------------
extern "C" void kernel_launch(void* const* d_in, const int* in_sizes, int n_in,
                              void* d_out, int out_size, void* d_ws, size_t ws_size,
                              hipStream_t stream) {
    (void)n_in; (void)out_size; (void)ws_size;
    const float* x   = (const float*)d_in[0];
    const float* cw0 = (const float*)d_in[1];
    const float* cb0 = (const float*)d_in[2];
    const float* cw1 = (const float*)d_in[3];
    const float* cb1 = (const float*)d_in[4];
    const float* cw2 = (const float*)d_in[5];
    const float* cb2 = (const float*)d_in[6];
    const float* ew  = (const float*)d_in[7];
    const float* eb  = (const float*)d_in[8];
    bool dict_order = (in_sizes[10] == 589824);
    const float *Wq, *Wk, *Wv, *Wo, *W1, *W2, *bq, *bk, *bv, *bo, *b1, *b2;
    if (dict_order) {
        Wq = (const float*)d_in[9];  Wk = (const float*)d_in[10];
        Wv = (const float*)d_in[11]; Wo = (const float*)d_in[12];
        W1 = (const float*)d_in[13]; W2 = (const float*)d_in[14];
        bq = (const float*)d_in[15]; bk = (const float*)d_in[16];
        bv = (const float*)d_in[17]; bo = (const float*)d_in[18];
        b1 = (const float*)d_in[19]; b2 = (const float*)d_in[20];
    } else {
        Wq = (const float*)d_in[9];  bq = (const float*)d_in[10];
        Wk = (const float*)d_in[11]; bk = (const float*)d_in[12];
        Wv = (const float*)d_in[13]; bv = (const float*)d_in[14];
        Wo = (const float*)d_in[15]; bo = (const float*)d_in[16];
        W1 = (const float*)d_in[17]; b1 = (const float*)d_in[18];
        W2 = (const float*)d_in[19]; b2 = (const float*)d_in[20];
    }
    const float* g1  = (const float*)d_in[21];
    const float* be1 = (const float*)d_in[22];
    const float* g2  = (const float*)d_in[23];
    const float* be2 = (const float*)d_in[24];
    const float* clw = (const float*)d_in[25];
    const float* clb = (const float*)d_in[26];

    // ---- workspace layout (bytes) ----
    char* wp = (char*)d_ws;
    float* pe    = (float*)wp; wp += 196608;      // 128*384 f32
    short* featb = (short*)wp; wp += 33554432;    // 8192*2048 bf16 (reused as FFN hidden)
    float* t     = (float*)wp; wp += 12582912;    // 8192*384 f32
    short* tb    = (short*)wp; wp += 6291456;     // 8192*384 bf16
    short* qkvb  = (short*)wp; wp += 18874368;    // 8192*1152 bf16
    short* ob    = (short*)wp; wp += 6291456;     // 8192*384 bf16 (attn out)
    short* ewT   = (short*)wp; wp += 1572864;     // 384 x 2048
    short* WqkvT = (short*)wp; wp += 3538944;     // 4 x 1152 x 384
    short* WoT   = (short*)wp; wp += 1179648;     // 4 x 384 x 384
    short* W1T   = (short*)wp; wp += 4718592;     // 4 x 1536 x 384
    short* W2T   = (short*)wp; wp += 4718592;     // 4 x 384 x 1536
    float* bqkv  = (float*)wp; wp += 18432;       // 4 x 1152 f32
    short* w2T   = (short*)wp; wp += 16384;       // 64 x 128 bf16 (conv2, paired-shift layout)
    short* hb    = featb;                         // FFN hidden 8192*1536 bf16

    const int ROWS = 8192;

    pe_kernel<<<128, 384, 0, stream>>>(pe);
    wcvt_kernel<<<dim3(64, 12, 1), 256, 0, stream>>>(ew, ewT, 2048, 384, 0, 0, 0);
    qkvcvt_kernel<<<dim3(12, 12, 12), 256, 0, stream>>>(Wq, Wk, Wv, WqkvT);
    wcvt_kernel<<<dim3(12, 12, 4), 256, 0, stream>>>(Wo, WoT, 384, 384, 0, 147456, 147456);
    wcvt_kernel<<<dim3(12, 48, 4), 256, 0, stream>>>(W1, W1T, 384, 1536, 0, 589824, 589824);
    wcvt_kernel<<<dim3(48, 12, 4), 256, 0, stream>>>(W2, W2T, 1536, 384, 0, 589824, 589824);
    biascat_kernel<<<4, 384, 0, stream>>>(bq, bk, bv, bqkv);
    w2cvt_kernel<<<32, 256, 0, stream>>>(cw2, w2T);
    cnn_kernel<<<2048, 256, 0, stream>>>(x, cw0, cb0, cw1, cb1, w2T, cb2, featb);

    // t/tb = relu(feat @ ew + eb) + pe
    gemm_bf16<29><<<dim3(6, 64), 256, 0, stream>>>(featb, ewT, eb, nullptr, pe,
                                                   t, tb, ROWS, 384, 2048);
    for (int i = 0; i < 4; ++i) {
        const short* WqkvTi = WqkvT + (size_t)i * 442368;
        const short* WoTi = WoT + (size_t)i * 147456;
        const short* W1Ti = W1T + (size_t)i * 589824;
        const short* W2Ti = W2T + (size_t)i * 589824;
        gemm_bf16_wide<16><<<dim3(9, 64), 256, 0, stream>>>(tb, WqkvTi,
            bqkv + i * 1152, nullptr, qkvb, ROWS, 1152, 384);
        attn_kernel<<<512, 256, 0, stream>>>(qkvb, ob);
        // t/tb = LN(o @ Wo + bo + t)
        gemm_ln<<<512, 256, 0, stream>>>(ob, WoTi, bo + i * 384, t,
            g1 + i * 384, be1 + i * 384, t, tb, 384);
        // hidden = relu(t @ W1 + b1)
        gemm_bf16_wide<17><<<dim3(12, 64), 256, 0, stream>>>(tb, W1Ti,
            b1 + i * 1536, nullptr, hb, ROWS, 1536, 384);
        // t/tb = LN(hidden @ W2 + b2 + t)
        gemm_ln<<<512, 256, 0, stream>>>(hb, W2Ti, b2 + i * 384, t,
            g2 + i * 384, be2 + i * 384, t, tb, 1536);
    }
    head_kernel<<<64, 384, 0, stream>>>(t, clw, clb, (float*)d_out);
}

// Round 7
// 621.527 us; speedup vs baseline: 1.2806x; 1.0143x over previous
//
#include <hip/hip_runtime.h>
#include <math.h>

// ---------------------------------------------------------------------------
// N=64, L=128, W=256, D=384, H=8, E=48, NL=4, DFF=1536, rows = N*L = 8192
// GEMMs: bf16 MFMA 16x16x32, A [M][K] bf16 row-major, Bt [N][K] bf16.
// R24: gemm_ln reshape BM=16 -> BM=32, 512 threads, grid 256, dbuf LDS.
// Old shape streamed the full 384xK B panel per 16 output rows: W2 = 604MB
// L2 B-traffic/dispatch (>=17us floor), Wo = 147MB, single-buffered with
// 2 barriers/k-iter. New: B-traffic halved, 1 barrier/k-iter, loads in
// flight during MFMA. Numerics bit-identical (same per-output K order,
// same LN 16-thread/row reduction).
// Post-mortem R23: attn VALU->MFMA: 729->630us; cnn now 51us (top dispatch),
// transformer GEMMs ~565us total. attn absmax held at 0.0.
// ---------------------------------------------------------------------------

typedef float f32x4 __attribute__((ext_vector_type(4)));
typedef short bf16x8 __attribute__((ext_vector_type(8)));
typedef short s16x4 __attribute__((ext_vector_type(4)));

__device__ __forceinline__ short f2bf(float f) {
    union { float f; unsigned u; } c; c.f = f;
    unsigned r = (c.u + 0x7FFFu + ((c.u >> 16) & 1u)) >> 16;
    return (short)r;
}
__device__ __forceinline__ float bf2f(short s) {
    union { unsigned u; float f; } c;
    c.u = ((unsigned)(unsigned short)s) << 16;
    return c.f;
}

__device__ __forceinline__ void gload_lds16(const void* g, void* l) {
    __builtin_amdgcn_global_load_lds(
        (const __attribute__((address_space(1))) unsigned int*)g,
        (__attribute__((address_space(3))) unsigned int*)l,
        16, 0, 0);
}

// ---------------- positional encoding table: pe[l][d] ----------------------
__global__ __launch_bounds__(384) void pe_kernel(float* __restrict__ pe) {
    int l = blockIdx.x, d = threadIdx.x;
    int i2 = d >> 1;
    float ang = (float)l * expf(-(2.0f * (float)i2 / 384.0f) * 9.210340371976184f);
    pe[l * 384 + d] = (d & 1) ? cosf(ang) : sinf(ang);
}

// ---------------- weight convert+transpose: W fp32 [K][N] -> bf16 [N][K] ---
__global__ __launch_bounds__(256) void wcvt_kernel(
    const float* __restrict__ W, short* __restrict__ Wt, int K, int N,
    int dstOff, int srcZ, int dstZ)
{
    __shared__ float tile[32][33];
    int kb = blockIdx.x * 32, nb = blockIdx.y * 32;
    const float* Wp = W + (size_t)blockIdx.z * srcZ;
    short* Wtp = Wt + (size_t)blockIdx.z * dstZ + dstOff;
    int tx = threadIdx.x & 31, ty = threadIdx.x >> 5;
    #pragma unroll
    for (int r = ty; r < 32; r += 8)
        tile[r][tx] = Wp[(size_t)(kb + r) * N + nb + tx];
    __syncthreads();
    #pragma unroll
    for (int r = ty; r < 32; r += 8)
        Wtp[(size_t)(nb + r) * K + kb + tx] = f2bf(tile[tx][r]);
}

// ---------------- Wq/Wk/Wv -> WqkvT in one dispatch (z = layer*3+which) ----
__global__ __launch_bounds__(256) void qkvcvt_kernel(
    const float* __restrict__ Wq, const float* __restrict__ Wk,
    const float* __restrict__ Wv, short* __restrict__ WqkvT)
{
    __shared__ float tile[32][33];
    int kb = blockIdx.x * 32, nb = blockIdx.y * 32;
    int layer = blockIdx.z / 3, which = blockIdx.z - layer * 3;
    const float* Wp = (which == 0 ? Wq : (which == 1 ? Wk : Wv)) +
                      (size_t)layer * 147456;
    short* Wtp = WqkvT + (size_t)layer * 442368 + (size_t)which * 147456;
    int tx = threadIdx.x & 31, ty = threadIdx.x >> 5;
    #pragma unroll
    for (int r = ty; r < 32; r += 8)
        tile[r][tx] = Wp[(size_t)(kb + r) * 384 + nb + tx];
    __syncthreads();
    #pragma unroll
    for (int r = ty; r < 32; r += 8)
        Wtp[(size_t)(nb + r) * 384 + kb + tx] = f2bf(tile[tx][r]);
}

// ---------------- conv2 weights -> paired-shift layout [64][128] -----------
// w2p[c][pr*32 + q*8 + j] = w2[c][ci*7 + sft], ci=(q&1)*8+j, sft=2*pr+(q>>1);
// sft==7 (pair 3, upper half) -> 0. Matches stage-C A-fragment reads.
__global__ __launch_bounds__(256) void w2cvt_kernel(
    const float* __restrict__ w2, short* __restrict__ w2T)
{
    int idx = blockIdx.x * 256 + threadIdx.x;   // 64*128 = 8192
    int c = idx >> 7, r = idx & 127;
    int pr = r >> 5, q = (r >> 3) & 3, j = r & 7;
    int ci = (q & 1) * 8 + j;
    int sft = 2 * pr + (q >> 1);
    w2T[idx] = (sft < 7) ? f2bf(w2[c * 112 + ci * 7 + sft]) : (short)0;
}

// ---------------- concatenated qkv bias: bqkv[l][1152] ---------------------
__global__ __launch_bounds__(384) void biascat_kernel(
    const float* __restrict__ bq, const float* __restrict__ bk,
    const float* __restrict__ bv, float* __restrict__ bqkv)
{
    int l = blockIdx.x, j = threadIdx.x;
    bqkv[l * 1152 + j] = bq[l * 384 + j];
    bqkv[l * 1152 + 384 + j] = bk[l * 384 + j];
    bqkv[l * 1152 + 768 + j] = bv[l * 384 + j];
}

// ---------------- fused CNN window encoder: 4 windows/block, 1 barrier -----
// LDS layout (26880 B -> 5 blocks/CU):
//   [0     .. 4224)   xs[4][264] f32   (x at idx j+4, zeros [0..3],[260..263])
//   [4224  .. 13056)  p0[4][4][138] f32 (conv0 out at idx j+3, zeros [0..2]
//                     and [131..133]; stride 138)
//   [13056 .. 26880)  p1T[4][72][24] bf16 (row=pos+3, pad rows zeroed)
__global__ __launch_bounds__(256, 4) void cnn_kernel(
    const float* __restrict__ x,
    const float* __restrict__ w0, const float* __restrict__ b0,
    const float* __restrict__ w1, const float* __restrict__ b1,
    const short* __restrict__ w2T, const float* __restrict__ b2,
    short* __restrict__ feat)
{
    __shared__ __align__(16) char smem[26880];
    float* xs  = (float*)smem;                    // [4][264]
    float* p0  = (float*)(smem + 4224);           // [4][4][138]
    short* p1T = (short*)(smem + 13056);          // [4][72][24]

    int tid = threadIdx.x;
    int w = tid >> 6, lane = tid & 63;
    size_t win = (size_t)blockIdx.x * 4 + w;
    int cq = lane >> 4, cl = lane & 15;

    float* xs_w = xs + w * 264;
    float* p0_w = p0 + w * 552;                   // 4*138
    short* p1T_w = p1T + w * 1728;

    // ---- per-wave setup: weights to regs (L2-broadcast), xs fill ----
    int ca = lane & 3;
    int cb = lane & 15, g = lane >> 4;
    float w0r[7], w1r[4][7];
    float b0r = b0[ca];
    float b1r = b1[cb];
    #pragma unroll
    for (int k = 0; k < 7; ++k) w0r[k] = w0[ca * 7 + k];
    #pragma unroll
    for (int ci = 0; ci < 4; ++ci)
        #pragma unroll
        for (int k = 0; k < 7; ++k) w1r[ci][k] = w1[(cb * 4 + ci) * 7 + k];

    {
        f32x4 v = *(const f32x4*)(x + win * 256 + lane * 4);
        *(f32x4*)&xs_w[4 + lane * 4] = v;
        if (lane < 2) *(f32x4*)&xs_w[lane * 260] = (f32x4){0.f, 0.f, 0.f, 0.f};
    }

    // ---- stage A (wave-local): conv0 + relu + pool2 -> p0_w[c][pp+3] ----
    {
        int pa = lane >> 2;
        #pragma unroll
        for (int t2 = 0; t2 < 8; ++t2) {
            int pp = t2 * 16 + pa;
            float rv[9];
            #pragma unroll
            for (int u = 0; u < 9; ++u) rv[u] = xs_w[2 * pp + u + 1];
            float a0 = b0r, a1 = b0r;
            #pragma unroll
            for (int k = 0; k < 7; ++k) {
                a0 = fmaf(w0r[k], rv[k], a0);
                a1 = fmaf(w0r[k], rv[k + 1], a1);
            }
            p0_w[ca * 138 + pp + 3] = fmaxf(fmaxf(a0, a1), 0.f);
        }
        if (lane < 4) {
            p0_w[lane * 138 + 0] = 0.f;
            p0_w[lane * 138 + 1] = 0.f;
            p0_w[lane * 138 + 2] = 0.f;
            p0_w[lane * 138 + 131] = 0.f;
            p0_w[lane * 138 + 132] = 0.f;
            p0_w[lane * 138 + 133] = 0.f;
        }
    }

    // ---- stage B (wave-local): conv1 + relu + pool2 -> p1T_w[3+pos][c] ----
    #pragma unroll
    for (int cc = 0; cc < 4; ++cc) {
        int cci = (cc + g) & 3;
        int j0 = g * 32 + cci * 8;           // padded pre-pool base
        float acc[8];
        #pragma unroll
        for (int m = 0; m < 8; ++m) acc[m] = b1r;
        #pragma unroll
        for (int ci = 0; ci < 4; ++ci) {
            float rv[14];
            #pragma unroll
            for (int u = 0; u < 14; ++u) rv[u] = p0_w[ci * 138 + j0 + u];
            #pragma unroll
            for (int k = 0; k < 7; ++k) {
                float ww = w1r[ci][k];
                #pragma unroll
                for (int m = 0; m < 8; ++m) acc[m] = fmaf(ww, rv[m + k], acc[m]);
            }
        }
        int po = g * 16 + cci * 4;
        #pragma unroll
        for (int m = 0; m < 4; ++m)
            p1T_w[(3 + po + m) * 24 + cb] =
                f2bf(fmaxf(fmaxf(acc[2 * m], acc[2 * m + 1]), 0.f));
    }
    // zero p1T pad rows (own window)
    {
        int* pz = (int*)p1T_w;
        if (lane < 36) pz[lane] = 0;
        if (lane < 60) pz[804 + lane] = 0;
    }
    __syncthreads();   // the ONLY barrier: all 4 windows' p1T ready

    // ---- stage C: conv2 as 4 paired-shift GEMMs, all 4 windows/wave ----
    f32x4 acc[4][4];   // [window v][mt]
    #pragma unroll
    for (int v = 0; v < 4; ++v)
        #pragma unroll
        for (int mt = 0; mt < 4; ++mt)
            acc[v][mt] = (f32x4){0.f, 0.f, 0.f, 0.f};

    {
        const short* bpb = p1T + (w * 16 + cl + (cq >> 1)) * 24 + (cq & 1) * 8;
        #pragma unroll
        for (int pr = 0; pr < 4; ++pr) {
            bf16x8 bfr[4];
            #pragma unroll
            for (int v = 0; v < 4; ++v)
                bfr[v] = *(const bf16x8*)&bpb[v * 1728 + pr * 48];
            #pragma unroll
            for (int mt = 0; mt < 4; ++mt) {
                bf16x8 af = *(const bf16x8*)&w2T[(mt * 16 + cl) * 128 +
                                                 pr * 32 + cq * 8];
                #pragma unroll
                for (int v = 0; v < 4; ++v)
                    acc[v][mt] = __builtin_amdgcn_mfma_f32_16x16x32_bf16(
                        af, bfr[v], acc[v][mt], 0, 0, 0);
            }
        }
    }

    // ---- epilogue: pool pairs via shfl, store bf16 (per window) ----
    int iev = (w * 16 + cl) >> 1;
    #pragma unroll
    for (int v = 0; v < 4; ++v) {
        short* fp = feat + ((size_t)blockIdx.x * 4 + v) * 2048;
        #pragma unroll
        for (int mt = 0; mt < 4; ++mt) {
            #pragma unroll
            for (int rg = 0; rg < 4; ++rg) {
                float vv = acc[v][mt][rg];
                float v2 = __shfl_xor(vv, 1, 64);
                if ((cl & 1) == 0) {
                    int c = mt * 16 + cq * 4 + rg;
                    float pv = fmaxf(fmaxf(vv, v2) + b2[c], 0.f);
                    fp[c * 32 + iev] = f2bf(pv);
                }
            }
        }
    }
}

// ---------------- bf16 MFMA GEMM (thin-N): BM=128, BN=64, double-buffered --
// EPI bits: 1=relu, 2=+resid(f32), 4=+pe, 8=write f32, 16=write bf16
template <int EPI>
__global__ __launch_bounds__(256) void gemm_bf16(
    const short* __restrict__ A, const short* __restrict__ Bt,
    const float* __restrict__ bias, const float* __restrict__ resid,
    const float* __restrict__ pe, float* __restrict__ outF,
    short* __restrict__ outB, int M, int N, int K)
{
    __shared__ short As[2][128 * 64];
    __shared__ short Bs[2][64 * 64];
    int tid = threadIdx.x;
    int w = tid >> 6, lane = tid & 63;
    int wm = w >> 1, wn = w & 1;
    int m0 = blockIdx.y * 128, n0 = blockIdx.x * 64;

    int rl = lane >> 3, sl = lane & 7;
    int cb = sl ^ rl;
    const short* aptr[4];
    const short* bptr[2];
    int arow[4], brow[2];
    #pragma unroll
    for (int l = 0; l < 4; ++l) {
        arow[l] = l * 32 + w * 8;
        aptr[l] = A + (size_t)(m0 + arow[l] + rl) * K + cb * 8;
    }
    #pragma unroll
    for (int l = 0; l < 2; ++l) {
        brow[l] = l * 32 + w * 8;
        bptr[l] = Bt + (size_t)(n0 + brow[l] + rl) * K + cb * 8;
    }

    int cq = lane >> 4, cl = lane & 15;
    f32x4 acc[4][2];
    #pragma unroll
    for (int mt = 0; mt < 4; ++mt)
        #pragma unroll
        for (int nt = 0; nt < 2; ++nt)
            acc[mt][nt] = (f32x4){0.f, 0.f, 0.f, 0.f};

    #pragma unroll
    for (int l = 0; l < 4; ++l) { gload_lds16(aptr[l], &As[0][arow[l] * 64]); aptr[l] += 64; }
    #pragma unroll
    for (int l = 0; l < 2; ++l) { gload_lds16(bptr[l], &Bs[0][brow[l] * 64]); bptr[l] += 64; }
    __syncthreads();

    int nk = K >> 6;
    for (int k = 0; k < nk; ++k) {
        int cur = k & 1;
        if (k + 1 < nk) {
            #pragma unroll
            for (int l = 0; l < 4; ++l) { gload_lds16(aptr[l], &As[cur ^ 1][arow[l] * 64]); aptr[l] += 64; }
            #pragma unroll
            for (int l = 0; l < 2; ++l) { gload_lds16(bptr[l], &Bs[cur ^ 1][brow[l] * 64]); bptr[l] += 64; }
        }
        #pragma unroll
        for (int s = 0; s < 2; ++s) {
            bf16x8 afr[4], bfr[2];
            #pragma unroll
            for (int mt = 0; mt < 4; ++mt) {
                int r = wm * 64 + mt * 16 + cl;
                int slot = (s * 4 + cq) ^ (r & 7);
                afr[mt] = *(const bf16x8*)&As[cur][r * 64 + slot * 8];
            }
            #pragma unroll
            for (int nt = 0; nt < 2; ++nt) {
                int r = wn * 32 + nt * 16 + cl;
                int slot = (s * 4 + cq) ^ (r & 7);
                bfr[nt] = *(const bf16x8*)&Bs[cur][r * 64 + slot * 8];
            }
            #pragma unroll
            for (int mt = 0; mt < 4; ++mt)
                #pragma unroll
                for (int nt = 0; nt < 2; ++nt)
                    acc[mt][nt] = __builtin_amdgcn_mfma_f32_16x16x32_bf16(
                        afr[mt], bfr[nt], acc[mt][nt], 0, 0, 0);
        }
        __syncthreads();
    }

    #pragma unroll
    for (int mt = 0; mt < 4; ++mt) {
        #pragma unroll
        for (int nt = 0; nt < 2; ++nt) {
            int col = n0 + wn * 32 + nt * 16 + cl;
            float bb = bias[col];
            #pragma unroll
            for (int rg = 0; rg < 4; ++rg) {
                int row = m0 + wm * 64 + mt * 16 + cq * 4 + rg;
                float v = acc[mt][nt][rg] + bb;
                if (EPI & 1) v = fmaxf(v, 0.f);
                if (EPI & 4) v += pe[(row & 127) * 384 + col];
                if (EPI & 2) v += resid[(size_t)row * N + col];
                if (EPI & 8) outF[(size_t)row * N + col] = v;
                if (EPI & 16) outB[(size_t)row * N + col] = f2bf(v);
            }
        }
    }
}

// ---------------- bf16 MFMA GEMM (wide-N): BM=128, BN=128, BK=32 dbuf ------
template <int EPI>
__global__ __launch_bounds__(256) void gemm_bf16_wide(
    const short* __restrict__ A, const short* __restrict__ Bt,
    const float* __restrict__ bias, float* __restrict__ outF,
    short* __restrict__ outB, int M, int N, int K)
{
    __shared__ short As[2][128 * 32];
    __shared__ short Bs[2][128 * 32];
    int tid = threadIdx.x;
    int w = tid >> 6, lane = tid & 63;
    int wm = w >> 1, wn = w & 1;
    int m0 = blockIdx.y * 128, n0 = blockIdx.x * 128;

    int rl = lane >> 2, sl = lane & 3;
    int cb = sl ^ (rl & 3) ^ ((rl >> 2) & 3);
    const short* aptr[2];
    const short* bptr[2];
    int srow[2];
    #pragma unroll
    for (int l = 0; l < 2; ++l) {
        srow[l] = w * 32 + l * 16;
        aptr[l] = A + (size_t)(m0 + srow[l] + rl) * K + cb * 8;
        bptr[l] = Bt + (size_t)(n0 + srow[l] + rl) * K + cb * 8;
    }

    int cq = lane >> 4, cl = lane & 15;
    f32x4 acc[4][4];
    #pragma unroll
    for (int mt = 0; mt < 4; ++mt)
        #pragma unroll
        for (int nt = 0; nt < 4; ++nt)
            acc[mt][nt] = (f32x4){0.f, 0.f, 0.f, 0.f};

    #pragma unroll
    for (int l = 0; l < 2; ++l) {
        gload_lds16(aptr[l], &As[0][srow[l] * 32]);
        gload_lds16(bptr[l], &Bs[0][srow[l] * 32]);
        aptr[l] += 32; bptr[l] += 32;
    }
    __syncthreads();

    int nk = K >> 5;
    for (int k = 0; k < nk; ++k) {
        int cur = k & 1;
        if (k + 1 < nk) {
            #pragma unroll
            for (int l = 0; l < 2; ++l) {
                gload_lds16(aptr[l], &As[cur ^ 1][srow[l] * 32]);
                gload_lds16(bptr[l], &Bs[cur ^ 1][srow[l] * 32]);
                aptr[l] += 32; bptr[l] += 32;
            }
        }
        bf16x8 afr[4], bfr[4];
        #pragma unroll
        for (int mt = 0; mt < 4; ++mt) {
            int r = wm * 64 + mt * 16 + cl;
            int slot = cq ^ (r & 3) ^ ((r >> 2) & 3);
            afr[mt] = *(const bf16x8*)&As[cur][r * 32 + slot * 8];
        }
        #pragma unroll
        for (int nt = 0; nt < 4; ++nt) {
            int r = wn * 64 + nt * 16 + cl;
            int slot = cq ^ (r & 3) ^ ((r >> 2) & 3);
            bfr[nt] = *(const bf16x8*)&Bs[cur][r * 32 + slot * 8];
        }
        #pragma unroll
        for (int mt = 0; mt < 4; ++mt)
            #pragma unroll
            for (int nt = 0; nt < 4; ++nt)
                acc[mt][nt] = __builtin_amdgcn_mfma_f32_16x16x32_bf16(
                    afr[mt], bfr[nt], acc[mt][nt], 0, 0, 0);
        __syncthreads();
    }

    #pragma unroll
    for (int mt = 0; mt < 4; ++mt) {
        #pragma unroll
        for (int nt = 0; nt < 4; ++nt) {
            int col = n0 + wn * 64 + nt * 16 + cl;
            float bb = bias[col];
            #pragma unroll
            for (int rg = 0; rg < 4; ++rg) {
                int row = m0 + wm * 64 + mt * 16 + cq * 4 + rg;
                float v = acc[mt][nt][rg] + bb;
                if (EPI & 1) v = fmaxf(v, 0.f);
                if (EPI & 8) outF[(size_t)row * N + col] = v;
                if (EPI & 16) outB[(size_t)row * N + col] = f2bf(v);
            }
        }
    }
}

// ---------------- fused GEMM + bias + residual + LayerNorm -----------------
// R24: BM=32, BN=384, BK=64, 512 threads, grid 256, double-buffered LDS.
// Wave w owns cols w*48..+47 (3 n-tiles) x 2 m-tiles. Numerics identical
// to the BM=16 version (same per-output K order, same LN reduction).
__global__ __launch_bounds__(512) void gemm_ln(
    const short* __restrict__ A, const short* __restrict__ Bt,
    const float* __restrict__ bias, const float* resid,
    const float* __restrict__ g, const float* __restrict__ be,
    float* t, short* __restrict__ tb, int K)
{
    __shared__ __align__(16) char smem[106496];
    short* As0 = (short*)smem;                 // [2][32*64]  = 8 KB
    short* Bs0 = (short*)(smem + 8192);        // [2][384*64] = 96 KB

    int tid = threadIdx.x;
    int w = tid >> 6, lane = tid & 63;
    int m0 = blockIdx.x * 32;
    int rl = lane >> 3, sl = lane & 7;
    int cb = sl ^ rl;

    const short* aptr = A + (size_t)(m0 + (w & 3) * 8 + rl) * K + cb * 8;
    const short* bptr[6];
    #pragma unroll
    for (int l = 0; l < 6; ++l)
        bptr[l] = Bt + (size_t)(w * 48 + l * 8 + rl) * K + cb * 8;

    int cq = lane >> 4, cl = lane & 15;
    f32x4 acc[2][3];
    #pragma unroll
    for (int mt = 0; mt < 2; ++mt)
        #pragma unroll
        for (int nt = 0; nt < 3; ++nt)
            acc[mt][nt] = (f32x4){0.f, 0.f, 0.f, 0.f};

    // prologue: stage buffer 0
    if (w < 4) { gload_lds16(aptr, &As0[(w * 8) * 64]); aptr += 64; }
    #pragma unroll
    for (int l = 0; l < 6; ++l) {
        gload_lds16(bptr[l], &Bs0[(w * 48 + l * 8) * 64]);
        bptr[l] += 64;
    }
    __syncthreads();

    int nk = K >> 6;
    for (int k = 0; k < nk; ++k) {
        int cur = k & 1;
        if (k + 1 < nk) {
            if (w < 4) { gload_lds16(aptr, &As0[(cur ^ 1) * 2048 + (w * 8) * 64]); aptr += 64; }
            #pragma unroll
            for (int l = 0; l < 6; ++l) {
                gload_lds16(bptr[l], &Bs0[(cur ^ 1) * 24576 + (w * 48 + l * 8) * 64]);
                bptr[l] += 64;
            }
        }
        const short* As = As0 + cur * 2048;
        const short* Bs = Bs0 + cur * 24576;
        #pragma unroll
        for (int s = 0; s < 2; ++s) {
            bf16x8 afr[2], bfr[3];
            #pragma unroll
            for (int mt = 0; mt < 2; ++mt) {
                int r = mt * 16 + cl;
                int slot = (s * 4 + cq) ^ (r & 7);
                afr[mt] = *(const bf16x8*)&As[r * 64 + slot * 8];
            }
            #pragma unroll
            for (int nt = 0; nt < 3; ++nt) {
                int r = w * 48 + nt * 16 + cl;
                int slot = (s * 4 + cq) ^ (r & 7);
                bfr[nt] = *(const bf16x8*)&Bs[r * 64 + slot * 8];
            }
            #pragma unroll
            for (int mt = 0; mt < 2; ++mt)
                #pragma unroll
                for (int nt = 0; nt < 3; ++nt)
                    acc[mt][nt] = __builtin_amdgcn_mfma_f32_16x16x32_bf16(
                        afr[mt], bfr[nt], acc[mt][nt], 0, 0, 0);
        }
        __syncthreads();
    }

    // ---- epilogue: y = acc + bias + resid -> LDS (32 x 388 f32) ----
    float* yb = (float*)smem;
    #pragma unroll
    for (int mt = 0; mt < 2; ++mt) {
        #pragma unroll
        for (int nt = 0; nt < 3; ++nt) {
            int col = w * 48 + nt * 16 + cl;
            float bb = bias[col];
            #pragma unroll
            for (int rg = 0; rg < 4; ++rg) {
                int rloc = mt * 16 + cq * 4 + rg;
                yb[rloc * 388 + col] =
                    acc[mt][nt][rg] + bb + resid[(size_t)(m0 + rloc) * 384 + col];
            }
        }
    }
    __syncthreads();

    // ---- LayerNorm: 16 threads per row (32 rows x 16 = 512) ----
    int rloc = tid >> 4, sub = tid & 15;
    f32x4 vals[6];
    float s = 0.f, s2 = 0.f;
    #pragma unroll
    for (int m = 0; m < 6; ++m) {
        f32x4 vv = *(const f32x4*)&yb[rloc * 388 + m * 64 + sub * 4];
        vals[m] = vv;
        #pragma unroll
        for (int j = 0; j < 4; ++j) {
            s += vv[j];
            s2 = fmaf(vv[j], vv[j], s2);
        }
    }
    s += __shfl_xor(s, 1, 64);  s2 += __shfl_xor(s2, 1, 64);
    s += __shfl_xor(s, 2, 64);  s2 += __shfl_xor(s2, 2, 64);
    s += __shfl_xor(s, 4, 64);  s2 += __shfl_xor(s2, 4, 64);
    s += __shfl_xor(s, 8, 64);  s2 += __shfl_xor(s2, 8, 64);
    float mean = s * (1.f / 384.f);
    float var = s2 * (1.f / 384.f) - mean * mean;
    float inv = rsqrtf(var + 1e-5f);

    size_t ro = (size_t)(m0 + rloc) * 384;
    #pragma unroll
    for (int m = 0; m < 6; ++m) {
        int c0 = m * 64 + sub * 4;
        f32x4 gg = *(const f32x4*)&g[c0];
        f32x4 bb = *(const f32x4*)&be[c0];
        f32x4 ov;
        s16x4 ob2;
        #pragma unroll
        for (int j = 0; j < 4; ++j) {
            float v = (vals[m][j] - mean) * inv * gg[j] + bb[j];
            ov[j] = v;
            ob2[j] = f2bf(v);
        }
        *(f32x4*)&t[ro + c0] = ov;
        *(s16x4*)&tb[ro + c0] = ob2;
    }
}

// ---------------- fused attention per (n,h): MFMA, 4 waves x 32 queries ----
__global__ __launch_bounds__(256) void attn_kernel(
    const short* __restrict__ qkv, short* __restrict__ o)
{
    __shared__ __align__(16) short lds[23936];
    short* Vt = lds;                  // [48][136] bf16
    short* P  = lds + 6528;           // [4][32][136] bf16 (per wave)

    int tid = threadIdx.x;
    int w = tid >> 6, lane = tid & 63;
    int cq = lane >> 4, cl = lane & 15;
    int n = blockIdx.x >> 3, h = blockIdx.x & 7;
    size_t base = (size_t)n * 147456 + (size_t)h * 48;   // n*128*1152
    const short* qp = qkv + base;
    const short* kp = qkv + base + 384;
    const short* vp = qkv + base + 768;

    // ---- stage Vt: V[key][e] -> Vt[e][key] (stride 136) ----
    {
        int key = tid >> 1, half = tid & 1;
        const short* vsrc = vp + (size_t)key * 1152 + half * 24;
        #pragma unroll
        for (int e4 = 0; e4 < 6; ++e4) {
            s16x4 vv = *(const s16x4*)(vsrc + e4 * 4);
            int e0 = half * 24 + e4 * 4;
            Vt[(e0 + 0) * 136 + key] = vv[0];
            Vt[(e0 + 1) * 136 + key] = vv[1];
            Vt[(e0 + 2) * 136 + key] = vv[2];
            Vt[(e0 + 3) * 136 + key] = vv[3];
        }
    }

    // ---- Q fragments for this wave (queries w*32 + mt*16 + cl) ----
    const bf16x8 zf = (bf16x8){0, 0, 0, 0, 0, 0, 0, 0};
    bf16x8 qf[2][2];
    #pragma unroll
    for (int mt = 0; mt < 2; ++mt) {
        const short* qrow = qp + (size_t)(w * 32 + mt * 16 + cl) * 1152;
        qf[mt][0] = *(const bf16x8*)(qrow + cq * 8);
        qf[mt][1] = (cq < 2) ? *(const bf16x8*)(qrow + 32 + cq * 8) : zf;
    }

    // ---- S = QK^T: 2 m-tiles x 8 k-tiles, 2 e-steps ----
    f32x4 sacc[2][8];
    #pragma unroll
    for (int mt = 0; mt < 2; ++mt)
        #pragma unroll
        for (int kt = 0; kt < 8; ++kt)
            sacc[mt][kt] = (f32x4){0.f, 0.f, 0.f, 0.f};

    #pragma unroll
    for (int kt = 0; kt < 8; ++kt) {
        const short* krow = kp + (size_t)(kt * 16 + cl) * 1152;
        bf16x8 kf0 = *(const bf16x8*)(krow + cq * 8);
        bf16x8 kf1 = (cq < 2) ? *(const bf16x8*)(krow + 32 + cq * 8) : zf;
        #pragma unroll
        for (int mt = 0; mt < 2; ++mt) {
            sacc[mt][kt] = __builtin_amdgcn_mfma_f32_16x16x32_bf16(
                qf[mt][0], kf0, sacc[mt][kt], 0, 0, 0);
            sacc[mt][kt] = __builtin_amdgcn_mfma_f32_16x16x32_bf16(
                qf[mt][1], kf1, sacc[mt][kt], 0, 0, 0);
        }
    }
    __syncthreads();   // Vt ready (placed after MFMA to overlap staging)

    // ---- softmax (exact, per row): lane holds rows {mt*16+cq*4+rg} ----
    const float temp = 0.14433756729740643f;  // 1/sqrt(48)
    short* Pw = P + w * 4352;
    float denom[2][4];
    #pragma unroll
    for (int mt = 0; mt < 2; ++mt) {
        #pragma unroll
        for (int rg = 0; rg < 4; ++rg) {
            float m0 = sacc[mt][0][rg];
            #pragma unroll
            for (int kt = 1; kt < 8; ++kt) m0 = fmaxf(m0, sacc[mt][kt][rg]);
            m0 = fmaxf(m0, __shfl_xor(m0, 1, 64));
            m0 = fmaxf(m0, __shfl_xor(m0, 2, 64));
            m0 = fmaxf(m0, __shfl_xor(m0, 4, 64));
            m0 = fmaxf(m0, __shfl_xor(m0, 8, 64));
            int row = mt * 16 + cq * 4 + rg;
            float se = 0.f;
            #pragma unroll
            for (int kt = 0; kt < 8; ++kt) {
                float p = __expf(temp * (sacc[mt][kt][rg] - m0));
                se += p;
                Pw[row * 136 + kt * 16 + cl] = f2bf(p);
            }
            se += __shfl_xor(se, 1, 64);
            se += __shfl_xor(se, 2, 64);
            se += __shfl_xor(se, 4, 64);
            se += __shfl_xor(se, 8, 64);
            denom[mt][rg] = se;
        }
    }

    // ---- PV: 2 m-tiles x 3 n-tiles (e=48) x 4 k-steps (keys=128) ----
    f32x4 oacc[2][3];
    #pragma unroll
    for (int mt = 0; mt < 2; ++mt)
        #pragma unroll
        for (int nt = 0; nt < 3; ++nt)
            oacc[mt][nt] = (f32x4){0.f, 0.f, 0.f, 0.f};

    #pragma unroll
    for (int ks = 0; ks < 4; ++ks) {
        bf16x8 paf[2];
        #pragma unroll
        for (int mt = 0; mt < 2; ++mt)
            paf[mt] = *(const bf16x8*)&Pw[(mt * 16 + cl) * 136 + ks * 32 + cq * 8];
        #pragma unroll
        for (int nt = 0; nt < 3; ++nt) {
            bf16x8 vf = *(const bf16x8*)&Vt[(nt * 16 + cl) * 136 + ks * 32 + cq * 8];
            #pragma unroll
            for (int mt = 0; mt < 2; ++mt)
                oacc[mt][nt] = __builtin_amdgcn_mfma_f32_16x16x32_bf16(
                    paf[mt], vf, oacc[mt][nt], 0, 0, 0);
        }
    }

    // ---- epilogue: scale by 1/denom, write o bf16 ----
    #pragma unroll
    for (int mt = 0; mt < 2; ++mt) {
        #pragma unroll
        for (int rg = 0; rg < 4; ++rg) {
            float inv = 1.f / denom[mt][rg];
            int qrow = w * 32 + mt * 16 + cq * 4 + rg;
            short* op = o + ((size_t)n * 128 + qrow) * 384 + h * 48;
            #pragma unroll
            for (int nt = 0; nt < 3; ++nt)
                op[nt * 16 + cl] = f2bf(oacc[mt][nt][rg] * inv);
        }
    }
}

// ---------------- classifier head ------------------------------------------
__global__ __launch_bounds__(384) void head_kernel(
    const float* __restrict__ t, const float* __restrict__ cls_w,
    const float* __restrict__ cls_b, float* __restrict__ out)
{
    int n = blockIdx.x, d = threadIdx.x;
    float s = 0.f;
    for (int l = 0; l < 128; ++l) s += t[((size_t)n * 128 + l) * 384 + d];
    float p = s * (1.f / 128.f) * cls_w[d];
    #pragma unroll
    for (int off = 32; off > 0; off >>= 1) p += __shfl_xor(p, off, 64);
    __shared__ float red[6];
    if ((threadIdx.x & 63) == 0) red[threadIdx.x >> 6] = p;
    __syncthreads();
    if (threadIdx.x == 0) {
        float tot = red[0] + red[1] + red[2] + red[3] + red[4] + red[5];
        out[n] = tot + cls_b[0];
    }
}

// ---------------------------------------------------------------------------
extern "C" void kernel_launch(void* const* d_in, const int* in_sizes, int n_in,
                              void* d_out, int out_size, void* d_ws, size_t ws_size,
                              hipStream_t stream) {
    (void)n_in; (void)out_size; (void)ws_size;
    const float* x   = (const float*)d_in[0];
    const float* cw0 = (const float*)d_in[1];
    const float* cb0 = (const float*)d_in[2];
    const float* cw1 = (const float*)d_in[3];
    const float* cb1 = (const float*)d_in[4];
    const float* cw2 = (const float*)d_in[5];
    const float* cb2 = (const float*)d_in[6];
    const float* ew  = (const float*)d_in[7];
    const float* eb  = (const float*)d_in[8];
    bool dict_order = (in_sizes[10] == 589824);
    const float *Wq, *Wk, *Wv, *Wo, *W1, *W2, *bq, *bk, *bv, *bo, *b1, *b2;
    if (dict_order) {
        Wq = (const float*)d_in[9];  Wk = (const float*)d_in[10];
        Wv = (const float*)d_in[11]; Wo = (const float*)d_in[12];
        W1 = (const float*)d_in[13]; W2 = (const float*)d_in[14];
        bq = (const float*)d_in[15]; bk = (const float*)d_in[16];
        bv = (const float*)d_in[17]; bo = (const float*)d_in[18];
        b1 = (const float*)d_in[19]; b2 = (const float*)d_in[20];
    } else {
        Wq = (const float*)d_in[9];  bq = (const float*)d_in[10];
        Wk = (const float*)d_in[11]; bk = (const float*)d_in[12];
        Wv = (const float*)d_in[13]; bv = (const float*)d_in[14];
        Wo = (const float*)d_in[15]; bo = (const float*)d_in[16];
        W1 = (const float*)d_in[17]; b1 = (const float*)d_in[18];
        W2 = (const float*)d_in[19]; b2 = (const float*)d_in[20];
    }
    const float* g1  = (const float*)d_in[21];
    const float* be1 = (const float*)d_in[22];
    const float* g2  = (const float*)d_in[23];
    const float* be2 = (const float*)d_in[24];
    const float* clw = (const float*)d_in[25];
    const float* clb = (const float*)d_in[26];

    // ---- workspace layout (bytes) ----
    char* wp = (char*)d_ws;
    float* pe    = (float*)wp; wp += 196608;      // 128*384 f32
    short* featb = (short*)wp; wp += 33554432;    // 8192*2048 bf16 (reused as FFN hidden)
    float* t     = (float*)wp; wp += 12582912;    // 8192*384 f32
    short* tb    = (short*)wp; wp += 6291456;     // 8192*384 bf16
    short* qkvb  = (short*)wp; wp += 18874368;    // 8192*1152 bf16
    short* ob    = (short*)wp; wp += 6291456;     // 8192*384 bf16 (attn out)
    short* ewT   = (short*)wp; wp += 1572864;     // 384 x 2048
    short* WqkvT = (short*)wp; wp += 3538944;     // 4 x 1152 x 384
    short* WoT   = (short*)wp; wp += 1179648;     // 4 x 384 x 384
    short* W1T   = (short*)wp; wp += 4718592;     // 4 x 1536 x 384
    short* W2T   = (short*)wp; wp += 4718592;     // 4 x 384 x 1536
    float* bqkv  = (float*)wp; wp += 18432;       // 4 x 1152 f32
    short* w2T   = (short*)wp; wp += 16384;       // 64 x 128 bf16 (conv2, paired-shift layout)
    short* hb    = featb;                         // FFN hidden 8192*1536 bf16

    const int ROWS = 8192;

    pe_kernel<<<128, 384, 0, stream>>>(pe);
    wcvt_kernel<<<dim3(64, 12, 1), 256, 0, stream>>>(ew, ewT, 2048, 384, 0, 0, 0);
    qkvcvt_kernel<<<dim3(12, 12, 12), 256, 0, stream>>>(Wq, Wk, Wv, WqkvT);
    wcvt_kernel<<<dim3(12, 12, 4), 256, 0, stream>>>(Wo, WoT, 384, 384, 0, 147456, 147456);
    wcvt_kernel<<<dim3(12, 48, 4), 256, 0, stream>>>(W1, W1T, 384, 1536, 0, 589824, 589824);
    wcvt_kernel<<<dim3(48, 12, 4), 256, 0, stream>>>(W2, W2T, 1536, 384, 0, 589824, 589824);
    biascat_kernel<<<4, 384, 0, stream>>>(bq, bk, bv, bqkv);
    w2cvt_kernel<<<32, 256, 0, stream>>>(cw2, w2T);
    cnn_kernel<<<2048, 256, 0, stream>>>(x, cw0, cb0, cw1, cb1, w2T, cb2, featb);

    // t/tb = relu(feat @ ew + eb) + pe
    gemm_bf16<29><<<dim3(6, 64), 256, 0, stream>>>(featb, ewT, eb, nullptr, pe,
                                                   t, tb, ROWS, 384, 2048);
    for (int i = 0; i < 4; ++i) {
        const short* WqkvTi = WqkvT + (size_t)i * 442368;
        const short* WoTi = WoT + (size_t)i * 147456;
        const short* W1Ti = W1T + (size_t)i * 589824;
        const short* W2Ti = W2T + (size_t)i * 589824;
        gemm_bf16_wide<16><<<dim3(9, 64), 256, 0, stream>>>(tb, WqkvTi,
            bqkv + i * 1152, nullptr, qkvb, ROWS, 1152, 384);
        attn_kernel<<<512, 256, 0, stream>>>(qkvb, ob);
        // t/tb = LN(o @ Wo + bo + t)
        gemm_ln<<<256, 512, 0, stream>>>(ob, WoTi, bo + i * 384, t,
            g1 + i * 384, be1 + i * 384, t, tb, 384);
        // hidden = relu(t @ W1 + b1)
        gemm_bf16_wide<17><<<dim3(12, 64), 256, 0, stream>>>(tb, W1Ti,
            b1 + i * 1536, nullptr, hb, ROWS, 1536, 384);
        // t/tb = LN(hidden @ W2 + b2 + t)
        gemm_ln<<<256, 512, 0, stream>>>(hb, W2Ti, b2 + i * 384, t,
            g2 + i * 384, be2 + i * 384, t, tb, 1536);
    }
    head_kernel<<<64, 384, 0, stream>>>(t, clw, clb, (float*)d_out);
}

// Round 8
// 601.790 us; speedup vs baseline: 1.3226x; 1.0328x over previous
//
#include <hip/hip_runtime.h>
#include <math.h>

// ---------------------------------------------------------------------------
// N=64, L=128, W=256, D=384, H=8, E=48, NL=4, DFF=1536, rows = N*L = 8192
// GEMMs: bf16 MFMA 16x16x32, A [M][K] bf16 row-major, Bt [N][K] bf16.
// R25: merge the 8 prep dispatches (pe, wcvt x4, qkvcvt, biascat, w2cvt)
// into ONE prep_kernel (7922 blocks, branch on blockIdx range; each branch
// is the verbatim old kernel body -> bit-identical outputs). Dispatch chain
// 31 -> 24. This is both a win and a probe: R24's gemm_ln reshape gained
// only 9us despite halving B-traffic, and compute models put the GEMM sum
// at ~150-250us vs ~570us measured outside cnn -> suspect per-dispatch
// ramp/drain overhead. If total drops ~25-35us, overhead confirmed (fuse
// more); if <5us, the time is inside the GEMMs (target internals next).
// Post-mortem R24: 630->621.5us; cnn 51us still top dispatch.
// ---------------------------------------------------------------------------

typedef float f32x4 __attribute__((ext_vector_type(4)));
typedef short bf16x8 __attribute__((ext_vector_type(8)));
typedef short s16x4 __attribute__((ext_vector_type(4)));

__device__ __forceinline__ short f2bf(float f) {
    union { float f; unsigned u; } c; c.f = f;
    unsigned r = (c.u + 0x7FFFu + ((c.u >> 16) & 1u)) >> 16;
    return (short)r;
}
__device__ __forceinline__ float bf2f(short s) {
    union { unsigned u; float f; } c;
    c.u = ((unsigned)(unsigned short)s) << 16;
    return c.f;
}

__device__ __forceinline__ void gload_lds16(const void* g, void* l) {
    __builtin_amdgcn_global_load_lds(
        (const __attribute__((address_space(1))) unsigned int*)g,
        (__attribute__((address_space(3))) unsigned int*)l,
        16, 0, 0);
}

// ---------------- merged prep: all weight cvt + pe + biascat + w2cvt -------
// Block ranges:
//   [0,768)      ewT   : [2048][384] f32 -> [384][2048] bf16 (64 x 12 tiles)
//   [768,2496)   WqkvT : 12 x 12 x (layer*3+which)
//   [2496,3072)  WoT   : 12 x 12 x 4
//   [3072,5376)  W1T   : 12 x 48 x 4
//   [5376,7680)  W2T   : 48 x 12 x 4
//   [7680,7872)  pe    : 128*384 f32
//   [7872,7890)  bqkv  : 4*1152 f32
//   [7890,7922)  w2T   : conv2 paired-shift layout [64][128]
__global__ __launch_bounds__(256) void prep_kernel(
    const float* __restrict__ ew,
    const float* __restrict__ Wq, const float* __restrict__ Wk,
    const float* __restrict__ Wv, const float* __restrict__ Wo,
    const float* __restrict__ W1, const float* __restrict__ W2,
    const float* __restrict__ bq, const float* __restrict__ bk,
    const float* __restrict__ bv, const float* __restrict__ w2,
    short* __restrict__ ewT, short* __restrict__ WqkvT,
    short* __restrict__ WoT, short* __restrict__ W1T,
    short* __restrict__ W2T, float* __restrict__ pe,
    float* __restrict__ bqkv, short* __restrict__ w2T)
{
    __shared__ float tile[32][33];
    int id = blockIdx.x;
    int tid = threadIdx.x;
    int tx = tid & 31, ty = tid >> 5;

    const float* Wp;
    short* Wtp;
    int K, N, kb, nb;

    if (id < 768) {
        K = 2048; N = 384;
        kb = (id & 63) * 32; nb = (id >> 6) * 32;
        Wp = ew; Wtp = ewT;
    } else if (id < 2496) {
        int t = id - 768;
        int kbi = t % 12, nbi = (t / 12) % 12, z = t / 144;
        int layer = z / 3, which = z - layer * 3;
        K = 384; N = 384; kb = kbi * 32; nb = nbi * 32;
        Wp = (which == 0 ? Wq : (which == 1 ? Wk : Wv)) + (size_t)layer * 147456;
        Wtp = WqkvT + (size_t)layer * 442368 + (size_t)which * 147456;
    } else if (id < 3072) {
        int t = id - 2496;
        int kbi = t % 12, nbi = (t / 12) % 12, z = t / 144;
        K = 384; N = 384; kb = kbi * 32; nb = nbi * 32;
        Wp = Wo + (size_t)z * 147456; Wtp = WoT + (size_t)z * 147456;
    } else if (id < 5376) {
        int t = id - 3072;
        int kbi = t % 12, nbi = (t / 12) % 48, z = t / 576;
        K = 384; N = 1536; kb = kbi * 32; nb = nbi * 32;
        Wp = W1 + (size_t)z * 589824; Wtp = W1T + (size_t)z * 589824;
    } else if (id < 7680) {
        int t = id - 5376;
        int kbi = t % 48, nbi = (t / 48) % 12, z = t / 576;
        K = 1536; N = 384; kb = kbi * 32; nb = nbi * 32;
        Wp = W2 + (size_t)z * 589824; Wtp = W2T + (size_t)z * 589824;
    } else if (id < 7872) {
        int idx = (id - 7680) * 256 + tid;
        int l = idx / 384, d = idx - l * 384;
        int i2 = d >> 1;
        float ang = (float)l * expf(-(2.0f * (float)i2 / 384.0f) * 9.210340371976184f);
        pe[idx] = (d & 1) ? cosf(ang) : sinf(ang);
        return;
    } else if (id < 7890) {
        int idx = (id - 7872) * 256 + tid;
        int l = idx / 1152, j3 = idx - l * 1152;
        int which = j3 / 384, j = j3 - which * 384;
        const float* b = (which == 0 ? bq : (which == 1 ? bk : bv));
        bqkv[idx] = b[l * 384 + j];
        return;
    } else {
        int idx = (id - 7890) * 256 + tid;
        int c = idx >> 7, r = idx & 127;
        int pr = r >> 5, q = (r >> 3) & 3, j = r & 7;
        int ci = (q & 1) * 8 + j;
        int sft = 2 * pr + (q >> 1);
        w2T[idx] = (sft < 7) ? f2bf(w2[c * 112 + ci * 7 + sft]) : (short)0;
        return;
    }

    #pragma unroll
    for (int r = ty; r < 32; r += 8)
        tile[r][tx] = Wp[(size_t)(kb + r) * N + nb + tx];
    __syncthreads();
    #pragma unroll
    for (int r = ty; r < 32; r += 8)
        Wtp[(size_t)(nb + r) * K + kb + tx] = f2bf(tile[tx][r]);
}

// ---------------- fused CNN window encoder: 4 windows/block, 1 barrier -----
// LDS layout (26880 B -> 5 blocks/CU):
//   [0     .. 4224)   xs[4][264] f32   (x at idx j+4, zeros [0..3],[260..263])
//   [4224  .. 13056)  p0[4][4][138] f32 (conv0 out at idx j+3, zeros [0..2]
//                     and [131..133]; stride 138)
//   [13056 .. 26880)  p1T[4][72][24] bf16 (row=pos+3, pad rows zeroed)
__global__ __launch_bounds__(256, 4) void cnn_kernel(
    const float* __restrict__ x,
    const float* __restrict__ w0, const float* __restrict__ b0,
    const float* __restrict__ w1, const float* __restrict__ b1,
    const short* __restrict__ w2T, const float* __restrict__ b2,
    short* __restrict__ feat)
{
    __shared__ __align__(16) char smem[26880];
    float* xs  = (float*)smem;                    // [4][264]
    float* p0  = (float*)(smem + 4224);           // [4][4][138]
    short* p1T = (short*)(smem + 13056);          // [4][72][24]

    int tid = threadIdx.x;
    int w = tid >> 6, lane = tid & 63;
    size_t win = (size_t)blockIdx.x * 4 + w;
    int cq = lane >> 4, cl = lane & 15;

    float* xs_w = xs + w * 264;
    float* p0_w = p0 + w * 552;                   // 4*138
    short* p1T_w = p1T + w * 1728;

    // ---- per-wave setup: weights to regs (L2-broadcast), xs fill ----
    int ca = lane & 3;
    int cb = lane & 15, g = lane >> 4;
    float w0r[7], w1r[4][7];
    float b0r = b0[ca];
    float b1r = b1[cb];
    #pragma unroll
    for (int k = 0; k < 7; ++k) w0r[k] = w0[ca * 7 + k];
    #pragma unroll
    for (int ci = 0; ci < 4; ++ci)
        #pragma unroll
        for (int k = 0; k < 7; ++k) w1r[ci][k] = w1[(cb * 4 + ci) * 7 + k];

    {
        f32x4 v = *(const f32x4*)(x + win * 256 + lane * 4);
        *(f32x4*)&xs_w[4 + lane * 4] = v;
        if (lane < 2) *(f32x4*)&xs_w[lane * 260] = (f32x4){0.f, 0.f, 0.f, 0.f};
    }

    // ---- stage A (wave-local): conv0 + relu + pool2 -> p0_w[c][pp+3] ----
    {
        int pa = lane >> 2;
        #pragma unroll
        for (int t2 = 0; t2 < 8; ++t2) {
            int pp = t2 * 16 + pa;
            float rv[9];
            #pragma unroll
            for (int u = 0; u < 9; ++u) rv[u] = xs_w[2 * pp + u + 1];
            float a0 = b0r, a1 = b0r;
            #pragma unroll
            for (int k = 0; k < 7; ++k) {
                a0 = fmaf(w0r[k], rv[k], a0);
                a1 = fmaf(w0r[k], rv[k + 1], a1);
            }
            p0_w[ca * 138 + pp + 3] = fmaxf(fmaxf(a0, a1), 0.f);
        }
        if (lane < 4) {
            p0_w[lane * 138 + 0] = 0.f;
            p0_w[lane * 138 + 1] = 0.f;
            p0_w[lane * 138 + 2] = 0.f;
            p0_w[lane * 138 + 131] = 0.f;
            p0_w[lane * 138 + 132] = 0.f;
            p0_w[lane * 138 + 133] = 0.f;
        }
    }

    // ---- stage B (wave-local): conv1 + relu + pool2 -> p1T_w[3+pos][c] ----
    #pragma unroll
    for (int cc = 0; cc < 4; ++cc) {
        int cci = (cc + g) & 3;
        int j0 = g * 32 + cci * 8;           // padded pre-pool base
        float acc[8];
        #pragma unroll
        for (int m = 0; m < 8; ++m) acc[m] = b1r;
        #pragma unroll
        for (int ci = 0; ci < 4; ++ci) {
            float rv[14];
            #pragma unroll
            for (int u = 0; u < 14; ++u) rv[u] = p0_w[ci * 138 + j0 + u];
            #pragma unroll
            for (int k = 0; k < 7; ++k) {
                float ww = w1r[ci][k];
                #pragma unroll
                for (int m = 0; m < 8; ++m) acc[m] = fmaf(ww, rv[m + k], acc[m]);
            }
        }
        int po = g * 16 + cci * 4;
        #pragma unroll
        for (int m = 0; m < 4; ++m)
            p1T_w[(3 + po + m) * 24 + cb] =
                f2bf(fmaxf(fmaxf(acc[2 * m], acc[2 * m + 1]), 0.f));
    }
    // zero p1T pad rows (own window)
    {
        int* pz = (int*)p1T_w;
        if (lane < 36) pz[lane] = 0;
        if (lane < 60) pz[804 + lane] = 0;
    }
    __syncthreads();   // the ONLY barrier: all 4 windows' p1T ready

    // ---- stage C: conv2 as 4 paired-shift GEMMs, all 4 windows/wave ----
    f32x4 acc[4][4];   // [window v][mt]
    #pragma unroll
    for (int v = 0; v < 4; ++v)
        #pragma unroll
        for (int mt = 0; mt < 4; ++mt)
            acc[v][mt] = (f32x4){0.f, 0.f, 0.f, 0.f};

    {
        const short* bpb = p1T + (w * 16 + cl + (cq >> 1)) * 24 + (cq & 1) * 8;
        #pragma unroll
        for (int pr = 0; pr < 4; ++pr) {
            bf16x8 bfr[4];
            #pragma unroll
            for (int v = 0; v < 4; ++v)
                bfr[v] = *(const bf16x8*)&bpb[v * 1728 + pr * 48];
            #pragma unroll
            for (int mt = 0; mt < 4; ++mt) {
                bf16x8 af = *(const bf16x8*)&w2T[(mt * 16 + cl) * 128 +
                                                 pr * 32 + cq * 8];
                #pragma unroll
                for (int v = 0; v < 4; ++v)
                    acc[v][mt] = __builtin_amdgcn_mfma_f32_16x16x32_bf16(
                        af, bfr[v], acc[v][mt], 0, 0, 0);
            }
        }
    }

    // ---- epilogue: pool pairs via shfl, store bf16 (per window) ----
    int iev = (w * 16 + cl) >> 1;
    #pragma unroll
    for (int v = 0; v < 4; ++v) {
        short* fp = feat + ((size_t)blockIdx.x * 4 + v) * 2048;
        #pragma unroll
        for (int mt = 0; mt < 4; ++mt) {
            #pragma unroll
            for (int rg = 0; rg < 4; ++rg) {
                float vv = acc[v][mt][rg];
                float v2 = __shfl_xor(vv, 1, 64);
                if ((cl & 1) == 0) {
                    int c = mt * 16 + cq * 4 + rg;
                    float pv = fmaxf(fmaxf(vv, v2) + b2[c], 0.f);
                    fp[c * 32 + iev] = f2bf(pv);
                }
            }
        }
    }
}

// ---------------- bf16 MFMA GEMM (thin-N): BM=128, BN=64, double-buffered --
// EPI bits: 1=relu, 2=+resid(f32), 4=+pe, 8=write f32, 16=write bf16
template <int EPI>
__global__ __launch_bounds__(256) void gemm_bf16(
    const short* __restrict__ A, const short* __restrict__ Bt,
    const float* __restrict__ bias, const float* __restrict__ resid,
    const float* __restrict__ pe, float* __restrict__ outF,
    short* __restrict__ outB, int M, int N, int K)
{
    __shared__ short As[2][128 * 64];
    __shared__ short Bs[2][64 * 64];
    int tid = threadIdx.x;
    int w = tid >> 6, lane = tid & 63;
    int wm = w >> 1, wn = w & 1;
    int m0 = blockIdx.y * 128, n0 = blockIdx.x * 64;

    int rl = lane >> 3, sl = lane & 7;
    int cb = sl ^ rl;
    const short* aptr[4];
    const short* bptr[2];
    int arow[4], brow[2];
    #pragma unroll
    for (int l = 0; l < 4; ++l) {
        arow[l] = l * 32 + w * 8;
        aptr[l] = A + (size_t)(m0 + arow[l] + rl) * K + cb * 8;
    }
    #pragma unroll
    for (int l = 0; l < 2; ++l) {
        brow[l] = l * 32 + w * 8;
        bptr[l] = Bt + (size_t)(n0 + brow[l] + rl) * K + cb * 8;
    }

    int cq = lane >> 4, cl = lane & 15;
    f32x4 acc[4][2];
    #pragma unroll
    for (int mt = 0; mt < 4; ++mt)
        #pragma unroll
        for (int nt = 0; nt < 2; ++nt)
            acc[mt][nt] = (f32x4){0.f, 0.f, 0.f, 0.f};

    #pragma unroll
    for (int l = 0; l < 4; ++l) { gload_lds16(aptr[l], &As[0][arow[l] * 64]); aptr[l] += 64; }
    #pragma unroll
    for (int l = 0; l < 2; ++l) { gload_lds16(bptr[l], &Bs[0][brow[l] * 64]); bptr[l] += 64; }
    __syncthreads();

    int nk = K >> 6;
    for (int k = 0; k < nk; ++k) {
        int cur = k & 1;
        if (k + 1 < nk) {
            #pragma unroll
            for (int l = 0; l < 4; ++l) { gload_lds16(aptr[l], &As[cur ^ 1][arow[l] * 64]); aptr[l] += 64; }
            #pragma unroll
            for (int l = 0; l < 2; ++l) { gload_lds16(bptr[l], &Bs[cur ^ 1][brow[l] * 64]); bptr[l] += 64; }
        }
        #pragma unroll
        for (int s = 0; s < 2; ++s) {
            bf16x8 afr[4], bfr[2];
            #pragma unroll
            for (int mt = 0; mt < 4; ++mt) {
                int r = wm * 64 + mt * 16 + cl;
                int slot = (s * 4 + cq) ^ (r & 7);
                afr[mt] = *(const bf16x8*)&As[cur][r * 64 + slot * 8];
            }
            #pragma unroll
            for (int nt = 0; nt < 2; ++nt) {
                int r = wn * 32 + nt * 16 + cl;
                int slot = (s * 4 + cq) ^ (r & 7);
                bfr[nt] = *(const bf16x8*)&Bs[cur][r * 64 + slot * 8];
            }
            #pragma unroll
            for (int mt = 0; mt < 4; ++mt)
                #pragma unroll
                for (int nt = 0; nt < 2; ++nt)
                    acc[mt][nt] = __builtin_amdgcn_mfma_f32_16x16x32_bf16(
                        afr[mt], bfr[nt], acc[mt][nt], 0, 0, 0);
        }
        __syncthreads();
    }

    #pragma unroll
    for (int mt = 0; mt < 4; ++mt) {
        #pragma unroll
        for (int nt = 0; nt < 2; ++nt) {
            int col = n0 + wn * 32 + nt * 16 + cl;
            float bb = bias[col];
            #pragma unroll
            for (int rg = 0; rg < 4; ++rg) {
                int row = m0 + wm * 64 + mt * 16 + cq * 4 + rg;
                float v = acc[mt][nt][rg] + bb;
                if (EPI & 1) v = fmaxf(v, 0.f);
                if (EPI & 4) v += pe[(row & 127) * 384 + col];
                if (EPI & 2) v += resid[(size_t)row * N + col];
                if (EPI & 8) outF[(size_t)row * N + col] = v;
                if (EPI & 16) outB[(size_t)row * N + col] = f2bf(v);
            }
        }
    }
}

// ---------------- bf16 MFMA GEMM (wide-N): BM=128, BN=128, BK=32 dbuf ------
template <int EPI>
__global__ __launch_bounds__(256) void gemm_bf16_wide(
    const short* __restrict__ A, const short* __restrict__ Bt,
    const float* __restrict__ bias, float* __restrict__ outF,
    short* __restrict__ outB, int M, int N, int K)
{
    __shared__ short As[2][128 * 32];
    __shared__ short Bs[2][128 * 32];
    int tid = threadIdx.x;
    int w = tid >> 6, lane = tid & 63;
    int wm = w >> 1, wn = w & 1;
    int m0 = blockIdx.y * 128, n0 = blockIdx.x * 128;

    int rl = lane >> 2, sl = lane & 3;
    int cb = sl ^ (rl & 3) ^ ((rl >> 2) & 3);
    const short* aptr[2];
    const short* bptr[2];
    int srow[2];
    #pragma unroll
    for (int l = 0; l < 2; ++l) {
        srow[l] = w * 32 + l * 16;
        aptr[l] = A + (size_t)(m0 + srow[l] + rl) * K + cb * 8;
        bptr[l] = Bt + (size_t)(n0 + srow[l] + rl) * K + cb * 8;
    }

    int cq = lane >> 4, cl = lane & 15;
    f32x4 acc[4][4];
    #pragma unroll
    for (int mt = 0; mt < 4; ++mt)
        #pragma unroll
        for (int nt = 0; nt < 4; ++nt)
            acc[mt][nt] = (f32x4){0.f, 0.f, 0.f, 0.f};

    #pragma unroll
    for (int l = 0; l < 2; ++l) {
        gload_lds16(aptr[l], &As[0][srow[l] * 32]);
        gload_lds16(bptr[l], &Bs[0][srow[l] * 32]);
        aptr[l] += 32; bptr[l] += 32;
    }
    __syncthreads();

    int nk = K >> 5;
    for (int k = 0; k < nk; ++k) {
        int cur = k & 1;
        if (k + 1 < nk) {
            #pragma unroll
            for (int l = 0; l < 2; ++l) {
                gload_lds16(aptr[l], &As[cur ^ 1][srow[l] * 32]);
                gload_lds16(bptr[l], &Bs[cur ^ 1][srow[l] * 32]);
                aptr[l] += 32; bptr[l] += 32;
            }
        }
        bf16x8 afr[4], bfr[4];
        #pragma unroll
        for (int mt = 0; mt < 4; ++mt) {
            int r = wm * 64 + mt * 16 + cl;
            int slot = cq ^ (r & 3) ^ ((r >> 2) & 3);
            afr[mt] = *(const bf16x8*)&As[cur][r * 32 + slot * 8];
        }
        #pragma unroll
        for (int nt = 0; nt < 4; ++nt) {
            int r = wn * 64 + nt * 16 + cl;
            int slot = cq ^ (r & 3) ^ ((r >> 2) & 3);
            bfr[nt] = *(const bf16x8*)&Bs[cur][r * 32 + slot * 8];
        }
        #pragma unroll
        for (int mt = 0; mt < 4; ++mt)
            #pragma unroll
            for (int nt = 0; nt < 4; ++nt)
                acc[mt][nt] = __builtin_amdgcn_mfma_f32_16x16x32_bf16(
                    afr[mt], bfr[nt], acc[mt][nt], 0, 0, 0);
        __syncthreads();
    }

    #pragma unroll
    for (int mt = 0; mt < 4; ++mt) {
        #pragma unroll
        for (int nt = 0; nt < 4; ++nt) {
            int col = n0 + wn * 64 + nt * 16 + cl;
            float bb = bias[col];
            #pragma unroll
            for (int rg = 0; rg < 4; ++rg) {
                int row = m0 + wm * 64 + mt * 16 + cq * 4 + rg;
                float v = acc[mt][nt][rg] + bb;
                if (EPI & 1) v = fmaxf(v, 0.f);
                if (EPI & 8) outF[(size_t)row * N + col] = v;
                if (EPI & 16) outB[(size_t)row * N + col] = f2bf(v);
            }
        }
    }
}

// ---------------- fused GEMM + bias + residual + LayerNorm -----------------
// R24: BM=32, BN=384, BK=64, 512 threads, grid 256, double-buffered LDS.
__global__ __launch_bounds__(512) void gemm_ln(
    const short* __restrict__ A, const short* __restrict__ Bt,
    const float* __restrict__ bias, const float* resid,
    const float* __restrict__ g, const float* __restrict__ be,
    float* t, short* __restrict__ tb, int K)
{
    __shared__ __align__(16) char smem[106496];
    short* As0 = (short*)smem;                 // [2][32*64]  = 8 KB
    short* Bs0 = (short*)(smem + 8192);        // [2][384*64] = 96 KB

    int tid = threadIdx.x;
    int w = tid >> 6, lane = tid & 63;
    int m0 = blockIdx.x * 32;
    int rl = lane >> 3, sl = lane & 7;
    int cb = sl ^ rl;

    const short* aptr = A + (size_t)(m0 + (w & 3) * 8 + rl) * K + cb * 8;
    const short* bptr[6];
    #pragma unroll
    for (int l = 0; l < 6; ++l)
        bptr[l] = Bt + (size_t)(w * 48 + l * 8 + rl) * K + cb * 8;

    int cq = lane >> 4, cl = lane & 15;
    f32x4 acc[2][3];
    #pragma unroll
    for (int mt = 0; mt < 2; ++mt)
        #pragma unroll
        for (int nt = 0; nt < 3; ++nt)
            acc[mt][nt] = (f32x4){0.f, 0.f, 0.f, 0.f};

    // prologue: stage buffer 0
    if (w < 4) { gload_lds16(aptr, &As0[(w * 8) * 64]); aptr += 64; }
    #pragma unroll
    for (int l = 0; l < 6; ++l) {
        gload_lds16(bptr[l], &Bs0[(w * 48 + l * 8) * 64]);
        bptr[l] += 64;
    }
    __syncthreads();

    int nk = K >> 6;
    for (int k = 0; k < nk; ++k) {
        int cur = k & 1;
        if (k + 1 < nk) {
            if (w < 4) { gload_lds16(aptr, &As0[(cur ^ 1) * 2048 + (w * 8) * 64]); aptr += 64; }
            #pragma unroll
            for (int l = 0; l < 6; ++l) {
                gload_lds16(bptr[l], &Bs0[(cur ^ 1) * 24576 + (w * 48 + l * 8) * 64]);
                bptr[l] += 64;
            }
        }
        const short* As = As0 + cur * 2048;
        const short* Bs = Bs0 + cur * 24576;
        #pragma unroll
        for (int s = 0; s < 2; ++s) {
            bf16x8 afr[2], bfr[3];
            #pragma unroll
            for (int mt = 0; mt < 2; ++mt) {
                int r = mt * 16 + cl;
                int slot = (s * 4 + cq) ^ (r & 7);
                afr[mt] = *(const bf16x8*)&As[r * 64 + slot * 8];
            }
            #pragma unroll
            for (int nt = 0; nt < 3; ++nt) {
                int r = w * 48 + nt * 16 + cl;
                int slot = (s * 4 + cq) ^ (r & 7);
                bfr[nt] = *(const bf16x8*)&Bs[r * 64 + slot * 8];
            }
            #pragma unroll
            for (int mt = 0; mt < 2; ++mt)
                #pragma unroll
                for (int nt = 0; nt < 3; ++nt)
                    acc[mt][nt] = __builtin_amdgcn_mfma_f32_16x16x32_bf16(
                        afr[mt], bfr[nt], acc[mt][nt], 0, 0, 0);
        }
        __syncthreads();
    }

    // ---- epilogue: y = acc + bias + resid -> LDS (32 x 388 f32) ----
    float* yb = (float*)smem;
    #pragma unroll
    for (int mt = 0; mt < 2; ++mt) {
        #pragma unroll
        for (int nt = 0; nt < 3; ++nt) {
            int col = w * 48 + nt * 16 + cl;
            float bb = bias[col];
            #pragma unroll
            for (int rg = 0; rg < 4; ++rg) {
                int rloc = mt * 16 + cq * 4 + rg;
                yb[rloc * 388 + col] =
                    acc[mt][nt][rg] + bb + resid[(size_t)(m0 + rloc) * 384 + col];
            }
        }
    }
    __syncthreads();

    // ---- LayerNorm: 16 threads per row (32 rows x 16 = 512) ----
    int rloc = tid >> 4, sub = tid & 15;
    f32x4 vals[6];
    float s = 0.f, s2 = 0.f;
    #pragma unroll
    for (int m = 0; m < 6; ++m) {
        f32x4 vv = *(const f32x4*)&yb[rloc * 388 + m * 64 + sub * 4];
        vals[m] = vv;
        #pragma unroll
        for (int j = 0; j < 4; ++j) {
            s += vv[j];
            s2 = fmaf(vv[j], vv[j], s2);
        }
    }
    s += __shfl_xor(s, 1, 64);  s2 += __shfl_xor(s2, 1, 64);
    s += __shfl_xor(s, 2, 64);  s2 += __shfl_xor(s2, 2, 64);
    s += __shfl_xor(s, 4, 64);  s2 += __shfl_xor(s2, 4, 64);
    s += __shfl_xor(s, 8, 64);  s2 += __shfl_xor(s2, 8, 64);
    float mean = s * (1.f / 384.f);
    float var = s2 * (1.f / 384.f) - mean * mean;
    float inv = rsqrtf(var + 1e-5f);

    size_t ro = (size_t)(m0 + rloc) * 384;
    #pragma unroll
    for (int m = 0; m < 6; ++m) {
        int c0 = m * 64 + sub * 4;
        f32x4 gg = *(const f32x4*)&g[c0];
        f32x4 bb = *(const f32x4*)&be[c0];
        f32x4 ov;
        s16x4 ob2;
        #pragma unroll
        for (int j = 0; j < 4; ++j) {
            float v = (vals[m][j] - mean) * inv * gg[j] + bb[j];
            ov[j] = v;
            ob2[j] = f2bf(v);
        }
        *(f32x4*)&t[ro + c0] = ov;
        *(s16x4*)&tb[ro + c0] = ob2;
    }
}

// ---------------- fused attention per (n,h): MFMA, 4 waves x 32 queries ----
__global__ __launch_bounds__(256) void attn_kernel(
    const short* __restrict__ qkv, short* __restrict__ o)
{
    __shared__ __align__(16) short lds[23936];
    short* Vt = lds;                  // [48][136] bf16
    short* P  = lds + 6528;           // [4][32][136] bf16 (per wave)

    int tid = threadIdx.x;
    int w = tid >> 6, lane = tid & 63;
    int cq = lane >> 4, cl = lane & 15;
    int n = blockIdx.x >> 3, h = blockIdx.x & 7;
    size_t base = (size_t)n * 147456 + (size_t)h * 48;   // n*128*1152
    const short* qp = qkv + base;
    const short* kp = qkv + base + 384;
    const short* vp = qkv + base + 768;

    // ---- stage Vt: V[key][e] -> Vt[e][key] (stride 136) ----
    {
        int key = tid >> 1, half = tid & 1;
        const short* vsrc = vp + (size_t)key * 1152 + half * 24;
        #pragma unroll
        for (int e4 = 0; e4 < 6; ++e4) {
            s16x4 vv = *(const s16x4*)(vsrc + e4 * 4);
            int e0 = half * 24 + e4 * 4;
            Vt[(e0 + 0) * 136 + key] = vv[0];
            Vt[(e0 + 1) * 136 + key] = vv[1];
            Vt[(e0 + 2) * 136 + key] = vv[2];
            Vt[(e0 + 3) * 136 + key] = vv[3];
        }
    }

    // ---- Q fragments for this wave (queries w*32 + mt*16 + cl) ----
    const bf16x8 zf = (bf16x8){0, 0, 0, 0, 0, 0, 0, 0};
    bf16x8 qf[2][2];
    #pragma unroll
    for (int mt = 0; mt < 2; ++mt) {
        const short* qrow = qp + (size_t)(w * 32 + mt * 16 + cl) * 1152;
        qf[mt][0] = *(const bf16x8*)(qrow + cq * 8);
        qf[mt][1] = (cq < 2) ? *(const bf16x8*)(qrow + 32 + cq * 8) : zf;
    }

    // ---- S = QK^T: 2 m-tiles x 8 k-tiles, 2 e-steps ----
    f32x4 sacc[2][8];
    #pragma unroll
    for (int mt = 0; mt < 2; ++mt)
        #pragma unroll
        for (int kt = 0; kt < 8; ++kt)
            sacc[mt][kt] = (f32x4){0.f, 0.f, 0.f, 0.f};

    #pragma unroll
    for (int kt = 0; kt < 8; ++kt) {
        const short* krow = kp + (size_t)(kt * 16 + cl) * 1152;
        bf16x8 kf0 = *(const bf16x8*)(krow + cq * 8);
        bf16x8 kf1 = (cq < 2) ? *(const bf16x8*)(krow + 32 + cq * 8) : zf;
        #pragma unroll
        for (int mt = 0; mt < 2; ++mt) {
            sacc[mt][kt] = __builtin_amdgcn_mfma_f32_16x16x32_bf16(
                qf[mt][0], kf0, sacc[mt][kt], 0, 0, 0);
            sacc[mt][kt] = __builtin_amdgcn_mfma_f32_16x16x32_bf16(
                qf[mt][1], kf1, sacc[mt][kt], 0, 0, 0);
        }
    }
    __syncthreads();   // Vt ready (placed after MFMA to overlap staging)

    // ---- softmax (exact, per row): lane holds rows {mt*16+cq*4+rg} ----
    const float temp = 0.14433756729740643f;  // 1/sqrt(48)
    short* Pw = P + w * 4352;
    float denom[2][4];
    #pragma unroll
    for (int mt = 0; mt < 2; ++mt) {
        #pragma unroll
        for (int rg = 0; rg < 4; ++rg) {
            float m0 = sacc[mt][0][rg];
            #pragma unroll
            for (int kt = 1; kt < 8; ++kt) m0 = fmaxf(m0, sacc[mt][kt][rg]);
            m0 = fmaxf(m0, __shfl_xor(m0, 1, 64));
            m0 = fmaxf(m0, __shfl_xor(m0, 2, 64));
            m0 = fmaxf(m0, __shfl_xor(m0, 4, 64));
            m0 = fmaxf(m0, __shfl_xor(m0, 8, 64));
            int row = mt * 16 + cq * 4 + rg;
            float se = 0.f;
            #pragma unroll
            for (int kt = 0; kt < 8; ++kt) {
                float p = __expf(temp * (sacc[mt][kt][rg] - m0));
                se += p;
                Pw[row * 136 + kt * 16 + cl] = f2bf(p);
            }
            se += __shfl_xor(se, 1, 64);
            se += __shfl_xor(se, 2, 64);
            se += __shfl_xor(se, 4, 64);
            se += __shfl_xor(se, 8, 64);
            denom[mt][rg] = se;
        }
    }

    // ---- PV: 2 m-tiles x 3 n-tiles (e=48) x 4 k-steps (keys=128) ----
    f32x4 oacc[2][3];
    #pragma unroll
    for (int mt = 0; mt < 2; ++mt)
        #pragma unroll
        for (int nt = 0; nt < 3; ++nt)
            oacc[mt][nt] = (f32x4){0.f, 0.f, 0.f, 0.f};

    #pragma unroll
    for (int ks = 0; ks < 4; ++ks) {
        bf16x8 paf[2];
        #pragma unroll
        for (int mt = 0; mt < 2; ++mt)
            paf[mt] = *(const bf16x8*)&Pw[(mt * 16 + cl) * 136 + ks * 32 + cq * 8];
        #pragma unroll
        for (int nt = 0; nt < 3; ++nt) {
            bf16x8 vf = *(const bf16x8*)&Vt[(nt * 16 + cl) * 136 + ks * 32 + cq * 8];
            #pragma unroll
            for (int mt = 0; mt < 2; ++mt)
                oacc[mt][nt] = __builtin_amdgcn_mfma_f32_16x16x32_bf16(
                    paf[mt], vf, oacc[mt][nt], 0, 0, 0);
        }
    }

    // ---- epilogue: scale by 1/denom, write o bf16 ----
    #pragma unroll
    for (int mt = 0; mt < 2; ++mt) {
        #pragma unroll
        for (int rg = 0; rg < 4; ++rg) {
            float inv = 1.f / denom[mt][rg];
            int qrow = w * 32 + mt * 16 + cq * 4 + rg;
            short* op = o + ((size_t)n * 128 + qrow) * 384 + h * 48;
            #pragma unroll
            for (int nt = 0; nt < 3; ++nt)
                op[nt * 16 + cl] = f2bf(oacc[mt][nt][rg] * inv);
        }
    }
}

// ---------------- classifier head ------------------------------------------
__global__ __launch_bounds__(384) void head_kernel(
    const float* __restrict__ t, const float* __restrict__ cls_w,
    const float* __restrict__ cls_b, float* __restrict__ out)
{
    int n = blockIdx.x, d = threadIdx.x;
    float s = 0.f;
    for (int l = 0; l < 128; ++l) s += t[((size_t)n * 128 + l) * 384 + d];
    float p = s * (1.f / 128.f) * cls_w[d];
    #pragma unroll
    for (int off = 32; off > 0; off >>= 1) p += __shfl_xor(p, off, 64);
    __shared__ float red[6];
    if ((threadIdx.x & 63) == 0) red[threadIdx.x >> 6] = p;
    __syncthreads();
    if (threadIdx.x == 0) {
        float tot = red[0] + red[1] + red[2] + red[3] + red[4] + red[5];
        out[n] = tot + cls_b[0];
    }
}

// ---------------------------------------------------------------------------
extern "C" void kernel_launch(void* const* d_in, const int* in_sizes, int n_in,
                              void* d_out, int out_size, void* d_ws, size_t ws_size,
                              hipStream_t stream) {
    (void)n_in; (void)out_size; (void)ws_size;
    const float* x   = (const float*)d_in[0];
    const float* cw0 = (const float*)d_in[1];
    const float* cb0 = (const float*)d_in[2];
    const float* cw1 = (const float*)d_in[3];
    const float* cb1 = (const float*)d_in[4];
    const float* cw2 = (const float*)d_in[5];
    const float* cb2 = (const float*)d_in[6];
    const float* ew  = (const float*)d_in[7];
    const float* eb  = (const float*)d_in[8];
    bool dict_order = (in_sizes[10] == 589824);
    const float *Wq, *Wk, *Wv, *Wo, *W1, *W2, *bq, *bk, *bv, *bo, *b1, *b2;
    if (dict_order) {
        Wq = (const float*)d_in[9];  Wk = (const float*)d_in[10];
        Wv = (const float*)d_in[11]; Wo = (const float*)d_in[12];
        W1 = (const float*)d_in[13]; W2 = (const float*)d_in[14];
        bq = (const float*)d_in[15]; bk = (const float*)d_in[16];
        bv = (const float*)d_in[17]; bo = (const float*)d_in[18];
        b1 = (const float*)d_in[19]; b2 = (const float*)d_in[20];
    } else {
        Wq = (const float*)d_in[9];  bq = (const float*)d_in[10];
        Wk = (const float*)d_in[11]; bk = (const float*)d_in[12];
        Wv = (const float*)d_in[13]; bv = (const float*)d_in[14];
        Wo = (const float*)d_in[15]; bo = (const float*)d_in[16];
        W1 = (const float*)d_in[17]; b1 = (const float*)d_in[18];
        W2 = (const float*)d_in[19]; b2 = (const float*)d_in[20];
    }
    const float* g1  = (const float*)d_in[21];
    const float* be1 = (const float*)d_in[22];
    const float* g2  = (const float*)d_in[23];
    const float* be2 = (const float*)d_in[24];
    const float* clw = (const float*)d_in[25];
    const float* clb = (const float*)d_in[26];

    // ---- workspace layout (bytes) ----
    char* wp = (char*)d_ws;
    float* pe    = (float*)wp; wp += 196608;      // 128*384 f32
    short* featb = (short*)wp; wp += 33554432;    // 8192*2048 bf16 (reused as FFN hidden)
    float* t     = (float*)wp; wp += 12582912;    // 8192*384 f32
    short* tb    = (short*)wp; wp += 6291456;     // 8192*384 bf16
    short* qkvb  = (short*)wp; wp += 18874368;    // 8192*1152 bf16
    short* ob    = (short*)wp; wp += 6291456;     // 8192*384 bf16 (attn out)
    short* ewT   = (short*)wp; wp += 1572864;     // 384 x 2048
    short* WqkvT = (short*)wp; wp += 3538944;     // 4 x 1152 x 384
    short* WoT   = (short*)wp; wp += 1179648;     // 4 x 384 x 384
    short* W1T   = (short*)wp; wp += 4718592;     // 4 x 1536 x 384
    short* W2T   = (short*)wp; wp += 4718592;     // 4 x 384 x 1536
    float* bqkv  = (float*)wp; wp += 18432;       // 4 x 1152 f32
    short* w2T   = (short*)wp; wp += 16384;       // 64 x 128 bf16 (conv2, paired-shift layout)
    short* hb    = featb;                         // FFN hidden 8192*1536 bf16

    const int ROWS = 8192;

    prep_kernel<<<7922, 256, 0, stream>>>(ew, Wq, Wk, Wv, Wo, W1, W2,
                                          bq, bk, bv, cw2,
                                          ewT, WqkvT, WoT, W1T, W2T,
                                          pe, bqkv, w2T);
    cnn_kernel<<<2048, 256, 0, stream>>>(x, cw0, cb0, cw1, cb1, w2T, cb2, featb);

    // t/tb = relu(feat @ ew + eb) + pe
    gemm_bf16<29><<<dim3(6, 64), 256, 0, stream>>>(featb, ewT, eb, nullptr, pe,
                                                   t, tb, ROWS, 384, 2048);
    for (int i = 0; i < 4; ++i) {
        const short* WqkvTi = WqkvT + (size_t)i * 442368;
        const short* WoTi = WoT + (size_t)i * 147456;
        const short* W1Ti = W1T + (size_t)i * 589824;
        const short* W2Ti = W2T + (size_t)i * 589824;
        gemm_bf16_wide<16><<<dim3(9, 64), 256, 0, stream>>>(tb, WqkvTi,
            bqkv + i * 1152, nullptr, qkvb, ROWS, 1152, 384);
        attn_kernel<<<512, 256, 0, stream>>>(qkvb, ob);
        // t/tb = LN(o @ Wo + bo + t)
        gemm_ln<<<256, 512, 0, stream>>>(ob, WoTi, bo + i * 384, t,
            g1 + i * 384, be1 + i * 384, t, tb, 384);
        // hidden = relu(t @ W1 + b1)
        gemm_bf16_wide<17><<<dim3(12, 64), 256, 0, stream>>>(tb, W1Ti,
            b1 + i * 1536, nullptr, hb, ROWS, 1536, 384);
        // t/tb = LN(hidden @ W2 + b2 + t)
        gemm_ln<<<256, 512, 0, stream>>>(hb, W2Ti, b2 + i * 384, t,
            g2 + i * 384, be2 + i * 384, t, tb, 1536);
    }
    head_kernel<<<64, 384, 0, stream>>>(t, clw, clb, (float*)d_out);
}

// Round 9
// 570.335 us; speedup vs baseline: 1.3955x; 1.0552x over previous
//
#include <hip/hip_runtime.h>
#include <math.h>

// ---------------------------------------------------------------------------
// N=64, L=128, W=256, D=384, H=8, E=48, NL=4, DFF=1536, rows = N*L = 8192
// GEMMs: bf16 MFMA 16x16x32, A [M][K] bf16 row-major, Bt [N][K] bf16.
// R26: fuse qkv-GEMM + attention into qkvattn_kernel. Block (n,h) (grid
// 512) computes its 128x144 qkv slice (BK=64 dbuf; same k-chunk order as
// the old BK=32 wide GEMM -> bit-identical), writes q/k/v+bias as bf16
// directly into LDS (Qs/Ks[128][56], V transposed into Vt[48][136] = the
// R23-verified attn layout), then runs R23's attn body verbatim from LDS.
// Removes 1 dispatch/layer + 151 MB of qkvb write+read traffic. LDS
// phases alias (max 76.5 KB) -> 2 blocks/CU, grid 512 = exact residency.
// Post-mortem R25: 621.5->601.8 (-20 for -7 dispatches) => ~3us/dispatch
// launch overhead confirmed; fewer+bigger kernels that also kill
// intermediate traffic is the lever.
// ---------------------------------------------------------------------------

typedef float f32x4 __attribute__((ext_vector_type(4)));
typedef short bf16x8 __attribute__((ext_vector_type(8)));
typedef short s16x4 __attribute__((ext_vector_type(4)));

__device__ __forceinline__ short f2bf(float f) {
    union { float f; unsigned u; } c; c.f = f;
    unsigned r = (c.u + 0x7FFFu + ((c.u >> 16) & 1u)) >> 16;
    return (short)r;
}
__device__ __forceinline__ float bf2f(short s) {
    union { unsigned u; float f; } c;
    c.u = ((unsigned)(unsigned short)s) << 16;
    return c.f;
}

__device__ __forceinline__ void gload_lds16(const void* g, void* l) {
    __builtin_amdgcn_global_load_lds(
        (const __attribute__((address_space(1))) unsigned int*)g,
        (__attribute__((address_space(3))) unsigned int*)l,
        16, 0, 0);
}

// ---------------- merged prep: all weight cvt + pe + biascat + w2cvt -------
__global__ __launch_bounds__(256) void prep_kernel(
    const float* __restrict__ ew,
    const float* __restrict__ Wq, const float* __restrict__ Wk,
    const float* __restrict__ Wv, const float* __restrict__ Wo,
    const float* __restrict__ W1, const float* __restrict__ W2,
    const float* __restrict__ bq, const float* __restrict__ bk,
    const float* __restrict__ bv, const float* __restrict__ w2,
    short* __restrict__ ewT, short* __restrict__ WqkvT,
    short* __restrict__ WoT, short* __restrict__ W1T,
    short* __restrict__ W2T, float* __restrict__ pe,
    float* __restrict__ bqkv, short* __restrict__ w2T)
{
    __shared__ float tile[32][33];
    int id = blockIdx.x;
    int tid = threadIdx.x;
    int tx = tid & 31, ty = tid >> 5;

    const float* Wp;
    short* Wtp;
    int K, N, kb, nb;

    if (id < 768) {
        K = 2048; N = 384;
        kb = (id & 63) * 32; nb = (id >> 6) * 32;
        Wp = ew; Wtp = ewT;
    } else if (id < 2496) {
        int t = id - 768;
        int kbi = t % 12, nbi = (t / 12) % 12, z = t / 144;
        int layer = z / 3, which = z - layer * 3;
        K = 384; N = 384; kb = kbi * 32; nb = nbi * 32;
        Wp = (which == 0 ? Wq : (which == 1 ? Wk : Wv)) + (size_t)layer * 147456;
        Wtp = WqkvT + (size_t)layer * 442368 + (size_t)which * 147456;
    } else if (id < 3072) {
        int t = id - 2496;
        int kbi = t % 12, nbi = (t / 12) % 12, z = t / 144;
        K = 384; N = 384; kb = kbi * 32; nb = nbi * 32;
        Wp = Wo + (size_t)z * 147456; Wtp = WoT + (size_t)z * 147456;
    } else if (id < 5376) {
        int t = id - 3072;
        int kbi = t % 12, nbi = (t / 12) % 48, z = t / 576;
        K = 384; N = 1536; kb = kbi * 32; nb = nbi * 32;
        Wp = W1 + (size_t)z * 589824; Wtp = W1T + (size_t)z * 589824;
    } else if (id < 7680) {
        int t = id - 5376;
        int kbi = t % 48, nbi = (t / 48) % 12, z = t / 576;
        K = 1536; N = 384; kb = kbi * 32; nb = nbi * 32;
        Wp = W2 + (size_t)z * 589824; Wtp = W2T + (size_t)z * 589824;
    } else if (id < 7872) {
        int idx = (id - 7680) * 256 + tid;
        int l = idx / 384, d = idx - l * 384;
        int i2 = d >> 1;
        float ang = (float)l * expf(-(2.0f * (float)i2 / 384.0f) * 9.210340371976184f);
        pe[idx] = (d & 1) ? cosf(ang) : sinf(ang);
        return;
    } else if (id < 7890) {
        int idx = (id - 7872) * 256 + tid;
        int l = idx / 1152, j3 = idx - l * 1152;
        int which = j3 / 384, j = j3 - which * 384;
        const float* b = (which == 0 ? bq : (which == 1 ? bk : bv));
        bqkv[idx] = b[l * 384 + j];
        return;
    } else {
        int idx = (id - 7890) * 256 + tid;
        int c = idx >> 7, r = idx & 127;
        int pr = r >> 5, q = (r >> 3) & 3, j = r & 7;
        int ci = (q & 1) * 8 + j;
        int sft = 2 * pr + (q >> 1);
        w2T[idx] = (sft < 7) ? f2bf(w2[c * 112 + ci * 7 + sft]) : (short)0;
        return;
    }

    #pragma unroll
    for (int r = ty; r < 32; r += 8)
        tile[r][tx] = Wp[(size_t)(kb + r) * N + nb + tx];
    __syncthreads();
    #pragma unroll
    for (int r = ty; r < 32; r += 8)
        Wtp[(size_t)(nb + r) * K + kb + tx] = f2bf(tile[tx][r]);
}

// ---------------- fused CNN window encoder: 4 windows/block, 1 barrier -----
__global__ __launch_bounds__(256, 4) void cnn_kernel(
    const float* __restrict__ x,
    const float* __restrict__ w0, const float* __restrict__ b0,
    const float* __restrict__ w1, const float* __restrict__ b1,
    const short* __restrict__ w2T, const float* __restrict__ b2,
    short* __restrict__ feat)
{
    __shared__ __align__(16) char smem[26880];
    float* xs  = (float*)smem;                    // [4][264]
    float* p0  = (float*)(smem + 4224);           // [4][4][138]
    short* p1T = (short*)(smem + 13056);          // [4][72][24]

    int tid = threadIdx.x;
    int w = tid >> 6, lane = tid & 63;
    size_t win = (size_t)blockIdx.x * 4 + w;
    int cq = lane >> 4, cl = lane & 15;

    float* xs_w = xs + w * 264;
    float* p0_w = p0 + w * 552;                   // 4*138
    short* p1T_w = p1T + w * 1728;

    int ca = lane & 3;
    int cb = lane & 15, g = lane >> 4;
    float w0r[7], w1r[4][7];
    float b0r = b0[ca];
    float b1r = b1[cb];
    #pragma unroll
    for (int k = 0; k < 7; ++k) w0r[k] = w0[ca * 7 + k];
    #pragma unroll
    for (int ci = 0; ci < 4; ++ci)
        #pragma unroll
        for (int k = 0; k < 7; ++k) w1r[ci][k] = w1[(cb * 4 + ci) * 7 + k];

    {
        f32x4 v = *(const f32x4*)(x + win * 256 + lane * 4);
        *(f32x4*)&xs_w[4 + lane * 4] = v;
        if (lane < 2) *(f32x4*)&xs_w[lane * 260] = (f32x4){0.f, 0.f, 0.f, 0.f};
    }

    // ---- stage A (wave-local) ----
    {
        int pa = lane >> 2;
        #pragma unroll
        for (int t2 = 0; t2 < 8; ++t2) {
            int pp = t2 * 16 + pa;
            float rv[9];
            #pragma unroll
            for (int u = 0; u < 9; ++u) rv[u] = xs_w[2 * pp + u + 1];
            float a0 = b0r, a1 = b0r;
            #pragma unroll
            for (int k = 0; k < 7; ++k) {
                a0 = fmaf(w0r[k], rv[k], a0);
                a1 = fmaf(w0r[k], rv[k + 1], a1);
            }
            p0_w[ca * 138 + pp + 3] = fmaxf(fmaxf(a0, a1), 0.f);
        }
        if (lane < 4) {
            p0_w[lane * 138 + 0] = 0.f;
            p0_w[lane * 138 + 1] = 0.f;
            p0_w[lane * 138 + 2] = 0.f;
            p0_w[lane * 138 + 131] = 0.f;
            p0_w[lane * 138 + 132] = 0.f;
            p0_w[lane * 138 + 133] = 0.f;
        }
    }

    // ---- stage B (wave-local) ----
    #pragma unroll
    for (int cc = 0; cc < 4; ++cc) {
        int cci = (cc + g) & 3;
        int j0 = g * 32 + cci * 8;
        float acc[8];
        #pragma unroll
        for (int m = 0; m < 8; ++m) acc[m] = b1r;
        #pragma unroll
        for (int ci = 0; ci < 4; ++ci) {
            float rv[14];
            #pragma unroll
            for (int u = 0; u < 14; ++u) rv[u] = p0_w[ci * 138 + j0 + u];
            #pragma unroll
            for (int k = 0; k < 7; ++k) {
                float ww = w1r[ci][k];
                #pragma unroll
                for (int m = 0; m < 8; ++m) acc[m] = fmaf(ww, rv[m + k], acc[m]);
            }
        }
        int po = g * 16 + cci * 4;
        #pragma unroll
        for (int m = 0; m < 4; ++m)
            p1T_w[(3 + po + m) * 24 + cb] =
                f2bf(fmaxf(fmaxf(acc[2 * m], acc[2 * m + 1]), 0.f));
    }
    {
        int* pz = (int*)p1T_w;
        if (lane < 36) pz[lane] = 0;
        if (lane < 60) pz[804 + lane] = 0;
    }
    __syncthreads();

    // ---- stage C: conv2 as 4 paired-shift GEMMs ----
    f32x4 acc[4][4];
    #pragma unroll
    for (int v = 0; v < 4; ++v)
        #pragma unroll
        for (int mt = 0; mt < 4; ++mt)
            acc[v][mt] = (f32x4){0.f, 0.f, 0.f, 0.f};

    {
        const short* bpb = p1T + (w * 16 + cl + (cq >> 1)) * 24 + (cq & 1) * 8;
        #pragma unroll
        for (int pr = 0; pr < 4; ++pr) {
            bf16x8 bfr[4];
            #pragma unroll
            for (int v = 0; v < 4; ++v)
                bfr[v] = *(const bf16x8*)&bpb[v * 1728 + pr * 48];
            #pragma unroll
            for (int mt = 0; mt < 4; ++mt) {
                bf16x8 af = *(const bf16x8*)&w2T[(mt * 16 + cl) * 128 +
                                                 pr * 32 + cq * 8];
                #pragma unroll
                for (int v = 0; v < 4; ++v)
                    acc[v][mt] = __builtin_amdgcn_mfma_f32_16x16x32_bf16(
                        af, bfr[v], acc[v][mt], 0, 0, 0);
            }
        }
    }

    int iev = (w * 16 + cl) >> 1;
    #pragma unroll
    for (int v = 0; v < 4; ++v) {
        short* fp = feat + ((size_t)blockIdx.x * 4 + v) * 2048;
        #pragma unroll
        for (int mt = 0; mt < 4; ++mt) {
            #pragma unroll
            for (int rg = 0; rg < 4; ++rg) {
                float vv = acc[v][mt][rg];
                float v2 = __shfl_xor(vv, 1, 64);
                if ((cl & 1) == 0) {
                    int c = mt * 16 + cq * 4 + rg;
                    float pv = fmaxf(fmaxf(vv, v2) + b2[c], 0.f);
                    fp[c * 32 + iev] = f2bf(pv);
                }
            }
        }
    }
}

// ---------------- bf16 MFMA GEMM (thin-N): BM=128, BN=64, double-buffered --
template <int EPI>
__global__ __launch_bounds__(256) void gemm_bf16(
    const short* __restrict__ A, const short* __restrict__ Bt,
    const float* __restrict__ bias, const float* __restrict__ resid,
    const float* __restrict__ pe, float* __restrict__ outF,
    short* __restrict__ outB, int M, int N, int K)
{
    __shared__ short As[2][128 * 64];
    __shared__ short Bs[2][64 * 64];
    int tid = threadIdx.x;
    int w = tid >> 6, lane = tid & 63;
    int wm = w >> 1, wn = w & 1;
    int m0 = blockIdx.y * 128, n0 = blockIdx.x * 64;

    int rl = lane >> 3, sl = lane & 7;
    int cb = sl ^ rl;
    const short* aptr[4];
    const short* bptr[2];
    int arow[4], brow[2];
    #pragma unroll
    for (int l = 0; l < 4; ++l) {
        arow[l] = l * 32 + w * 8;
        aptr[l] = A + (size_t)(m0 + arow[l] + rl) * K + cb * 8;
    }
    #pragma unroll
    for (int l = 0; l < 2; ++l) {
        brow[l] = l * 32 + w * 8;
        bptr[l] = Bt + (size_t)(n0 + brow[l] + rl) * K + cb * 8;
    }

    int cq = lane >> 4, cl = lane & 15;
    f32x4 acc[4][2];
    #pragma unroll
    for (int mt = 0; mt < 4; ++mt)
        #pragma unroll
        for (int nt = 0; nt < 2; ++nt)
            acc[mt][nt] = (f32x4){0.f, 0.f, 0.f, 0.f};

    #pragma unroll
    for (int l = 0; l < 4; ++l) { gload_lds16(aptr[l], &As[0][arow[l] * 64]); aptr[l] += 64; }
    #pragma unroll
    for (int l = 0; l < 2; ++l) { gload_lds16(bptr[l], &Bs[0][brow[l] * 64]); bptr[l] += 64; }
    __syncthreads();

    int nk = K >> 6;
    for (int k = 0; k < nk; ++k) {
        int cur = k & 1;
        if (k + 1 < nk) {
            #pragma unroll
            for (int l = 0; l < 4; ++l) { gload_lds16(aptr[l], &As[cur ^ 1][arow[l] * 64]); aptr[l] += 64; }
            #pragma unroll
            for (int l = 0; l < 2; ++l) { gload_lds16(bptr[l], &Bs[cur ^ 1][brow[l] * 64]); bptr[l] += 64; }
        }
        #pragma unroll
        for (int s = 0; s < 2; ++s) {
            bf16x8 afr[4], bfr[2];
            #pragma unroll
            for (int mt = 0; mt < 4; ++mt) {
                int r = wm * 64 + mt * 16 + cl;
                int slot = (s * 4 + cq) ^ (r & 7);
                afr[mt] = *(const bf16x8*)&As[cur][r * 64 + slot * 8];
            }
            #pragma unroll
            for (int nt = 0; nt < 2; ++nt) {
                int r = wn * 32 + nt * 16 + cl;
                int slot = (s * 4 + cq) ^ (r & 7);
                bfr[nt] = *(const bf16x8*)&Bs[cur][r * 64 + slot * 8];
            }
            #pragma unroll
            for (int mt = 0; mt < 4; ++mt)
                #pragma unroll
                for (int nt = 0; nt < 2; ++nt)
                    acc[mt][nt] = __builtin_amdgcn_mfma_f32_16x16x32_bf16(
                        afr[mt], bfr[nt], acc[mt][nt], 0, 0, 0);
        }
        __syncthreads();
    }

    #pragma unroll
    for (int mt = 0; mt < 4; ++mt) {
        #pragma unroll
        for (int nt = 0; nt < 2; ++nt) {
            int col = n0 + wn * 32 + nt * 16 + cl;
            float bb = bias[col];
            #pragma unroll
            for (int rg = 0; rg < 4; ++rg) {
                int row = m0 + wm * 64 + mt * 16 + cq * 4 + rg;
                float v = acc[mt][nt][rg] + bb;
                if (EPI & 1) v = fmaxf(v, 0.f);
                if (EPI & 4) v += pe[(row & 127) * 384 + col];
                if (EPI & 2) v += resid[(size_t)row * N + col];
                if (EPI & 8) outF[(size_t)row * N + col] = v;
                if (EPI & 16) outB[(size_t)row * N + col] = f2bf(v);
            }
        }
    }
}

// ---------------- bf16 MFMA GEMM (wide-N): BM=128, BN=128, BK=32 dbuf ------
template <int EPI>
__global__ __launch_bounds__(256) void gemm_bf16_wide(
    const short* __restrict__ A, const short* __restrict__ Bt,
    const float* __restrict__ bias, float* __restrict__ outF,
    short* __restrict__ outB, int M, int N, int K)
{
    __shared__ short As[2][128 * 32];
    __shared__ short Bs[2][128 * 32];
    int tid = threadIdx.x;
    int w = tid >> 6, lane = tid & 63;
    int wm = w >> 1, wn = w & 1;
    int m0 = blockIdx.y * 128, n0 = blockIdx.x * 128;

    int rl = lane >> 2, sl = lane & 3;
    int cb = sl ^ (rl & 3) ^ ((rl >> 2) & 3);
    const short* aptr[2];
    const short* bptr[2];
    int srow[2];
    #pragma unroll
    for (int l = 0; l < 2; ++l) {
        srow[l] = w * 32 + l * 16;
        aptr[l] = A + (size_t)(m0 + srow[l] + rl) * K + cb * 8;
        bptr[l] = Bt + (size_t)(n0 + srow[l] + rl) * K + cb * 8;
    }

    int cq = lane >> 4, cl = lane & 15;
    f32x4 acc[4][4];
    #pragma unroll
    for (int mt = 0; mt < 4; ++mt)
        #pragma unroll
        for (int nt = 0; nt < 4; ++nt)
            acc[mt][nt] = (f32x4){0.f, 0.f, 0.f, 0.f};

    #pragma unroll
    for (int l = 0; l < 2; ++l) {
        gload_lds16(aptr[l], &As[0][srow[l] * 32]);
        gload_lds16(bptr[l], &Bs[0][srow[l] * 32]);
        aptr[l] += 32; bptr[l] += 32;
    }
    __syncthreads();

    int nk = K >> 5;
    for (int k = 0; k < nk; ++k) {
        int cur = k & 1;
        if (k + 1 < nk) {
            #pragma unroll
            for (int l = 0; l < 2; ++l) {
                gload_lds16(aptr[l], &As[cur ^ 1][srow[l] * 32]);
                gload_lds16(bptr[l], &Bs[cur ^ 1][srow[l] * 32]);
                aptr[l] += 32; bptr[l] += 32;
            }
        }
        bf16x8 afr[4], bfr[4];
        #pragma unroll
        for (int mt = 0; mt < 4; ++mt) {
            int r = wm * 64 + mt * 16 + cl;
            int slot = cq ^ (r & 3) ^ ((r >> 2) & 3);
            afr[mt] = *(const bf16x8*)&As[cur][r * 32 + slot * 8];
        }
        #pragma unroll
        for (int nt = 0; nt < 4; ++nt) {
            int r = wn * 64 + nt * 16 + cl;
            int slot = cq ^ (r & 3) ^ ((r >> 2) & 3);
            bfr[nt] = *(const bf16x8*)&Bs[cur][r * 32 + slot * 8];
        }
        #pragma unroll
        for (int mt = 0; mt < 4; ++mt)
            #pragma unroll
            for (int nt = 0; nt < 4; ++nt)
                acc[mt][nt] = __builtin_amdgcn_mfma_f32_16x16x32_bf16(
                    afr[mt], bfr[nt], acc[mt][nt], 0, 0, 0);
        __syncthreads();
    }

    #pragma unroll
    for (int mt = 0; mt < 4; ++mt) {
        #pragma unroll
        for (int nt = 0; nt < 4; ++nt) {
            int col = n0 + wn * 64 + nt * 16 + cl;
            float bb = bias[col];
            #pragma unroll
            for (int rg = 0; rg < 4; ++rg) {
                int row = m0 + wm * 64 + mt * 16 + cq * 4 + rg;
                float v = acc[mt][nt][rg] + bb;
                if (EPI & 1) v = fmaxf(v, 0.f);
                if (EPI & 8) outF[(size_t)row * N + col] = v;
                if (EPI & 16) outB[(size_t)row * N + col] = f2bf(v);
            }
        }
    }
}

// ---------------- fused GEMM + bias + residual + LayerNorm -----------------
// R24: BM=32, BN=384, BK=64, 512 threads, grid 256, double-buffered LDS.
__global__ __launch_bounds__(512) void gemm_ln(
    const short* __restrict__ A, const short* __restrict__ Bt,
    const float* __restrict__ bias, const float* resid,
    const float* __restrict__ g, const float* __restrict__ be,
    float* t, short* __restrict__ tb, int K)
{
    __shared__ __align__(16) char smem[106496];
    short* As0 = (short*)smem;                 // [2][32*64]  = 8 KB
    short* Bs0 = (short*)(smem + 8192);        // [2][384*64] = 96 KB

    int tid = threadIdx.x;
    int w = tid >> 6, lane = tid & 63;
    int m0 = blockIdx.x * 32;
    int rl = lane >> 3, sl = lane & 7;
    int cb = sl ^ rl;

    const short* aptr = A + (size_t)(m0 + (w & 3) * 8 + rl) * K + cb * 8;
    const short* bptr[6];
    #pragma unroll
    for (int l = 0; l < 6; ++l)
        bptr[l] = Bt + (size_t)(w * 48 + l * 8 + rl) * K + cb * 8;

    int cq = lane >> 4, cl = lane & 15;
    f32x4 acc[2][3];
    #pragma unroll
    for (int mt = 0; mt < 2; ++mt)
        #pragma unroll
        for (int nt = 0; nt < 3; ++nt)
            acc[mt][nt] = (f32x4){0.f, 0.f, 0.f, 0.f};

    if (w < 4) { gload_lds16(aptr, &As0[(w * 8) * 64]); aptr += 64; }
    #pragma unroll
    for (int l = 0; l < 6; ++l) {
        gload_lds16(bptr[l], &Bs0[(w * 48 + l * 8) * 64]);
        bptr[l] += 64;
    }
    __syncthreads();

    int nk = K >> 6;
    for (int k = 0; k < nk; ++k) {
        int cur = k & 1;
        if (k + 1 < nk) {
            if (w < 4) { gload_lds16(aptr, &As0[(cur ^ 1) * 2048 + (w * 8) * 64]); aptr += 64; }
            #pragma unroll
            for (int l = 0; l < 6; ++l) {
                gload_lds16(bptr[l], &Bs0[(cur ^ 1) * 24576 + (w * 48 + l * 8) * 64]);
                bptr[l] += 64;
            }
        }
        const short* As = As0 + cur * 2048;
        const short* Bs = Bs0 + cur * 24576;
        #pragma unroll
        for (int s = 0; s < 2; ++s) {
            bf16x8 afr[2], bfr[3];
            #pragma unroll
            for (int mt = 0; mt < 2; ++mt) {
                int r = mt * 16 + cl;
                int slot = (s * 4 + cq) ^ (r & 7);
                afr[mt] = *(const bf16x8*)&As[r * 64 + slot * 8];
            }
            #pragma unroll
            for (int nt = 0; nt < 3; ++nt) {
                int r = w * 48 + nt * 16 + cl;
                int slot = (s * 4 + cq) ^ (r & 7);
                bfr[nt] = *(const bf16x8*)&Bs[r * 64 + slot * 8];
            }
            #pragma unroll
            for (int mt = 0; mt < 2; ++mt)
                #pragma unroll
                for (int nt = 0; nt < 3; ++nt)
                    acc[mt][nt] = __builtin_amdgcn_mfma_f32_16x16x32_bf16(
                        afr[mt], bfr[nt], acc[mt][nt], 0, 0, 0);
        }
        __syncthreads();
    }

    float* yb = (float*)smem;
    #pragma unroll
    for (int mt = 0; mt < 2; ++mt) {
        #pragma unroll
        for (int nt = 0; nt < 3; ++nt) {
            int col = w * 48 + nt * 16 + cl;
            float bb = bias[col];
            #pragma unroll
            for (int rg = 0; rg < 4; ++rg) {
                int rloc = mt * 16 + cq * 4 + rg;
                yb[rloc * 388 + col] =
                    acc[mt][nt][rg] + bb + resid[(size_t)(m0 + rloc) * 384 + col];
            }
        }
    }
    __syncthreads();

    int rloc = tid >> 4, sub = tid & 15;
    f32x4 vals[6];
    float s = 0.f, s2 = 0.f;
    #pragma unroll
    for (int m = 0; m < 6; ++m) {
        f32x4 vv = *(const f32x4*)&yb[rloc * 388 + m * 64 + sub * 4];
        vals[m] = vv;
        #pragma unroll
        for (int j = 0; j < 4; ++j) {
            s += vv[j];
            s2 = fmaf(vv[j], vv[j], s2);
        }
    }
    s += __shfl_xor(s, 1, 64);  s2 += __shfl_xor(s2, 1, 64);
    s += __shfl_xor(s, 2, 64);  s2 += __shfl_xor(s2, 2, 64);
    s += __shfl_xor(s, 4, 64);  s2 += __shfl_xor(s2, 4, 64);
    s += __shfl_xor(s, 8, 64);  s2 += __shfl_xor(s2, 8, 64);
    float mean = s * (1.f / 384.f);
    float var = s2 * (1.f / 384.f) - mean * mean;
    float inv = rsqrtf(var + 1e-5f);

    size_t ro = (size_t)(m0 + rloc) * 384;
    #pragma unroll
    for (int m = 0; m < 6; ++m) {
        int c0 = m * 64 + sub * 4;
        f32x4 gg = *(const f32x4*)&g[c0];
        f32x4 bb = *(const f32x4*)&be[c0];
        f32x4 ov;
        s16x4 ob2;
        #pragma unroll
        for (int j = 0; j < 4; ++j) {
            float v = (vals[m][j] - mean) * inv * gg[j] + bb[j];
            ov[j] = v;
            ob2[j] = f2bf(v);
        }
        *(f32x4*)&t[ro + c0] = ov;
        *(s16x4*)&tb[ro + c0] = ob2;
    }
}

// ---------------- fused qkv-GEMM + attention per (n,h) ---------------------
// Phase 1: C[128][144] = tb rows (n*128..+127) @ WqkvT rows {g*384+h*48..+47}
// (BK=64 dbuf, same k-chunk order as old BK=32 wide GEMM -> bit-identical).
// Epilogue: +bias, f2bf -> Qs/Ks[128][56] LDS, V transposed -> Vt[48][136].
// Phase 2: R23 attn body verbatim, sources from LDS. LDS aliased:
//   GEMM: As0[0..32768) Bs0[32768..69632)
//   attn: Qs[0..14336) Ks[14336..28672) Vt[28672..41728) P[41728..76544)
__global__ __launch_bounds__(256) void qkvattn_kernel(
    const short* __restrict__ A, const short* __restrict__ Bt,
    const float* __restrict__ bias, short* __restrict__ o)
{
    __shared__ __align__(16) char smem[76544];
    short* As0 = (short*)smem;                 // [2][128*64]
    short* Bs0 = (short*)(smem + 32768);       // [2][144*64]
    short* Qs  = (short*)smem;                 // [128][56]
    short* Ks  = (short*)(smem + 14336);       // [128][56]
    short* Vt  = (short*)(smem + 28672);       // [48][136]
    short* P   = (short*)(smem + 41728);       // [4][32][136]

    int tid = threadIdx.x;
    int w = tid >> 6, lane = tid & 63;
    int cq = lane >> 4, cl = lane & 15;
    int n = blockIdx.x >> 3, h = blockIdx.x & 7;
    int m0 = n * 128;

    // ---- phase 1: qkv GEMM ----
    int rl = lane >> 3, sl = lane & 7;
    int cb = sl ^ rl;
    const short* aptr[4];
    int arow[4];
    #pragma unroll
    for (int l = 0; l < 4; ++l) {
        arow[l] = l * 32 + w * 8;
        aptr[l] = A + (size_t)(m0 + arow[l] + rl) * 384 + cb * 8;
    }
    const short* bptr[5];
    int brow[5];
    #pragma unroll
    for (int l = 0; l < 5; ++l) {
        brow[l] = (l < 4) ? (l * 32 + w * 8) : (128 + w * 8);
        int r = brow[l] + rl;
        int g0 = (r >= 96) ? 2 : ((r >= 48) ? 1 : 0);
        int loc = r - g0 * 48;
        bptr[l] = Bt + (size_t)(g0 * 384 + h * 48 + loc) * 384 + cb * 8;
    }

    f32x4 acc[2][9];
    #pragma unroll
    for (int mt = 0; mt < 2; ++mt)
        #pragma unroll
        for (int nt = 0; nt < 9; ++nt)
            acc[mt][nt] = (f32x4){0.f, 0.f, 0.f, 0.f};

    #pragma unroll
    for (int l = 0; l < 4; ++l) { gload_lds16(aptr[l], &As0[arow[l] * 64]); aptr[l] += 64; }
    #pragma unroll
    for (int l = 0; l < 5; ++l) {
        if (l < 4 || w < 2) { gload_lds16(bptr[l], &Bs0[brow[l] * 64]); }
        bptr[l] += 64;
    }
    __syncthreads();

    for (int k = 0; k < 6; ++k) {
        int cur = k & 1;
        if (k + 1 < 6) {
            #pragma unroll
            for (int l = 0; l < 4; ++l) {
                gload_lds16(aptr[l], &As0[(cur ^ 1) * 8192 + arow[l] * 64]);
                aptr[l] += 64;
            }
            #pragma unroll
            for (int l = 0; l < 5; ++l) {
                if (l < 4 || w < 2)
                    gload_lds16(bptr[l], &Bs0[(cur ^ 1) * 9216 + brow[l] * 64]);
                bptr[l] += 64;
            }
        }
        const short* Asb = As0 + cur * 8192;
        const short* Bsb = Bs0 + cur * 9216;
        #pragma unroll
        for (int s = 0; s < 2; ++s) {
            bf16x8 afr[2], bfr[9];
            #pragma unroll
            for (int mt = 0; mt < 2; ++mt) {
                int r = w * 32 + mt * 16 + cl;
                int slot = (s * 4 + cq) ^ (r & 7);
                afr[mt] = *(const bf16x8*)&Asb[r * 64 + slot * 8];
            }
            #pragma unroll
            for (int nt = 0; nt < 9; ++nt) {
                int r = nt * 16 + cl;
                int slot = (s * 4 + cq) ^ (r & 7);
                bfr[nt] = *(const bf16x8*)&Bsb[r * 64 + slot * 8];
            }
            #pragma unroll
            for (int mt = 0; mt < 2; ++mt)
                #pragma unroll
                for (int nt = 0; nt < 9; ++nt)
                    acc[mt][nt] = __builtin_amdgcn_mfma_f32_16x16x32_bf16(
                        afr[mt], bfr[nt], acc[mt][nt], 0, 0, 0);
        }
        __syncthreads();
    }
    // (last barrier of loop: all MFMA reads of As0/Bs0 done -> safe to alias)

    // ---- epilogue: +bias, bf16 -> Qs/Ks (row-major) and Vt (transposed) ----
    const float* bh = bias + h * 48;
    #pragma unroll
    for (int mt = 0; mt < 2; ++mt) {
        #pragma unroll
        for (int nt = 0; nt < 9; ++nt) {
            int grp = nt / 3;
            int col = (nt - grp * 3) * 16 + cl;     // 0..47 within group
            float bb = bh[grp * 384 + col];
            if (grp == 2) {
                int row0 = w * 32 + mt * 16 + cq * 4;
                s16x4 pv;
                #pragma unroll
                for (int rg = 0; rg < 4; ++rg) pv[rg] = f2bf(acc[mt][nt][rg] + bb);
                *(s16x4*)&Vt[col * 136 + row0] = pv;
            } else {
                short* dst = (grp == 0) ? Qs : Ks;
                #pragma unroll
                for (int rg = 0; rg < 4; ++rg) {
                    int row = w * 32 + mt * 16 + cq * 4 + rg;
                    dst[row * 56 + col] = f2bf(acc[mt][nt][rg] + bb);
                }
            }
        }
    }
    __syncthreads();   // Qs/Ks/Vt ready for all waves

    // ---- phase 2: attention (R23 structure, LDS sources) ----
    const bf16x8 zf = (bf16x8){0, 0, 0, 0, 0, 0, 0, 0};
    bf16x8 qf[2][2];
    #pragma unroll
    for (int mt = 0; mt < 2; ++mt) {
        int r = w * 32 + mt * 16 + cl;
        qf[mt][0] = *(const bf16x8*)&Qs[r * 56 + cq * 8];
        qf[mt][1] = (cq < 2) ? *(const bf16x8*)&Qs[r * 56 + 32 + cq * 8] : zf;
    }

    f32x4 sacc[2][8];
    #pragma unroll
    for (int mt = 0; mt < 2; ++mt)
        #pragma unroll
        for (int kt = 0; kt < 8; ++kt)
            sacc[mt][kt] = (f32x4){0.f, 0.f, 0.f, 0.f};

    #pragma unroll
    for (int kt = 0; kt < 8; ++kt) {
        int r = kt * 16 + cl;
        bf16x8 kf0 = *(const bf16x8*)&Ks[r * 56 + cq * 8];
        bf16x8 kf1 = (cq < 2) ? *(const bf16x8*)&Ks[r * 56 + 32 + cq * 8] : zf;
        #pragma unroll
        for (int mt = 0; mt < 2; ++mt) {
            sacc[mt][kt] = __builtin_amdgcn_mfma_f32_16x16x32_bf16(
                qf[mt][0], kf0, sacc[mt][kt], 0, 0, 0);
            sacc[mt][kt] = __builtin_amdgcn_mfma_f32_16x16x32_bf16(
                qf[mt][1], kf1, sacc[mt][kt], 0, 0, 0);
        }
    }

    const float temp = 0.14433756729740643f;  // 1/sqrt(48)
    short* Pw = P + w * 4352;
    float denom[2][4];
    #pragma unroll
    for (int mt = 0; mt < 2; ++mt) {
        #pragma unroll
        for (int rg = 0; rg < 4; ++rg) {
            float mx = sacc[mt][0][rg];
            #pragma unroll
            for (int kt = 1; kt < 8; ++kt) mx = fmaxf(mx, sacc[mt][kt][rg]);
            mx = fmaxf(mx, __shfl_xor(mx, 1, 64));
            mx = fmaxf(mx, __shfl_xor(mx, 2, 64));
            mx = fmaxf(mx, __shfl_xor(mx, 4, 64));
            mx = fmaxf(mx, __shfl_xor(mx, 8, 64));
            int row = mt * 16 + cq * 4 + rg;
            float se = 0.f;
            #pragma unroll
            for (int kt = 0; kt < 8; ++kt) {
                float p = __expf(temp * (sacc[mt][kt][rg] - mx));
                se += p;
                Pw[row * 136 + kt * 16 + cl] = f2bf(p);
            }
            se += __shfl_xor(se, 1, 64);
            se += __shfl_xor(se, 2, 64);
            se += __shfl_xor(se, 4, 64);
            se += __shfl_xor(se, 8, 64);
            denom[mt][rg] = se;
        }
    }

    f32x4 oacc[2][3];
    #pragma unroll
    for (int mt = 0; mt < 2; ++mt)
        #pragma unroll
        for (int nt = 0; nt < 3; ++nt)
            oacc[mt][nt] = (f32x4){0.f, 0.f, 0.f, 0.f};

    #pragma unroll
    for (int ks = 0; ks < 4; ++ks) {
        bf16x8 paf[2];
        #pragma unroll
        for (int mt = 0; mt < 2; ++mt)
            paf[mt] = *(const bf16x8*)&Pw[(mt * 16 + cl) * 136 + ks * 32 + cq * 8];
        #pragma unroll
        for (int nt = 0; nt < 3; ++nt) {
            bf16x8 vf = *(const bf16x8*)&Vt[(nt * 16 + cl) * 136 + ks * 32 + cq * 8];
            #pragma unroll
            for (int mt = 0; mt < 2; ++mt)
                oacc[mt][nt] = __builtin_amdgcn_mfma_f32_16x16x32_bf16(
                    paf[mt], vf, oacc[mt][nt], 0, 0, 0);
        }
    }

    #pragma unroll
    for (int mt = 0; mt < 2; ++mt) {
        #pragma unroll
        for (int rg = 0; rg < 4; ++rg) {
            float inv = 1.f / denom[mt][rg];
            int qrow = w * 32 + mt * 16 + cq * 4 + rg;
            short* op = o + ((size_t)n * 128 + qrow) * 384 + h * 48;
            #pragma unroll
            for (int nt = 0; nt < 3; ++nt)
                op[nt * 16 + cl] = f2bf(oacc[mt][nt][rg] * inv);
        }
    }
}

// ---------------- classifier head ------------------------------------------
__global__ __launch_bounds__(384) void head_kernel(
    const float* __restrict__ t, const float* __restrict__ cls_w,
    const float* __restrict__ cls_b, float* __restrict__ out)
{
    int n = blockIdx.x, d = threadIdx.x;
    float s = 0.f;
    for (int l = 0; l < 128; ++l) s += t[((size_t)n * 128 + l) * 384 + d];
    float p = s * (1.f / 128.f) * cls_w[d];
    #pragma unroll
    for (int off = 32; off > 0; off >>= 1) p += __shfl_xor(p, off, 64);
    __shared__ float red[6];
    if ((threadIdx.x & 63) == 0) red[threadIdx.x >> 6] = p;
    __syncthreads();
    if (threadIdx.x == 0) {
        float tot = red[0] + red[1] + red[2] + red[3] + red[4] + red[5];
        out[n] = tot + cls_b[0];
    }
}

// ---------------------------------------------------------------------------
extern "C" void kernel_launch(void* const* d_in, const int* in_sizes, int n_in,
                              void* d_out, int out_size, void* d_ws, size_t ws_size,
                              hipStream_t stream) {
    (void)n_in; (void)out_size; (void)ws_size;
    const float* x   = (const float*)d_in[0];
    const float* cw0 = (const float*)d_in[1];
    const float* cb0 = (const float*)d_in[2];
    const float* cw1 = (const float*)d_in[3];
    const float* cb1 = (const float*)d_in[4];
    const float* cw2 = (const float*)d_in[5];
    const float* cb2 = (const float*)d_in[6];
    const float* ew  = (const float*)d_in[7];
    const float* eb  = (const float*)d_in[8];
    bool dict_order = (in_sizes[10] == 589824);
    const float *Wq, *Wk, *Wv, *Wo, *W1, *W2, *bq, *bk, *bv, *bo, *b1, *b2;
    if (dict_order) {
        Wq = (const float*)d_in[9];  Wk = (const float*)d_in[10];
        Wv = (const float*)d_in[11]; Wo = (const float*)d_in[12];
        W1 = (const float*)d_in[13]; W2 = (const float*)d_in[14];
        bq = (const float*)d_in[15]; bk = (const float*)d_in[16];
        bv = (const float*)d_in[17]; bo = (const float*)d_in[18];
        b1 = (const float*)d_in[19]; b2 = (const float*)d_in[20];
    } else {
        Wq = (const float*)d_in[9];  bq = (const float*)d_in[10];
        Wk = (const float*)d_in[11]; bk = (const float*)d_in[12];
        Wv = (const float*)d_in[13]; bv = (const float*)d_in[14];
        Wo = (const float*)d_in[15]; bo = (const float*)d_in[16];
        W1 = (const float*)d_in[17]; b1 = (const float*)d_in[18];
        W2 = (const float*)d_in[19]; b2 = (const float*)d_in[20];
    }
    const float* g1  = (const float*)d_in[21];
    const float* be1 = (const float*)d_in[22];
    const float* g2  = (const float*)d_in[23];
    const float* be2 = (const float*)d_in[24];
    const float* clw = (const float*)d_in[25];
    const float* clb = (const float*)d_in[26];

    // ---- workspace layout (bytes) ----
    char* wp = (char*)d_ws;
    float* pe    = (float*)wp; wp += 196608;      // 128*384 f32
    short* featb = (short*)wp; wp += 33554432;    // 8192*2048 bf16 (reused as FFN hidden)
    float* t     = (float*)wp; wp += 12582912;    // 8192*384 f32
    short* tb    = (short*)wp; wp += 6291456;     // 8192*384 bf16
    short* qkvb  = (short*)wp; wp += 18874368;    // 8192*1152 bf16 (unused after R26)
    short* ob    = (short*)wp; wp += 6291456;     // 8192*384 bf16 (attn out)
    short* ewT   = (short*)wp; wp += 1572864;     // 384 x 2048
    short* WqkvT = (short*)wp; wp += 3538944;     // 4 x 1152 x 384
    short* WoT   = (short*)wp; wp += 1179648;     // 4 x 384 x 384
    short* W1T   = (short*)wp; wp += 4718592;     // 4 x 1536 x 384
    short* W2T   = (short*)wp; wp += 4718592;     // 4 x 384 x 1536
    float* bqkv  = (float*)wp; wp += 18432;       // 4 x 1152 f32
    short* w2T   = (short*)wp; wp += 16384;       // 64 x 128 bf16 (conv2, paired-shift layout)
    short* hb    = featb;                         // FFN hidden 8192*1536 bf16
    (void)qkvb;

    const int ROWS = 8192;

    prep_kernel<<<7922, 256, 0, stream>>>(ew, Wq, Wk, Wv, Wo, W1, W2,
                                          bq, bk, bv, cw2,
                                          ewT, WqkvT, WoT, W1T, W2T,
                                          pe, bqkv, w2T);
    cnn_kernel<<<2048, 256, 0, stream>>>(x, cw0, cb0, cw1, cb1, w2T, cb2, featb);

    // t/tb = relu(feat @ ew + eb) + pe
    gemm_bf16<29><<<dim3(6, 64), 256, 0, stream>>>(featb, ewT, eb, nullptr, pe,
                                                   t, tb, ROWS, 384, 2048);
    for (int i = 0; i < 4; ++i) {
        const short* WqkvTi = WqkvT + (size_t)i * 442368;
        const short* WoTi = WoT + (size_t)i * 147456;
        const short* W1Ti = W1T + (size_t)i * 589824;
        const short* W2Ti = W2T + (size_t)i * 589824;
        // ob = attn(qkv(tb)) fused
        qkvattn_kernel<<<512, 256, 0, stream>>>(tb, WqkvTi, bqkv + i * 1152, ob);
        // t/tb = LN(o @ Wo + bo + t)
        gemm_ln<<<256, 512, 0, stream>>>(ob, WoTi, bo + i * 384, t,
            g1 + i * 384, be1 + i * 384, t, tb, 384);
        // hidden = relu(t @ W1 + b1)
        gemm_bf16_wide<17><<<dim3(12, 64), 256, 0, stream>>>(tb, W1Ti,
            b1 + i * 1536, nullptr, hb, ROWS, 1536, 384);
        // t/tb = LN(hidden @ W2 + b2 + t)
        gemm_ln<<<256, 512, 0, stream>>>(hb, W2Ti, b2 + i * 384, t,
            g2 + i * 384, be2 + i * 384, t, tb, 1536);
    }
    head_kernel<<<64, 384, 0, stream>>>(t, clw, clb, (float*)d_out);
}